// Round 4
// baseline (1164.610 us; speedup 1.0000x reference)
//
#include <hip/hip_runtime.h>
#include <math.h>

#define CC 32
#define LL 16
#define HH 64
#define WW 64
#define WF 33
#define RR 16
#define PI_F 3.14159265358979323846f

// ---- workspace layout (floats). Regions reused across phases. ----
#define OFF_F1      0          // 2097152  f1 (conv1 out); later reused as Y2
#define OFF_COLSUM  2097152    // 32768    [l][c][w]
#define OFF_GLOB    2130432    // 512
#define OFF_FEAT    2130944    // 16896    [l][wf][c]
#define OFF_ARE     2147840    // 270336   [l][c][wf][r]
#define OFF_AIM     2418176    // 270336
#define OFF_SGG     2688512    // 270336
#define OFF_XFR     2958848    // 1081344  [l][c][h][f]
#define OFF_XFI     4040192    // 1081344
#define OFF_YFR     5121536    // 1081344
#define OFF_YFI     6202880    // 1081344
#define OFF_Y1      2958848    // 2097152  (overlaps dead XFR/XFI)
#define OFF_Y2      0          // 2097152  (overlaps dead F1)
#define OFF_GNM     7284224    // 64
#define OFF_GNR     7284288    // 64
#define OFF_YM      7284352    // 32768    [l][h][c]
#define OFF_GATE    7317120    // 32768
#define OFF_WVEC    7349888    // 66
#define OFF_WT      7350016    // 18432: transposed conv1 (9216) + conv2 (9216) weights
// total ~29.5 MB

__device__ __forceinline__ float sigmoidf_(float x){ return 1.0f/(1.0f+expf(-x)); }

// ---- K0: collapse mix/rank_scale/proj into two 32-vectors ----
__global__ void k_prep(const float* __restrict__ mix_w, const float* __restrict__ mix_b,
                       const float* __restrict__ rank_scale, const float* __restrict__ proj_w,
                       const float* __restrict__ proj_b, float* __restrict__ ws){
    float* wv = ws + OFF_WVEC;
    int t = threadIdx.x;
    if (t < 32){
        float sre=0.f, sim=0.f;
        for (int r=0;r<RR;r++){
            float a = proj_w[r]*rank_scale[r];
            sre += a*mix_w[r*2*RR + t];
            sim += a*mix_w[(RR+r)*2*RR + t];
        }
        wv[t] = sre;
        wv[32+t] = sim;
    }
    if (t == 0){
        float cre=0.f, cim=0.f;
        for (int r=0;r<RR;r++){
            float a = proj_w[r]*rank_scale[r];
            cre += a*mix_b[r];
            cim += a*mix_b[RR+r];
        }
        wv[64] = cre + proj_b[0];
        wv[65] = cim;
    }
}

// ---- K0b: pre-transpose conv weights OIHW -> [tap][co] (tap = ci*9+kh*3+kw) ----
__global__ void k_wprep(const float* __restrict__ c1w, const float* __restrict__ c2w,
                        float* __restrict__ ws){
    int i = blockIdx.x*256 + threadIdx.x;
    if (i >= 2*9216) return;
    int which = (i >= 9216);
    int j = which ? i - 9216 : i;
    int tap = j >> 5, co = j & 31;
    const float* cw = which ? c2w : c1w;
    ws[OFF_WT + i] = cw[co*288 + tap];
}

// ---- K1/K2: 3x3 SAME conv (32->32) + SiLU, LDS-staged, reg-prefetch pipelined.
// MODE 0: src=x, write silu to f1.  MODE 1: src=f1, reduce to colsum.
// Block = (l, h-tile of 2 rows). 256 thr = 16 wq(4w) x 2 row x 8 cg(4co).
template<int MODE>
__global__ __launch_bounds__(256, 4) void k_conv(const float* __restrict__ src,
                                                 long ci_stride, long l_stride,
                                                 const float* __restrict__ wT,
                                                 const float* __restrict__ cb,
                                                 float* __restrict__ ws){
    __shared__ float xs[8][4][66];      // 8-ci chunk, 4 rows, halo cols [0]/[65] zeroed
    __shared__ float lw[2304];          // per-chunk weights [cil*9+tap][co]
    __shared__ float red[MODE ? CC*WW : 1];

    const int tid = threadIdx.x;
    const int l   = blockIdx.x >> 5;
    const int h0  = (blockIdx.x & 31)*2;

    const int wq  = tid & 15;
    const int row = (tid >> 4) & 1;
    const int cg  = tid >> 5;
    const int w0  = wq*4;
    const int co0 = cg*4;

    if (MODE){
        for (int i = tid; i < CC*WW; i += 256) red[i] = 0.f;
    }
    if (tid < 64){   // zero halo columns once (never overwritten)
        int cil = tid >> 3, rr = (tid >> 1) & 3, e = tid & 1;
        xs[cil][rr][e ? 65 : 0] = 0.f;
    }

    const float* sbase = src + (long)l*l_stride;

    // decode staging indices once
    const int s_cil = tid >> 8;           // 0 for tid<256 contributions handled per j below
    (void)s_cil;

    float xv[8], wv[9];
    // ---- prologue: load + write chunk 0 ----
    #pragma unroll
    for (int j = 0; j < 8; ++j){
        int i = tid + j*256;
        int cil = i >> 8, rr = (i >> 6) & 3, w = i & 63;
        int h = h0 - 1 + rr;
        xv[j] = (h >= 0 && h < HH) ? sbase[(long)cil*ci_stride + h*WW + w] : 0.f;
    }
    #pragma unroll
    for (int j = 0; j < 9; ++j) wv[j] = wT[tid + j*256];
    #pragma unroll
    for (int j = 0; j < 8; ++j){
        int i = tid + j*256;
        xs[i >> 8][(i >> 6) & 3][1 + (i & 63)] = xv[j];
    }
    #pragma unroll
    for (int j = 0; j < 9; ++j) lw[tid + j*256] = wv[j];

    float acc[4][4];
    #pragma unroll
    for (int i=0;i<4;i++)
        #pragma unroll
        for (int j=0;j<4;j++) acc[i][j]=0.f;

    #pragma unroll 1
    for (int chunk = 0; chunk < 4; ++chunk){
        // issue next chunk's loads (latency hides under compute below)
        if (chunk < 3){
            #pragma unroll
            for (int j = 0; j < 8; ++j){
                int i = tid + j*256;
                int cil = i >> 8, rr = (i >> 6) & 3, w = i & 63;
                int h = h0 - 1 + rr;
                xv[j] = (h >= 0 && h < HH) ? sbase[(long)((chunk+1)*8+cil)*ci_stride + h*WW + w] : 0.f;
            }
            #pragma unroll
            for (int j = 0; j < 9; ++j) wv[j] = wT[(chunk+1)*2304 + tid + j*256];
        }
        __syncthreads();   // staged chunk visible
        #pragma unroll
        for (int cil = 0; cil < 8; ++cil){
            #pragma unroll
            for (int kh = 0; kh < 3; ++kh){
                const float* xr = &xs[cil][row+kh][w0];   // [w0-1+j] -> xr[j]
                float xv0=xr[0],xv1=xr[1],xv2=xr[2],xv3=xr[3],xv4=xr[4],xv5=xr[5];
                const float* wp = &lw[(cil*9 + kh*3)*32 + co0];
                #pragma unroll
                for (int kw = 0; kw < 3; ++kw){
                    float4 wa = *(const float4*)(wp + kw*32);
                    float x0 = (kw==0)?xv0:((kw==1)?xv1:xv2);
                    float x1 = (kw==0)?xv1:((kw==1)?xv2:xv3);
                    float x2 = (kw==0)?xv2:((kw==1)?xv3:xv4);
                    float x3 = (kw==0)?xv3:((kw==1)?xv4:xv5);
                    acc[0][0] += x0*wa.x; acc[0][1] += x1*wa.x; acc[0][2] += x2*wa.x; acc[0][3] += x3*wa.x;
                    acc[1][0] += x0*wa.y; acc[1][1] += x1*wa.y; acc[1][2] += x2*wa.y; acc[1][3] += x3*wa.y;
                    acc[2][0] += x0*wa.z; acc[2][1] += x1*wa.z; acc[2][2] += x2*wa.z; acc[2][3] += x3*wa.z;
                    acc[3][0] += x0*wa.w; acc[3][1] += x1*wa.w; acc[3][2] += x2*wa.w; acc[3][3] += x3*wa.w;
                }
            }
        }
        __syncthreads();   // reads done; safe to overwrite stage
        if (chunk < 3){
            #pragma unroll
            for (int j = 0; j < 8; ++j){
                int i = tid + j*256;
                xs[i >> 8][(i >> 6) & 3][1 + (i & 63)] = xv[j];
            }
            #pragma unroll
            for (int j = 0; j < 9; ++j) lw[tid + j*256] = wv[j];
        }
    }

    if (MODE == 0){
        const int h = h0 + row;
        float* dst = ws + OFF_F1 + (((long)l*CC)*HH + h)*WW + w0;
        #pragma unroll
        for (int i = 0; i < 4; ++i){
            float bias = cb[co0+i];
            float4 o;
            float a0 = acc[i][0]+bias, a1 = acc[i][1]+bias, a2 = acc[i][2]+bias, a3 = acc[i][3]+bias;
            o.x = a0*sigmoidf_(a0); o.y = a1*sigmoidf_(a1);
            o.z = a2*sigmoidf_(a2); o.w = a3*sigmoidf_(a3);
            *(float4*)(dst + (long)(co0+i)*HH*WW) = o;
        }
    } else {
        #pragma unroll
        for (int i = 0; i < 4; ++i){
            float bias = cb[co0+i];
            #pragma unroll
            for (int j = 0; j < 4; ++j){
                float a = acc[i][j] + bias;
                a = a*sigmoidf_(a);
                a += __shfl_xor(a, 16, 64);   // row0+row1 pair
                if (row == 0) atomicAdd(&red[(co0+i)*WW + w0 + j], a);
            }
        }
        __syncthreads();
        // 2048 values, 256 threads: co = t>>3, wseg = (t&7)*8
        int co = tid >> 3, wseg = (tid & 7)*8;
        #pragma unroll
        for (int j = 0; j < 8; ++j){
            float v = red[co*WW + wseg + j];
            atomicAdd(&ws[OFF_COLSUM + (l*CC+co)*WW + wseg + j], v);
        }
    }
}

// ---- K3: glob (gsum derived from colsum). Grid = 16 blocks x 64 thr. ----
__global__ void k_glob(const float* __restrict__ gfc_w, const float* __restrict__ gfc_b,
                       float* __restrict__ ws){
    __shared__ float gs[CC];
    int l = blockIdx.x;
    int tid = threadIdx.x;
    if (tid < 32){
        const float* cs = ws + OFF_COLSUM + (l*CC+tid)*WW;
        float s = 0.f;
        for (int w=0;w<WW;w++) s += cs[w];
        gs[tid] = s;
    }
    __syncthreads();
    if (tid < 32){
        float acc = gfc_b[tid];
        for (int i=0;i<CC;i++) acc += gs[i]*(1.0f/4096.0f)*gfc_w[tid*CC+i];
        ws[OFF_GLOB + l*CC + tid] = sigmoidf_(acc);
    }
}

// ---- K4: adaptive pool * glob ----
__global__ void k_feat(float* __restrict__ ws){
    int t = blockIdx.x*blockDim.x + threadIdx.x;
    if (t >= LL*WF*CC) return;
    int c = t & 31;
    int lw_ = t >> 5;
    int wf = lw_ % WF, l = lw_ / WF;
    int s = (wf*64)/33;
    int e = ((wf+1)*64 + 32)/33;
    const float* cs = ws + OFF_COLSUM + (l*CC+c)*WW;
    float sum = 0.f;
    for (int w=s;w<e;w++) sum += cs[w];
    ws[OFF_FEAT + (l*WF+wf)*CC + c] = ws[OFF_GLOB + l*CC + c] * sum / (64.0f*(float)(e-s));
}

// ---- K5: head ----
__global__ void k_head(const float* __restrict__ hw, const float* __restrict__ hb,
                       const float* __restrict__ dt, float* __restrict__ ws){
    int t = blockIdx.x*blockDim.x + threadIdx.x;
    if (t >= LL*WF*CC*RR) return;
    int r = t & 15, c = (t>>4) & 31;
    int lw_ = t >> 9;
    int wf = lw_ % WF, l = lw_ / WF;
    const float* feat = ws + OFF_FEAT + (l*WF+wf)*CC;
    int j0 = (c*RR + r)*3;
    const float* w0 = hw + j0*CC;
    float p0=hb[j0], p1=hb[j0+1], p2=hb[j0+2];
    for (int i=0;i<CC;i++){
        float fv = feat[i];
        p0 += fv*w0[i]; p1 += fv*w0[CC+i]; p2 += fv*w0[2*CC+i];
    }
    float nu = fmaxf(p0,0.f) + log1pf(expf(-fabsf(p0)));
    float th = tanhf(p1)*PI_F;
    float sg = sigmoidf_(p2);
    float dtv = dt[l];
    float decay = expf(-nu*dtv);
    float ang = th*dtv;
    float g = 1.0f - expf(-2.0f*fmaxf(dtv,0.f));
    int idx = ((l*CC+c)*WF+wf)*RR + r;
    ws[OFF_ARE+idx] = decay*cosf(ang);
    ws[OFF_AIM+idx] = decay*sinf(ang);
    ws[OFF_SGG+idx] = sg*g;
}

// ---- K6: rfft over W (direct DFT). Block = (l,c). ----
__global__ void k_rfft(const float* __restrict__ x, float* __restrict__ ws){
    __shared__ float plane[HH][WW+1];
    __shared__ float ct[64], st[64];
    int b = blockIdx.x; int l = b >> 5, c = b & 31;
    int tid = threadIdx.x;
    if (tid < 64){
        float ang = 2.0f*PI_F*(float)tid/64.0f;
        ct[tid] = cosf(ang); st[tid] = sinf(ang);
    }
    const float* xp = x + (c*LL + l)*HH*WW;
    for (int k=0;k<16;k++){
        int pix = tid + k*256;
        plane[pix>>6][pix&63] = xp[pix];
    }
    __syncthreads();
    float* xfr = ws + OFF_XFR + (l*CC + c)*HH*WF;
    float* xfi = ws + OFF_XFI + (l*CC + c)*HH*WF;
    for (int k=0;k<9;k++){
        int oi = tid + k*256;
        if (oi >= HH*WF) break;
        int h = oi/WF, f = oi - h*WF;
        float re=0.f, im=0.f;
        int idx = 0;
        for (int w=0;w<WW;w++){
            float v = plane[h][w];
            re += v*ct[idx]; im -= v*st[idx];
            idx = (idx + f) & 63;
        }
        xfr[oi] = re; xfi[oi] = im;
    }
}

// ---- K7: scan over L, fused collapsed mix/proj ----
__global__ void k_scan(float* __restrict__ ws){
    __shared__ float wv[66];
    int tid = threadIdx.x;
    if (tid < 66) wv[tid] = ws[OFF_WVEC + tid];
    __syncthreads();
    int t = blockIdx.x*256 + tid;
    if (t >= CC*HH*WF) return;
    int f = t % WF;
    int c = t / (HH*WF);
    float sre[RR], sim[RR];
    #pragma unroll
    for (int r=0;r<RR;r++){ sre[r]=0.f; sim[r]=0.f; }
    for (int l=0;l<LL;l++){
        int base = ((l*CC+c)*WF+f)*RR;
        const float4* A4 = reinterpret_cast<const float4*>(ws + OFF_ARE + base);
        const float4* I4 = reinterpret_cast<const float4*>(ws + OFF_AIM + base);
        const float4* S4 = reinterpret_cast<const float4*>(ws + OFF_SGG + base);
        float ar[RR], ai[RR], sg[RR];
        #pragma unroll
        for (int q=0;q<4;q++){
            float4 a = A4[q], bb = I4[q], s = S4[q];
            ar[4*q]=a.x; ar[4*q+1]=a.y; ar[4*q+2]=a.z; ar[4*q+3]=a.w;
            ai[4*q]=bb.x; ai[4*q+1]=bb.y; ai[4*q+2]=bb.z; ai[4*q+3]=bb.w;
            sg[4*q]=s.x; sg[4*q+1]=s.y; sg[4*q+2]=s.z; sg[4*q+3]=s.w;
        }
        float xr = ws[OFF_XFR + l*(CC*HH*WF) + t];
        float xi = ws[OFF_XFI + l*(CC*HH*WF) + t];
        float yr = wv[64], yi = wv[65];
        #pragma unroll
        for (int r=0;r<RR;r++){
            float nre = ar[r]*sre[r] - ai[r]*sim[r] + sg[r]*xr;
            float nim = ar[r]*sim[r] + ai[r]*sre[r] + sg[r]*xi;
            sre[r]=nre; sim[r]=nim;
            yr += wv[r]*nre + wv[16+r]*nim;
            yi += wv[32+r]*nre + wv[48+r]*nim;
        }
        ws[OFF_YFR + l*(CC*HH*WF) + t] = yr;
        ws[OFF_YFI + l*(CC*HH*WF) + t] = yi;
    }
}

// ---- K8: irfft ----
__global__ void k_irfft(float* __restrict__ ws){
    __shared__ float yr[HH][WF], yi[HH][WF];
    __shared__ float ct[64], st[64];
    int b = blockIdx.x; int l = b>>5, c = b&31;
    int tid = threadIdx.x;
    if (tid < 64){ float ang = 2.f*PI_F*(float)tid/64.f; ct[tid]=cosf(ang); st[tid]=sinf(ang); }
    const float* Yr = ws + OFF_YFR + (l*CC+c)*HH*WF;
    const float* Yi = ws + OFF_YFI + (l*CC+c)*HH*WF;
    for (int k=0;k<9;k++){
        int i = tid + k*256;
        if (i < HH*WF){ int h=i/WF, f=i-h*WF; yr[h][f]=Yr[i]; yi[h][f]=Yi[i]; }
    }
    __syncthreads();
    float* y1 = ws + OFF_Y1 + (l*CC+c)*HH*WW;
    for (int k=0;k<16;k++){
        int pix = tid + k*256;
        int h = pix>>6, w = pix&63;
        float acc = yr[h][0] + ((w&1)? -yr[h][32] : yr[h][32]);
        #pragma unroll
        for (int f=1;f<32;f++){
            int a = (f*w)&63;
            acc += 2.0f*(yr[h][f]*ct[a] - yi[h][f]*st[a]);
        }
        y1[pix] = acc*(1.0f/64.0f);
    }
}

// ---- K9: pif ----
__global__ void k_pif(const float* __restrict__ pw, const float* __restrict__ pb,
                      float* __restrict__ ws){
    __shared__ float row[CC][WW];
    int b = blockIdx.x; int l = b>>6, h = b&63;
    int tid = threadIdx.x;
    for (int k=0;k<8;k++){
        int i = tid + k*256;
        int ci = i>>6, w = i&63;
        row[ci][w] = ws[OFF_Y1 + ((l*CC+ci)*HH + h)*WW + w];
    }
    __syncthreads();
    for (int k=0;k<8;k++){
        int i = tid + k*256;
        int o = i>>6, w = i&63;
        float acc = pb[o];
        #pragma unroll
        for (int ci=0;ci<CC;ci++) acc += pw[o*CC+ci]*row[ci][w];
        ws[OFF_Y2 + ((l*CC+o)*HH + h)*WW + w] = acc;
    }
}

// ---- K10: GroupNorm stats ----
__global__ void k_gnstat(float* __restrict__ ws){
    __shared__ float rs[256], rq[256];
    int b = blockIdx.x; int l = b>>2, g = b&3;
    const float* z = ws + OFF_Y2 + (l*CC + g*8)*HH*WW;
    int tid = threadIdx.x;
    float s=0.f, q=0.f;
    for (int i=tid;i<8*HH*WW;i+=256){ float v=z[i]; s+=v; q+=v*v; }
    rs[tid]=s; rq[tid]=q; __syncthreads();
    for (int off=128; off>0; off>>=1){
        if (tid<off){ rs[tid]+=rs[tid+off]; rq[tid]+=rq[tid+off]; }
        __syncthreads();
    }
    if (tid==0){
        float mean = rs[0]/32768.0f;
        float var = rq[0]/32768.0f - mean*mean;
        ws[OFF_GNM + b] = mean;
        ws[OFF_GNR + b] = rsqrtf(var + 1e-5f);
    }
}

// ---- K11: normalize + W-mean ----
__global__ void k_normym(const float* __restrict__ gn_w, const float* __restrict__ gn_b,
                         float* __restrict__ ws){
    int b = blockIdx.x; int l = b>>5, c = b&31;
    int tid = threadIdx.x;
    int g = c>>3;
    float mu = ws[OFF_GNM + l*4+g], rstd = ws[OFF_GNR + l*4+g];
    float gw = gn_w[c], gb = gn_b[c];
    float* z = ws + OFF_Y2 + (l*CC+c)*HH*WW;
    int w = tid&63, hs = tid>>6;
    for (int k=0;k<16;k++){
        int h = hs*16 + k;
        int i = h*WW + w;
        float v = (z[i]-mu)*rstd*gw + gb;
        z[i] = v;
        float s = v;
        for (int off=32; off>0; off>>=1) s += __shfl_down(s, off, 64);
        if ((tid&63)==0) ws[OFF_YM + (l*HH+h)*CC + c] = s*(1.0f/64.0f);
    }
}

// ---- K12: gate MLP ----
__global__ void k_gate(const float* __restrict__ g1w, const float* __restrict__ g1b,
                       const float* __restrict__ g2w, const float* __restrict__ g2b,
                       float* __restrict__ ws){
    int t = blockIdx.x*256 + threadIdx.x;
    if (t >= LL*HH*CC) return;
    int c = t & 31, h = (t>>5)&63, l = t>>11;
    const float* ym = ws + OFF_YM + (l*HH+h)*CC;
    float mid[4];
    #pragma unroll
    for (int m=0;m<4;m++){
        float a = g1b[m];
        for (int i=0;i<CC;i++) a += ym[i]*g1w[m*CC+i];
        mid[m] = a*sigmoidf_(a);
    }
    float a = g2b[c];
    #pragma unroll
    for (int m=0;m<4;m++) a += mid[m]*g2w[c*4+m];
    ws[OFF_GATE + t] = sigmoidf_(a);
}

// ---- K13: residual ----
__global__ void k_final(const float* __restrict__ x, float* __restrict__ out,
                        const float* __restrict__ ws){
    int t = blockIdx.x*256 + threadIdx.x;
    int w = t&63, h = (t>>6)&63, l = (t>>12)&15, c = t>>16;
    float z = ws[OFF_Y2 + ((l*CC+c)*HH+h)*WW + w];
    float gt = ws[OFF_GATE + (l*HH+h)*CC + c];
    out[t] = x[t] + z*gt;
}

extern "C" void kernel_launch(void* const* d_in, const int* in_sizes, int n_in,
                              void* d_out, int out_size, void* d_ws, size_t ws_size,
                              hipStream_t stream){
    const float* x    = (const float*)d_in[0];
    const float* dt   = (const float*)d_in[1];
    const float* c1w  = (const float*)d_in[2];
    const float* c1b  = (const float*)d_in[3];
    const float* c2w  = (const float*)d_in[4];
    const float* c2b  = (const float*)d_in[5];
    const float* gfcw = (const float*)d_in[6];
    const float* gfcb = (const float*)d_in[7];
    const float* hw   = (const float*)d_in[8];
    const float* hb   = (const float*)d_in[9];
    const float* mixw = (const float*)d_in[10];
    const float* mixb = (const float*)d_in[11];
    const float* rs   = (const float*)d_in[12];
    const float* pjw  = (const float*)d_in[13];
    const float* pjb  = (const float*)d_in[14];
    const float* pifw = (const float*)d_in[15];
    const float* pifb = (const float*)d_in[16];
    const float* gnw  = (const float*)d_in[17];
    const float* gnb  = (const float*)d_in[18];
    const float* g1w  = (const float*)d_in[19];
    const float* g1b  = (const float*)d_in[20];
    const float* g2w  = (const float*)d_in[21];
    const float* g2b  = (const float*)d_in[22];
    float* ws  = (float*)d_ws;
    float* out = (float*)d_out;

    k_prep  <<<1,    64,  0, stream>>>(mixw, mixb, rs, pjw, pjb, ws);
    k_wprep <<<72,   256, 0, stream>>>(c1w, c2w, ws);
    hipMemsetAsync((void*)(ws + OFF_COLSUM), 0, 32768*sizeof(float), stream);
    // conv1: src = x, layout [C][L][H][W]
    k_conv<0><<<512, 256, 0, stream>>>(x, (long)LL*HH*WW, (long)HH*WW, ws + OFF_WT, c1b, ws);
    // conv2: src = f1 in ws, layout [L][C][H][W]
    k_conv<1><<<512, 256, 0, stream>>>(ws + OFF_F1, (long)HH*WW, (long)CC*HH*WW, ws + OFF_WT + 9216, c2b, ws);
    k_glob  <<<16,   64,  0, stream>>>(gfcw, gfcb, ws);
    k_feat  <<<66,   256, 0, stream>>>(ws);
    k_head  <<<1056, 256, 0, stream>>>(hw, hb, dt, ws);
    k_rfft  <<<512,  256, 0, stream>>>(x, ws);
    k_scan  <<<264,  256, 0, stream>>>(ws);
    k_irfft <<<512,  256, 0, stream>>>(ws);
    k_pif   <<<1024, 256, 0, stream>>>(pifw, pifb, ws);
    k_gnstat<<<64,   256, 0, stream>>>(ws);
    k_normym<<<512,  256, 0, stream>>>(gnw, gnb, ws);
    k_gate  <<<128,  256, 0, stream>>>(g1w, g1b, g2w, g2b, ws);
    k_final <<<8192, 256, 0, stream>>>(x, out, ws);
}

// Round 5
// 367.199 us; speedup vs baseline: 3.1716x; 3.1716x over previous
//
#include <hip/hip_runtime.h>
#include <math.h>

#define CC 32
#define LL 16
#define HH 64
#define WW 64
#define WF 33
#define RR 16
#define PI_F 3.14159265358979323846f

// ---- workspace layout (floats). Regions reused across phases. ----
#define OFF_F1      0          // 2097152  f1 (conv1 out); later reused as Y2
#define OFF_COLSUM  2097152    // 32768    [l][c][w]
#define OFF_GLOB    2130432    // 512
#define OFF_FEAT    2130944    // 16896    [l][wf][c]
#define OFF_ARE     2147840    // 270336   [l][c][wf][r]
#define OFF_AIM     2418176    // 270336
#define OFF_SGG     2688512    // 270336
#define OFF_XFR     2958848    // 1081344  [l][c][h][f]
#define OFF_XFI     4040192    // 1081344
#define OFF_YFR     5121536    // 1081344
#define OFF_YFI     6202880    // 1081344
#define OFF_Y1      2958848    // 2097152  (overlaps dead XFR/XFI)
#define OFF_Y2      0          // 2097152  (overlaps dead F1)
#define OFF_GNM     7284224    // 64
#define OFF_GNR     7284288    // 64
#define OFF_YM      7284352    // 32768    [l][h][c]
#define OFF_GATE    7317120    // 32768
#define OFF_WVEC    7349888    // 66
#define OFF_WT      7350016    // 18432: transposed conv1 (9216) + conv2 (9216)
// total ~29.5 MB

__device__ __forceinline__ float sigmoidf_(float x){ return 1.0f/(1.0f+expf(-x)); }

// ---- K0: collapse mix/rank_scale/proj into two 32-vectors ----
__global__ void k_prep(const float* __restrict__ mix_w, const float* __restrict__ mix_b,
                       const float* __restrict__ rank_scale, const float* __restrict__ proj_w,
                       const float* __restrict__ proj_b, float* __restrict__ ws){
    float* wv = ws + OFF_WVEC;
    int t = threadIdx.x;
    if (t < 32){
        float sre=0.f, sim=0.f;
        for (int r=0;r<RR;r++){
            float a = proj_w[r]*rank_scale[r];
            sre += a*mix_w[r*2*RR + t];
            sim += a*mix_w[(RR+r)*2*RR + t];
        }
        wv[t] = sre;
        wv[32+t] = sim;
    }
    if (t == 0){
        float cre=0.f, cim=0.f;
        for (int r=0;r<RR;r++){
            float a = proj_w[r]*rank_scale[r];
            cre += a*mix_b[r];
            cim += a*mix_b[RR+r];
        }
        wv[64] = cre + proj_b[0];
        wv[65] = cim;
    }
}

// ---- K0b: pre-transpose conv weights OIHW -> [tap][co] (tap = ci*9+kh*3+kw) ----
__global__ void k_wprep(const float* __restrict__ c1w, const float* __restrict__ c2w,
                        float* __restrict__ ws){
    int i = blockIdx.x*256 + threadIdx.x;
    if (i >= 2*9216) return;
    int which = (i >= 9216);
    int j = which ? i - 9216 : i;
    int tap = j >> 5, co = j & 31;
    const float* cw = which ? c2w : c1w;
    ws[OFF_WT + i] = cw[co*288 + tap];
}

// ---- K1/K2: 3x3 SAME conv (32->32) + SiLU.
// Whole 32-ci input tile staged once (one barrier), weights staged as a
// LINEAR copy from pre-transposed wT (zero bank conflicts). No reg-held
// prefetch arrays across barriers (R3's spill lesson).
// Block = (l, h-tile of 2 rows). 256 thr = 16 wq(4w) x 2 row x 8 cg(4co).
template<int MODE>
__global__ __launch_bounds__(256, 2) void k_conv(const float* __restrict__ src,
                                                 long ci_stride, long l_stride,
                                                 const float* __restrict__ wT,
                                                 const float* __restrict__ cb,
                                                 float* __restrict__ ws){
    __shared__ float xs[CC][4][66];     // 33 KB: all 32 ci, rows h0-1..h0+2, halo cols
    __shared__ float lw[9216];          // 36 KB: [tap][co]
    __shared__ float red[MODE ? CC*WW : 1];

    const int tid = threadIdx.x;
    const int l   = blockIdx.x >> 5;
    const int h0  = (blockIdx.x & 31)*2;

    const int wq  = tid & 15;
    const int row = (tid >> 4) & 1;
    const int cg  = tid >> 5;
    const int w0  = wq*4;
    const int co0 = cg*4;

    // linear weight stage: coalesced read, conflict-free write
    #pragma unroll 6
    for (int j = 0; j < 36; ++j) lw[tid + j*256] = wT[tid + j*256];
    if (MODE){
        #pragma unroll
        for (int i = tid; i < CC*WW; i += 256) red[i] = 0.f;
    }
    // zero halo columns: 32ci x 4rows x 2 = 256 entries, one per thread
    xs[tid>>3][(tid>>1)&3][(tid&1) ? 65 : 0] = 0.f;

    // input stage: per thread rr/w fixed, loop over ci (i>>8 == j exactly)
    const int rr = (tid >> 6) & 3;
    const int w  = tid & 63;
    const int h  = h0 - 1 + rr;
    const bool hv = (h >= 0 && h < HH);
    const float* sbase = src + (long)l*l_stride + (hv ? h*WW + w : 0);
    #pragma unroll 8
    for (int j = 0; j < 32; ++j){
        xs[j][rr][1+w] = hv ? sbase[(long)j*ci_stride] : 0.f;
    }
    __syncthreads();

    float acc[4][4];
    #pragma unroll
    for (int i=0;i<4;i++)
        #pragma unroll
        for (int j=0;j<4;j++) acc[i][j]=0.f;

    #pragma unroll 2
    for (int cil = 0; cil < CC; ++cil){
        #pragma unroll
        for (int kh = 0; kh < 3; ++kh){
            const float* xr = &xs[cil][row+kh][w0];   // [w0-1+j] -> xr[j]
            float xv0=xr[0],xv1=xr[1],xv2=xr[2],xv3=xr[3],xv4=xr[4],xv5=xr[5];
            const float* wp = &lw[(cil*9 + kh*3)*32 + co0];
            #pragma unroll
            for (int kw = 0; kw < 3; ++kw){
                float4 wa = *(const float4*)(wp + kw*32);
                float x0 = (kw==0)?xv0:((kw==1)?xv1:xv2);
                float x1 = (kw==0)?xv1:((kw==1)?xv2:xv3);
                float x2 = (kw==0)?xv2:((kw==1)?xv3:xv4);
                float x3 = (kw==0)?xv3:((kw==1)?xv4:xv5);
                acc[0][0] += x0*wa.x; acc[0][1] += x1*wa.x; acc[0][2] += x2*wa.x; acc[0][3] += x3*wa.x;
                acc[1][0] += x0*wa.y; acc[1][1] += x1*wa.y; acc[1][2] += x2*wa.y; acc[1][3] += x3*wa.y;
                acc[2][0] += x0*wa.z; acc[2][1] += x1*wa.z; acc[2][2] += x2*wa.z; acc[2][3] += x3*wa.z;
                acc[3][0] += x0*wa.w; acc[3][1] += x1*wa.w; acc[3][2] += x2*wa.w; acc[3][3] += x3*wa.w;
            }
        }
    }

    if (MODE == 0){
        const int hh2 = h0 + row;
        float* dst = ws + OFF_F1 + (((long)l*CC)*HH + hh2)*WW + w0;
        #pragma unroll
        for (int i = 0; i < 4; ++i){
            float bias = cb[co0+i];
            float4 o;
            float a0 = acc[i][0]+bias, a1 = acc[i][1]+bias, a2 = acc[i][2]+bias, a3 = acc[i][3]+bias;
            o.x = a0*sigmoidf_(a0); o.y = a1*sigmoidf_(a1);
            o.z = a2*sigmoidf_(a2); o.w = a3*sigmoidf_(a3);
            *(float4*)(dst + (long)(co0+i)*HH*WW) = o;
        }
    } else {
        __syncthreads();
        #pragma unroll
        for (int i = 0; i < 4; ++i){
            float bias = cb[co0+i];
            #pragma unroll
            for (int j = 0; j < 4; ++j){
                float a = acc[i][j] + bias;
                a = a*sigmoidf_(a);
                a += __shfl_xor(a, 16, 64);   // row0+row1 pair
                if (row == 0) atomicAdd(&red[(co0+i)*WW + w0 + j], a);
            }
        }
        __syncthreads();
        int co = tid >> 3, wseg = (tid & 7)*8;
        #pragma unroll
        for (int j = 0; j < 8; ++j){
            float v = red[co*WW + wseg + j];
            atomicAdd(&ws[OFF_COLSUM + (l*CC+co)*WW + wseg + j], v);
        }
    }
}

// ---- K3: glob (gsum derived from colsum) ----
__global__ void k_glob(const float* __restrict__ gfc_w, const float* __restrict__ gfc_b,
                       float* __restrict__ ws){
    __shared__ float gs[CC];
    int l = blockIdx.x;
    int tid = threadIdx.x;
    if (tid < 32){
        const float* cs = ws + OFF_COLSUM + (l*CC+tid)*WW;
        float s = 0.f;
        for (int w=0;w<WW;w++) s += cs[w];
        gs[tid] = s;
    }
    __syncthreads();
    if (tid < 32){
        float acc = gfc_b[tid];
        for (int i=0;i<CC;i++) acc += gs[i]*(1.0f/4096.0f)*gfc_w[tid*CC+i];
        ws[OFF_GLOB + l*CC + tid] = sigmoidf_(acc);
    }
}

// ---- K4: adaptive pool * glob ----
__global__ void k_feat(float* __restrict__ ws){
    int t = blockIdx.x*blockDim.x + threadIdx.x;
    if (t >= LL*WF*CC) return;
    int c = t & 31;
    int lw_ = t >> 5;
    int wf = lw_ % WF, l = lw_ / WF;
    int s = (wf*64)/33;
    int e = ((wf+1)*64 + 32)/33;
    const float* cs = ws + OFF_COLSUM + (l*CC+c)*WW;
    float sum = 0.f;
    for (int w=s;w<e;w++) sum += cs[w];
    ws[OFF_FEAT + (l*WF+wf)*CC + c] = ws[OFF_GLOB + l*CC + c] * sum / (64.0f*(float)(e-s));
}

// ---- K5: head ----
__global__ void k_head(const float* __restrict__ hw, const float* __restrict__ hb,
                       const float* __restrict__ dt, float* __restrict__ ws){
    int t = blockIdx.x*blockDim.x + threadIdx.x;
    if (t >= LL*WF*CC*RR) return;
    int r = t & 15, c = (t>>4) & 31;
    int lw_ = t >> 9;
    int wf = lw_ % WF, l = lw_ / WF;
    const float* feat = ws + OFF_FEAT + (l*WF+wf)*CC;
    int j0 = (c*RR + r)*3;
    const float* w0 = hw + j0*CC;
    float p0=hb[j0], p1=hb[j0+1], p2=hb[j0+2];
    for (int i=0;i<CC;i++){
        float fv = feat[i];
        p0 += fv*w0[i]; p1 += fv*w0[CC+i]; p2 += fv*w0[2*CC+i];
    }
    float nu = fmaxf(p0,0.f) + log1pf(expf(-fabsf(p0)));
    float th = tanhf(p1)*PI_F;
    float sg = sigmoidf_(p2);
    float dtv = dt[l];
    float decay = expf(-nu*dtv);
    float ang = th*dtv;
    float g = 1.0f - expf(-2.0f*fmaxf(dtv,0.f));
    int idx = ((l*CC+c)*WF+wf)*RR + r;
    ws[OFF_ARE+idx] = decay*cosf(ang);
    ws[OFF_AIM+idx] = decay*sinf(ang);
    ws[OFF_SGG+idx] = sg*g;
}

// ---- K6: rfft over W (direct DFT). Block = (l,c). ----
__global__ void k_rfft(const float* __restrict__ x, float* __restrict__ ws){
    __shared__ float plane[HH][WW+1];
    __shared__ float ct[64], st[64];
    int b = blockIdx.x; int l = b >> 5, c = b & 31;
    int tid = threadIdx.x;
    if (tid < 64){
        float ang = 2.0f*PI_F*(float)tid/64.0f;
        ct[tid] = cosf(ang); st[tid] = sinf(ang);
    }
    const float* xp = x + (c*LL + l)*HH*WW;
    for (int k=0;k<16;k++){
        int pix = tid + k*256;
        plane[pix>>6][pix&63] = xp[pix];
    }
    __syncthreads();
    float* xfr = ws + OFF_XFR + (l*CC + c)*HH*WF;
    float* xfi = ws + OFF_XFI + (l*CC + c)*HH*WF;
    for (int k=0;k<9;k++){
        int oi = tid + k*256;
        if (oi >= HH*WF) break;
        int h = oi/WF, f = oi - h*WF;
        float re=0.f, im=0.f;
        int idx = 0;
        for (int w=0;w<WW;w++){
            float v = plane[h][w];
            re += v*ct[idx]; im -= v*st[idx];
            idx = (idx + f) & 63;
        }
        xfr[oi] = re; xfi[oi] = im;
    }
}

// ---- K7: scan over L, fused collapsed mix/proj ----
__global__ void k_scan(float* __restrict__ ws){
    __shared__ float wv[66];
    int tid = threadIdx.x;
    if (tid < 66) wv[tid] = ws[OFF_WVEC + tid];
    __syncthreads();
    int t = blockIdx.x*256 + tid;
    if (t >= CC*HH*WF) return;
    int f = t % WF;
    int c = t / (HH*WF);
    float sre[RR], sim[RR];
    #pragma unroll
    for (int r=0;r<RR;r++){ sre[r]=0.f; sim[r]=0.f; }
    for (int l=0;l<LL;l++){
        int base = ((l*CC+c)*WF+f)*RR;
        const float4* A4 = reinterpret_cast<const float4*>(ws + OFF_ARE + base);
        const float4* I4 = reinterpret_cast<const float4*>(ws + OFF_AIM + base);
        const float4* S4 = reinterpret_cast<const float4*>(ws + OFF_SGG + base);
        float ar[RR], ai[RR], sg[RR];
        #pragma unroll
        for (int q=0;q<4;q++){
            float4 a = A4[q], bb = I4[q], s = S4[q];
            ar[4*q]=a.x; ar[4*q+1]=a.y; ar[4*q+2]=a.z; ar[4*q+3]=a.w;
            ai[4*q]=bb.x; ai[4*q+1]=bb.y; ai[4*q+2]=bb.z; ai[4*q+3]=bb.w;
            sg[4*q]=s.x; sg[4*q+1]=s.y; sg[4*q+2]=s.z; sg[4*q+3]=s.w;
        }
        float xr = ws[OFF_XFR + l*(CC*HH*WF) + t];
        float xi = ws[OFF_XFI + l*(CC*HH*WF) + t];
        float yr = wv[64], yi = wv[65];
        #pragma unroll
        for (int r=0;r<RR;r++){
            float nre = ar[r]*sre[r] - ai[r]*sim[r] + sg[r]*xr;
            float nim = ar[r]*sim[r] + ai[r]*sre[r] + sg[r]*xi;
            sre[r]=nre; sim[r]=nim;
            yr += wv[r]*nre + wv[16+r]*nim;
            yi += wv[32+r]*nre + wv[48+r]*nim;
        }
        ws[OFF_YFR + l*(CC*HH*WF) + t] = yr;
        ws[OFF_YFI + l*(CC*HH*WF) + t] = yi;
    }
}

// ---- K8: irfft ----
__global__ void k_irfft(float* __restrict__ ws){
    __shared__ float yr[HH][WF], yi[HH][WF];
    __shared__ float ct[64], st[64];
    int b = blockIdx.x; int l = b>>5, c = b&31;
    int tid = threadIdx.x;
    if (tid < 64){ float ang = 2.f*PI_F*(float)tid/64.f; ct[tid]=cosf(ang); st[tid]=sinf(ang); }
    const float* Yr = ws + OFF_YFR + (l*CC+c)*HH*WF;
    const float* Yi = ws + OFF_YFI + (l*CC+c)*HH*WF;
    for (int k=0;k<9;k++){
        int i = tid + k*256;
        if (i < HH*WF){ int h=i/WF, f=i-h*WF; yr[h][f]=Yr[i]; yi[h][f]=Yi[i]; }
    }
    __syncthreads();
    float* y1 = ws + OFF_Y1 + (l*CC+c)*HH*WW;
    for (int k=0;k<16;k++){
        int pix = tid + k*256;
        int h = pix>>6, w = pix&63;
        float acc = yr[h][0] + ((w&1)? -yr[h][32] : yr[h][32]);
        #pragma unroll
        for (int f=1;f<32;f++){
            int a = (f*w)&63;
            acc += 2.0f*(yr[h][f]*ct[a] - yi[h][f]*st[a]);
        }
        y1[pix] = acc*(1.0f/64.0f);
    }
}

// ---- K9: pif ----
__global__ void k_pif(const float* __restrict__ pw, const float* __restrict__ pb,
                      float* __restrict__ ws){
    __shared__ float row[CC][WW];
    int b = blockIdx.x; int l = b>>6, h = b&63;
    int tid = threadIdx.x;
    for (int k=0;k<8;k++){
        int i = tid + k*256;
        int ci = i>>6, w = i&63;
        row[ci][w] = ws[OFF_Y1 + ((l*CC+ci)*HH + h)*WW + w];
    }
    __syncthreads();
    for (int k=0;k<8;k++){
        int i = tid + k*256;
        int o = i>>6, w = i&63;
        float acc = pb[o];
        #pragma unroll
        for (int ci=0;ci<CC;ci++) acc += pw[o*CC+ci]*row[ci][w];
        ws[OFF_Y2 + ((l*CC+o)*HH + h)*WW + w] = acc;
    }
}

// ---- K10: GroupNorm stats ----
__global__ void k_gnstat(float* __restrict__ ws){
    __shared__ float rs[256], rq[256];
    int b = blockIdx.x; int l = b>>2, g = b&3;
    const float* z = ws + OFF_Y2 + (l*CC + g*8)*HH*WW;
    int tid = threadIdx.x;
    float s=0.f, q=0.f;
    for (int i=tid;i<8*HH*WW;i+=256){ float v=z[i]; s+=v; q+=v*v; }
    rs[tid]=s; rq[tid]=q; __syncthreads();
    for (int off=128; off>0; off>>=1){
        if (tid<off){ rs[tid]+=rs[tid+off]; rq[tid]+=rq[tid+off]; }
        __syncthreads();
    }
    if (tid==0){
        float mean = rs[0]/32768.0f;
        float var = rq[0]/32768.0f - mean*mean;
        ws[OFF_GNM + b] = mean;
        ws[OFF_GNR + b] = rsqrtf(var + 1e-5f);
    }
}

// ---- K11: normalize + W-mean ----
__global__ void k_normym(const float* __restrict__ gn_w, const float* __restrict__ gn_b,
                         float* __restrict__ ws){
    int b = blockIdx.x; int l = b>>5, c = b&31;
    int tid = threadIdx.x;
    int g = c>>3;
    float mu = ws[OFF_GNM + l*4+g], rstd = ws[OFF_GNR + l*4+g];
    float gw = gn_w[c], gb = gn_b[c];
    float* z = ws + OFF_Y2 + (l*CC+c)*HH*WW;
    int w = tid&63, hs = tid>>6;
    for (int k=0;k<16;k++){
        int h = hs*16 + k;
        int i = h*WW + w;
        float v = (z[i]-mu)*rstd*gw + gb;
        z[i] = v;
        float s = v;
        for (int off=32; off>0; off>>=1) s += __shfl_down(s, off, 64);
        if ((tid&63)==0) ws[OFF_YM + (l*HH+h)*CC + c] = s*(1.0f/64.0f);
    }
}

// ---- K12: gate MLP ----
__global__ void k_gate(const float* __restrict__ g1w, const float* __restrict__ g1b,
                       const float* __restrict__ g2w, const float* __restrict__ g2b,
                       float* __restrict__ ws){
    int t = blockIdx.x*256 + threadIdx.x;
    if (t >= LL*HH*CC) return;
    int c = t & 31, h = (t>>5)&63, l = t>>11;
    const float* ym = ws + OFF_YM + (l*HH+h)*CC;
    float mid[4];
    #pragma unroll
    for (int m=0;m<4;m++){
        float a = g1b[m];
        for (int i=0;i<CC;i++) a += ym[i]*g1w[m*CC+i];
        mid[m] = a*sigmoidf_(a);
    }
    float a = g2b[c];
    #pragma unroll
    for (int m=0;m<4;m++) a += mid[m]*g2w[c*4+m];
    ws[OFF_GATE + t] = sigmoidf_(a);
}

// ---- K13: residual (float4) ----
__global__ void k_final(const float* __restrict__ x, float* __restrict__ out,
                        const float* __restrict__ ws){
    int t = blockIdx.x*256 + threadIdx.x;   // quad index
    int n = t*4;
    int h = (n>>6)&63, l = (n>>12)&15, c = n>>16;
    float4 z  = *(const float4*)(ws + OFF_Y2 + (((l*CC+c)*HH+h)*WW) + (n&63));
    float  gt = ws[OFF_GATE + (l*HH+h)*CC + c];
    float4 xv = *(const float4*)(x + n);
    float4 o;
    o.x = xv.x + z.x*gt; o.y = xv.y + z.y*gt;
    o.z = xv.z + z.z*gt; o.w = xv.w + z.w*gt;
    *(float4*)(out + n) = o;
}

extern "C" void kernel_launch(void* const* d_in, const int* in_sizes, int n_in,
                              void* d_out, int out_size, void* d_ws, size_t ws_size,
                              hipStream_t stream){
    const float* x    = (const float*)d_in[0];
    const float* dt   = (const float*)d_in[1];
    const float* c1w  = (const float*)d_in[2];
    const float* c1b  = (const float*)d_in[3];
    const float* c2w  = (const float*)d_in[4];
    const float* c2b  = (const float*)d_in[5];
    const float* gfcw = (const float*)d_in[6];
    const float* gfcb = (const float*)d_in[7];
    const float* hw   = (const float*)d_in[8];
    const float* hb   = (const float*)d_in[9];
    const float* mixw = (const float*)d_in[10];
    const float* mixb = (const float*)d_in[11];
    const float* rs   = (const float*)d_in[12];
    const float* pjw  = (const float*)d_in[13];
    const float* pjb  = (const float*)d_in[14];
    const float* pifw = (const float*)d_in[15];
    const float* pifb = (const float*)d_in[16];
    const float* gnw  = (const float*)d_in[17];
    const float* gnb  = (const float*)d_in[18];
    const float* g1w  = (const float*)d_in[19];
    const float* g1b  = (const float*)d_in[20];
    const float* g2w  = (const float*)d_in[21];
    const float* g2b  = (const float*)d_in[22];
    float* ws  = (float*)d_ws;
    float* out = (float*)d_out;

    k_prep  <<<1,    64,  0, stream>>>(mixw, mixb, rs, pjw, pjb, ws);
    k_wprep <<<72,   256, 0, stream>>>(c1w, c2w, ws);
    hipMemsetAsync((void*)(ws + OFF_COLSUM), 0, 32768*sizeof(float), stream);
    // conv1: src = x, layout [C][L][H][W]
    k_conv<0><<<512, 256, 0, stream>>>(x, (long)LL*HH*WW, (long)HH*WW, ws + OFF_WT, c1b, ws);
    // conv2: src = f1 in ws, layout [L][C][H][W]
    k_conv<1><<<512, 256, 0, stream>>>(ws + OFF_F1, (long)HH*WW, (long)CC*HH*WW, ws + OFF_WT + 9216, c2b, ws);
    k_glob  <<<16,   64,  0, stream>>>(gfcw, gfcb, ws);
    k_feat  <<<66,   256, 0, stream>>>(ws);
    k_head  <<<1056, 256, 0, stream>>>(hw, hb, dt, ws);
    k_rfft  <<<512,  256, 0, stream>>>(x, ws);
    k_scan  <<<264,  256, 0, stream>>>(ws);
    k_irfft <<<512,  256, 0, stream>>>(ws);
    k_pif   <<<1024, 256, 0, stream>>>(pifw, pifb, ws);
    k_gnstat<<<64,   256, 0, stream>>>(ws);
    k_normym<<<512,  256, 0, stream>>>(gnw, gnb, ws);
    k_gate  <<<128,  256, 0, stream>>>(g1w, g1b, g2w, g2b, ws);
    k_final <<<2048, 256, 0, stream>>>(x, out, ws);
}

// Round 6
// 365.370 us; speedup vs baseline: 3.1875x; 1.0050x over previous
//
#include <hip/hip_runtime.h>
#include <hip/hip_bf16.h>
#include <math.h>

#define CC 32
#define LL 16
#define HH 64
#define WW 64
#define WF 33
#define RR 16
#define PI_F 3.14159265358979323846f

typedef __attribute__((ext_vector_type(8))) short short8;
typedef __attribute__((ext_vector_type(4))) float f32x4;

// ---- workspace layout (floats). Regions reused across phases. ----
#define OFF_F1      0          // f1 packed bf16 [l][h][w][ci] (2M ushort = 4MB); later reused as Y2 (fp32)
#define OFF_COLSUM  2097152    // 32768    [l][c][w]
#define OFF_GLOB    2130432    // 512
#define OFF_FEAT    2130944    // 16896    [l][wf][c]
#define OFF_ARE     2147840    // 270336   [l][c][wf][r]
#define OFF_AIM     2418176    // 270336
#define OFF_SGG     2688512    // 270336
#define OFF_XFR     2958848    // 1081344  [l][c][h][f]
#define OFF_XFI     4040192    // 1081344
#define OFF_YFR     5121536    // 1081344
#define OFF_YFI     6202880    // 1081344
#define OFF_Y1      2958848    // 2097152  (overlaps dead XFR/XFI)
#define OFF_Y2      0          // 2097152  (overlaps dead F1)
#define OFF_GNM     7284224    // 64
#define OFF_GNR     7284288    // 64
#define OFF_YM      7284352    // 32768    [l][h][c]
#define OFF_GATE    7317120    // 32768
#define OFF_WVEC    7349888    // 66
#define OFF_WT      7350016    // 18432 ushort = 9216 floats region (bf16-packed conv weights)
// total ~29.5 MB

__device__ __forceinline__ float sigmoidf_(float x){ return 1.0f/(1.0f+expf(-x)); }
__device__ __forceinline__ unsigned short f2bf(float v){
    __hip_bfloat16 b = __float2bfloat16(v);
    return *reinterpret_cast<unsigned short*>(&b);
}

// ---- K0: collapse mix/rank_scale/proj into two 32-vectors ----
__global__ void k_prep(const float* __restrict__ mix_w, const float* __restrict__ mix_b,
                       const float* __restrict__ rank_scale, const float* __restrict__ proj_w,
                       const float* __restrict__ proj_b, float* __restrict__ ws){
    float* wv = ws + OFF_WVEC;
    int t = threadIdx.x;
    if (t < 32){
        float sre=0.f, sim=0.f;
        for (int r=0;r<RR;r++){
            float a = proj_w[r]*rank_scale[r];
            sre += a*mix_w[r*2*RR + t];
            sim += a*mix_w[(RR+r)*2*RR + t];
        }
        wv[t] = sre;
        wv[32+t] = sim;
    }
    if (t == 0){
        float cre=0.f, cim=0.f;
        for (int r=0;r<RR;r++){
            float a = proj_w[r]*rank_scale[r];
            cre += a*mix_b[r];
            cim += a*mix_b[RR+r];
        }
        wv[64] = cre + proj_b[0];
        wv[65] = cim;
    }
}

// ---- K0b: pack conv weights into MFMA A-fragment lane order, bf16.
// idx = tap*1024 + ct*512 + lane*8 + j ; co = ct*16 + (lane&15); ci = (lane>>4)*8 + j
__global__ void k_wprep(const float* __restrict__ c1w, const float* __restrict__ c2w,
                        float* __restrict__ ws){
    int i = blockIdx.x*256 + threadIdx.x;
    if (i >= 2*9216) return;
    int which = (i >= 9216);
    int j = which ? i - 9216 : i;
    int je   = j & 7;
    int lane = (j >> 3) & 63;
    int ct   = (j >> 9) & 1;
    int tap  = j >> 10;             // 0..8 = kh*3+kw
    int kh = tap/3, kw = tap - kh*3;
    int co = ct*16 + (lane & 15);
    int ci = (lane >> 4)*8 + je;
    const float* cw = which ? c2w : c1w;
    float v = cw[((co*CC + ci)*3 + kh)*3 + kw];
    unsigned short* wt = (unsigned short*)(ws + OFF_WT);
    wt[i] = f2bf(v);
}

// ---- K1: conv1 (MFMA, bf16). Block = (l, h). Writes silu out as packed bf16
//      f1p[l][h][w][ci] with the 16B XOR swizzle-compatible linear layout. ----
__global__ __launch_bounds__(256, 4) void k_conv1m(const float* __restrict__ x,
                                                   const unsigned short* __restrict__ wt,
                                                   const float* __restrict__ cb,
                                                   unsigned short* __restrict__ f1p){
    __shared__ __align__(16) unsigned short xs[3*66*32];  // [row][wIdx][ci] bf16, swizzled
    __shared__ __align__(16) unsigned short pw[9216];     // packed weights

    const int tid  = threadIdx.x;
    const int l    = blockIdx.x >> 6;
    const int h    = blockIdx.x & 63;
    const int wid  = tid >> 6;
    const int lane = tid & 63;
    const int col  = lane & 15;
    const int kgrp = lane >> 4;

    // weights: linear copy (18432B = 4608 u32)
    {
        const unsigned int* src = (const unsigned int*)wt;
        unsigned int* dst = (unsigned int*)pw;
        #pragma unroll
        for (int j = 0; j < 18; ++j) dst[tid + j*256] = src[tid + j*256];
    }
    // input stage: rows h-1..h+1 as bf16, swizzled cib
    {
        const int rr = tid >> 6;       // 0..3 (3 = halo-zero crew)
        const int w  = tid & 63;
        if (rr < 3){
            int hh = h - 1 + rr;
            bool hv = (hh >= 0 && hh < HH);
            const float* sp = x + (long)l*HH*WW + hh*WW + w;   // + ci*LL*HH*WW
            int wIdx = 1 + w;
            #pragma unroll
            for (int cib = 0; cib < 4; ++cib){
                float v[8];
                #pragma unroll
                for (int k = 0; k < 8; ++k)
                    v[k] = hv ? sp[(long)(cib*8 + k)*LL*HH*WW] : 0.f;
                uint4 p;
                p.x = (unsigned)f2bf(v[0]) | ((unsigned)f2bf(v[1])<<16);
                p.y = (unsigned)f2bf(v[2]) | ((unsigned)f2bf(v[3])<<16);
                p.z = (unsigned)f2bf(v[4]) | ((unsigned)f2bf(v[5])<<16);
                p.w = (unsigned)f2bf(v[6]) | ((unsigned)f2bf(v[7])<<16);
                int cs = cib ^ (wIdx & 3);
                *(uint4*)&xs[(rr*66 + wIdx)*32 + cs*8] = p;
            }
        } else {
            int s = tid & 63;
            if (s < 24){
                int row = s >> 3, rest = s & 7;
                int wIdx = (rest >> 2) ? 65 : 0;
                int cib = rest & 3;
                *(uint4*)&xs[(row*66 + wIdx)*32 + cib*8] = make_uint4(0,0,0,0);
            }
        }
    }
    __syncthreads();

    #pragma unroll
    for (int u = 0; u < 2; ++u){
        int unit = wid + u*4;           // 0..7
        int ct   = unit >> 2;
        int wt16 = unit & 3;
        int colw = wt16*16 + col;       // output w
        f32x4 acc = {0.f,0.f,0.f,0.f};
        #pragma unroll
        for (int kh = 0; kh < 3; ++kh){
            #pragma unroll
            for (int kw = 0; kw < 3; ++kw){
                int wIdx = colw + kw;
                int cs = kgrp ^ (wIdx & 3);
                short8 b = *(const short8*)&xs[(kh*66 + wIdx)*32 + cs*8];
                short8 a = *(const short8*)&pw[((kh*3+kw)*2 + ct)*512 + lane*8];
                acc = __builtin_amdgcn_mfma_f32_16x16x32_bf16(a, b, acc, 0, 0, 0);
            }
        }
        int co0 = ct*16 + kgrp*4;
        float o[4];
        #pragma unroll
        for (int r = 0; r < 4; ++r){
            float v = acc[r] + cb[co0+r];
            o[r] = v * sigmoidf_(v);
        }
        uint2 pk;
        pk.x = (unsigned)f2bf(o[0]) | ((unsigned)f2bf(o[1])<<16);
        pk.y = (unsigned)f2bf(o[2]) | ((unsigned)f2bf(o[3])<<16);
        *(uint2*)&f1p[(((long)l*HH + h)*WW + colw)*32 + co0] = pk;
    }
}

// ---- K2: conv2 (MFMA, bf16) from packed f1p; reduces silu out to colsum ----
__global__ __launch_bounds__(256, 4) void k_conv2m(const unsigned short* __restrict__ f1p,
                                                   const unsigned short* __restrict__ wt,
                                                   const float* __restrict__ cb,
                                                   float* __restrict__ ws){
    __shared__ __align__(16) unsigned short xs[3*66*32];
    __shared__ __align__(16) unsigned short pw[9216];
    __shared__ float red[CC*WW];

    const int tid  = threadIdx.x;
    const int l    = blockIdx.x >> 6;
    const int h    = blockIdx.x & 63;
    const int wid  = tid >> 6;
    const int lane = tid & 63;
    const int col  = lane & 15;
    const int kgrp = lane >> 4;

    {
        const unsigned int* src = (const unsigned int*)wt;
        unsigned int* dst = (unsigned int*)pw;
        #pragma unroll
        for (int j = 0; j < 18; ++j) dst[tid + j*256] = src[tid + j*256];
    }
    #pragma unroll
    for (int i = tid; i < CC*WW; i += 256) red[i] = 0.f;
    {
        const int rr = tid >> 6;
        const int w  = tid & 63;
        if (rr < 3){
            int hh = h - 1 + rr;
            bool hv = (hh >= 0 && hh < HH);
            const uint4* sp = (const uint4*)&f1p[(((long)l*HH + hh)*WW + w)*32];
            int wIdx = 1 + w;
            #pragma unroll
            for (int cib = 0; cib < 4; ++cib){
                uint4 p = hv ? sp[cib] : make_uint4(0,0,0,0);
                int cs = cib ^ (wIdx & 3);
                *(uint4*)&xs[(rr*66 + wIdx)*32 + cs*8] = p;
            }
        } else {
            int s = tid & 63;
            if (s < 24){
                int row = s >> 3, rest = s & 7;
                int wIdx = (rest >> 2) ? 65 : 0;
                int cib = rest & 3;
                *(uint4*)&xs[(row*66 + wIdx)*32 + cib*8] = make_uint4(0,0,0,0);
            }
        }
    }
    __syncthreads();

    #pragma unroll
    for (int u = 0; u < 2; ++u){
        int unit = wid + u*4;
        int ct   = unit >> 2;
        int wt16 = unit & 3;
        int colw = wt16*16 + col;
        f32x4 acc = {0.f,0.f,0.f,0.f};
        #pragma unroll
        for (int kh = 0; kh < 3; ++kh){
            #pragma unroll
            for (int kw = 0; kw < 3; ++kw){
                int wIdx = colw + kw;
                int cs = kgrp ^ (wIdx & 3);
                short8 b = *(const short8*)&xs[(kh*66 + wIdx)*32 + cs*8];
                short8 a = *(const short8*)&pw[((kh*3+kw)*2 + ct)*512 + lane*8];
                acc = __builtin_amdgcn_mfma_f32_16x16x32_bf16(a, b, acc, 0, 0, 0);
            }
        }
        int co0 = ct*16 + kgrp*4;
        #pragma unroll
        for (int r = 0; r < 4; ++r){
            float v = acc[r] + cb[co0+r];
            v = v * sigmoidf_(v);
            atomicAdd(&red[(co0+r)*WW + colw], v);
        }
    }
    __syncthreads();
    int co = tid >> 3, wseg = (tid & 7)*8;
    #pragma unroll
    for (int j = 0; j < 8; ++j){
        float v = red[co*WW + wseg + j];
        atomicAdd(&ws[OFF_COLSUM + (l*CC+co)*WW + wseg + j], v);
    }
}

// ---- K3: glob (gsum derived from colsum) ----
__global__ void k_glob(const float* __restrict__ gfc_w, const float* __restrict__ gfc_b,
                       float* __restrict__ ws){
    __shared__ float gs[CC];
    int l = blockIdx.x;
    int tid = threadIdx.x;
    if (tid < 32){
        const float* cs = ws + OFF_COLSUM + (l*CC+tid)*WW;
        float s = 0.f;
        for (int w=0;w<WW;w++) s += cs[w];
        gs[tid] = s;
    }
    __syncthreads();
    if (tid < 32){
        float acc = gfc_b[tid];
        for (int i=0;i<CC;i++) acc += gs[i]*(1.0f/4096.0f)*gfc_w[tid*CC+i];
        ws[OFF_GLOB + l*CC + tid] = sigmoidf_(acc);
    }
}

// ---- K4: adaptive pool * glob ----
__global__ void k_feat(float* __restrict__ ws){
    int t = blockIdx.x*blockDim.x + threadIdx.x;
    if (t >= LL*WF*CC) return;
    int c = t & 31;
    int lw_ = t >> 5;
    int wf = lw_ % WF, l = lw_ / WF;
    int s = (wf*64)/33;
    int e = ((wf+1)*64 + 32)/33;
    const float* cs = ws + OFF_COLSUM + (l*CC+c)*WW;
    float sum = 0.f;
    for (int w=s;w<e;w++) sum += cs[w];
    ws[OFF_FEAT + (l*WF+wf)*CC + c] = ws[OFF_GLOB + l*CC + c] * sum / (64.0f*(float)(e-s));
}

// ---- K5: head ----
__global__ void k_head(const float* __restrict__ hw, const float* __restrict__ hb,
                       const float* __restrict__ dt, float* __restrict__ ws){
    int t = blockIdx.x*blockDim.x + threadIdx.x;
    if (t >= LL*WF*CC*RR) return;
    int r = t & 15, c = (t>>4) & 31;
    int lw_ = t >> 9;
    int wf = lw_ % WF, l = lw_ / WF;
    const float* feat = ws + OFF_FEAT + (l*WF+wf)*CC;
    int j0 = (c*RR + r)*3;
    const float* w0 = hw + j0*CC;
    float p0=hb[j0], p1=hb[j0+1], p2=hb[j0+2];
    for (int i=0;i<CC;i++){
        float fv = feat[i];
        p0 += fv*w0[i]; p1 += fv*w0[CC+i]; p2 += fv*w0[2*CC+i];
    }
    float nu = fmaxf(p0,0.f) + log1pf(expf(-fabsf(p0)));
    float th = tanhf(p1)*PI_F;
    float sg = sigmoidf_(p2);
    float dtv = dt[l];
    float decay = expf(-nu*dtv);
    float ang = th*dtv;
    float g = 1.0f - expf(-2.0f*fmaxf(dtv,0.f));
    int idx = ((l*CC+c)*WF+wf)*RR + r;
    ws[OFF_ARE+idx] = decay*cosf(ang);
    ws[OFF_AIM+idx] = decay*sinf(ang);
    ws[OFF_SGG+idx] = sg*g;
}

// ---- K6: rfft over W (direct DFT). Block = (l,c). ----
__global__ void k_rfft(const float* __restrict__ x, float* __restrict__ ws){
    __shared__ float plane[HH][WW+1];
    __shared__ float ct[64], st[64];
    int b = blockIdx.x; int l = b >> 5, c = b & 31;
    int tid = threadIdx.x;
    if (tid < 64){
        float ang = 2.0f*PI_F*(float)tid/64.0f;
        ct[tid] = cosf(ang); st[tid] = sinf(ang);
    }
    const float* xp = x + (c*LL + l)*HH*WW;
    for (int k=0;k<16;k++){
        int pix = tid + k*256;
        plane[pix>>6][pix&63] = xp[pix];
    }
    __syncthreads();
    float* xfr = ws + OFF_XFR + (l*CC + c)*HH*WF;
    float* xfi = ws + OFF_XFI + (l*CC + c)*HH*WF;
    for (int k=0;k<9;k++){
        int oi = tid + k*256;
        if (oi >= HH*WF) break;
        int h = oi/WF, f = oi - h*WF;
        float re=0.f, im=0.f;
        int idx = 0;
        for (int w=0;w<WW;w++){
            float v = plane[h][w];
            re += v*ct[idx]; im -= v*st[idx];
            idx = (idx + f) & 63;
        }
        xfr[oi] = re; xfi[oi] = im;
    }
}

// ---- K7: scan over L, fused collapsed mix/proj ----
__global__ void k_scan(float* __restrict__ ws){
    __shared__ float wv[66];
    int tid = threadIdx.x;
    if (tid < 66) wv[tid] = ws[OFF_WVEC + tid];
    __syncthreads();
    int t = blockIdx.x*256 + tid;
    if (t >= CC*HH*WF) return;
    int f = t % WF;
    int c = t / (HH*WF);
    float sre[RR], sim[RR];
    #pragma unroll
    for (int r=0;r<RR;r++){ sre[r]=0.f; sim[r]=0.f; }
    for (int l=0;l<LL;l++){
        int base = ((l*CC+c)*WF+f)*RR;
        const float4* A4 = reinterpret_cast<const float4*>(ws + OFF_ARE + base);
        const float4* I4 = reinterpret_cast<const float4*>(ws + OFF_AIM + base);
        const float4* S4 = reinterpret_cast<const float4*>(ws + OFF_SGG + base);
        float ar[RR], ai[RR], sg[RR];
        #pragma unroll
        for (int q=0;q<4;q++){
            float4 a = A4[q], bb = I4[q], s = S4[q];
            ar[4*q]=a.x; ar[4*q+1]=a.y; ar[4*q+2]=a.z; ar[4*q+3]=a.w;
            ai[4*q]=bb.x; ai[4*q+1]=bb.y; ai[4*q+2]=bb.z; ai[4*q+3]=bb.w;
            sg[4*q]=s.x; sg[4*q+1]=s.y; sg[4*q+2]=s.z; sg[4*q+3]=s.w;
        }
        float xr = ws[OFF_XFR + l*(CC*HH*WF) + t];
        float xi = ws[OFF_XFI + l*(CC*HH*WF) + t];
        float yr = wv[64], yi = wv[65];
        #pragma unroll
        for (int r=0;r<RR;r++){
            float nre = ar[r]*sre[r] - ai[r]*sim[r] + sg[r]*xr;
            float nim = ar[r]*sim[r] + ai[r]*sre[r] + sg[r]*xi;
            sre[r]=nre; sim[r]=nim;
            yr += wv[r]*nre + wv[16+r]*nim;
            yi += wv[32+r]*nre + wv[48+r]*nim;
        }
        ws[OFF_YFR + l*(CC*HH*WF) + t] = yr;
        ws[OFF_YFI + l*(CC*HH*WF) + t] = yi;
    }
}

// ---- K8: irfft ----
__global__ void k_irfft(float* __restrict__ ws){
    __shared__ float yr[HH][WF], yi[HH][WF];
    __shared__ float ct[64], st[64];
    int b = blockIdx.x; int l = b>>5, c = b&31;
    int tid = threadIdx.x;
    if (tid < 64){ float ang = 2.f*PI_F*(float)tid/64.f; ct[tid]=cosf(ang); st[tid]=sinf(ang); }
    const float* Yr = ws + OFF_YFR + (l*CC+c)*HH*WF;
    const float* Yi = ws + OFF_YFI + (l*CC+c)*HH*WF;
    for (int k=0;k<9;k++){
        int i = tid + k*256;
        if (i < HH*WF){ int h=i/WF, f=i-h*WF; yr[h][f]=Yr[i]; yi[h][f]=Yi[i]; }
    }
    __syncthreads();
    float* y1 = ws + OFF_Y1 + (l*CC+c)*HH*WW;
    for (int k=0;k<16;k++){
        int pix = tid + k*256;
        int h = pix>>6, w = pix&63;
        float acc = yr[h][0] + ((w&1)? -yr[h][32] : yr[h][32]);
        #pragma unroll
        for (int f=1;f<32;f++){
            int a = (f*w)&63;
            acc += 2.0f*(yr[h][f]*ct[a] - yi[h][f]*st[a]);
        }
        y1[pix] = acc*(1.0f/64.0f);
    }
}

// ---- K9: pif ----
__global__ void k_pif(const float* __restrict__ pw, const float* __restrict__ pb,
                      float* __restrict__ ws){
    __shared__ float row[CC][WW];
    int b = blockIdx.x; int l = b>>6, h = b&63;
    int tid = threadIdx.x;
    for (int k=0;k<8;k++){
        int i = tid + k*256;
        int ci = i>>6, w = i&63;
        row[ci][w] = ws[OFF_Y1 + ((l*CC+ci)*HH + h)*WW + w];
    }
    __syncthreads();
    for (int k=0;k<8;k++){
        int i = tid + k*256;
        int o = i>>6, w = i&63;
        float acc = pb[o];
        #pragma unroll
        for (int ci=0;ci<CC;ci++) acc += pw[o*CC+ci]*row[ci][w];
        ws[OFF_Y2 + ((l*CC+o)*HH + h)*WW + w] = acc;
    }
}

// ---- K10: GroupNorm stats ----
__global__ void k_gnstat(float* __restrict__ ws){
    __shared__ float rs[256], rq[256];
    int b = blockIdx.x; int l = b>>2, g = b&3;
    const float* z = ws + OFF_Y2 + (l*CC + g*8)*HH*WW;
    int tid = threadIdx.x;
    float s=0.f, q=0.f;
    for (int i=tid;i<8*HH*WW;i+=256){ float v=z[i]; s+=v; q+=v*v; }
    rs[tid]=s; rq[tid]=q; __syncthreads();
    for (int off=128; off>0; off>>=1){
        if (tid<off){ rs[tid]+=rs[tid+off]; rq[tid]+=rq[tid+off]; }
        __syncthreads();
    }
    if (tid==0){
        float mean = rs[0]/32768.0f;
        float var = rq[0]/32768.0f - mean*mean;
        ws[OFF_GNM + b] = mean;
        ws[OFF_GNR + b] = rsqrtf(var + 1e-5f);
    }
}

// ---- K11: normalize + W-mean ----
__global__ void k_normym(const float* __restrict__ gn_w, const float* __restrict__ gn_b,
                         float* __restrict__ ws){
    int b = blockIdx.x; int l = b>>5, c = b&31;
    int tid = threadIdx.x;
    int g = c>>3;
    float mu = ws[OFF_GNM + l*4+g], rstd = ws[OFF_GNR + l*4+g];
    float gw = gn_w[c], gb = gn_b[c];
    float* z = ws + OFF_Y2 + (l*CC+c)*HH*WW;
    int w = tid&63, hs = tid>>6;
    for (int k=0;k<16;k++){
        int h = hs*16 + k;
        int i = h*WW + w;
        float v = (z[i]-mu)*rstd*gw + gb;
        z[i] = v;
        float s = v;
        for (int off=32; off>0; off>>=1) s += __shfl_down(s, off, 64);
        if ((tid&63)==0) ws[OFF_YM + (l*HH+h)*CC + c] = s*(1.0f/64.0f);
    }
}

// ---- K12: gate MLP ----
__global__ void k_gate(const float* __restrict__ g1w, const float* __restrict__ g1b,
                       const float* __restrict__ g2w, const float* __restrict__ g2b,
                       float* __restrict__ ws){
    int t = blockIdx.x*256 + threadIdx.x;
    if (t >= LL*HH*CC) return;
    int c = t & 31, h = (t>>5)&63, l = t>>11;
    const float* ym = ws + OFF_YM + (l*HH+h)*CC;
    float mid[4];
    #pragma unroll
    for (int m=0;m<4;m++){
        float a = g1b[m];
        for (int i=0;i<CC;i++) a += ym[i]*g1w[m*CC+i];
        mid[m] = a*sigmoidf_(a);
    }
    float a = g2b[c];
    #pragma unroll
    for (int m=0;m<4;m++) a += mid[m]*g2w[c*4+m];
    ws[OFF_GATE + t] = sigmoidf_(a);
}

// ---- K13: residual (float4) ----
__global__ void k_final(const float* __restrict__ x, float* __restrict__ out,
                        const float* __restrict__ ws){
    int t = blockIdx.x*256 + threadIdx.x;   // quad index
    int n = t*4;
    int h = (n>>6)&63, l = (n>>12)&15, c = n>>16;
    float4 z  = *(const float4*)(ws + OFF_Y2 + (((l*CC+c)*HH+h)*WW) + (n&63));
    float  gt = ws[OFF_GATE + (l*HH+h)*CC + c];
    float4 xv = *(const float4*)(x + n);
    float4 o;
    o.x = xv.x + z.x*gt; o.y = xv.y + z.y*gt;
    o.z = xv.z + z.z*gt; o.w = xv.w + z.w*gt;
    *(float4*)(out + n) = o;
}

extern "C" void kernel_launch(void* const* d_in, const int* in_sizes, int n_in,
                              void* d_out, int out_size, void* d_ws, size_t ws_size,
                              hipStream_t stream){
    const float* x    = (const float*)d_in[0];
    const float* dt   = (const float*)d_in[1];
    const float* c1w  = (const float*)d_in[2];
    const float* c1b  = (const float*)d_in[3];
    const float* c2w  = (const float*)d_in[4];
    const float* c2b  = (const float*)d_in[5];
    const float* gfcw = (const float*)d_in[6];
    const float* gfcb = (const float*)d_in[7];
    const float* hw   = (const float*)d_in[8];
    const float* hb   = (const float*)d_in[9];
    const float* mixw = (const float*)d_in[10];
    const float* mixb = (const float*)d_in[11];
    const float* rs   = (const float*)d_in[12];
    const float* pjw  = (const float*)d_in[13];
    const float* pjb  = (const float*)d_in[14];
    const float* pifw = (const float*)d_in[15];
    const float* pifb = (const float*)d_in[16];
    const float* gnw  = (const float*)d_in[17];
    const float* gnb  = (const float*)d_in[18];
    const float* g1w  = (const float*)d_in[19];
    const float* g1b  = (const float*)d_in[20];
    const float* g2w  = (const float*)d_in[21];
    const float* g2b  = (const float*)d_in[22];
    float* ws  = (float*)d_ws;
    float* out = (float*)d_out;
    unsigned short* wt  = (unsigned short*)(ws + OFF_WT);
    unsigned short* f1p = (unsigned short*)(ws + OFF_F1);

    k_prep  <<<1,    64,  0, stream>>>(mixw, mixb, rs, pjw, pjb, ws);
    k_wprep <<<72,   256, 0, stream>>>(c1w, c2w, ws);
    hipMemsetAsync((void*)(ws + OFF_COLSUM), 0, 32768*sizeof(float), stream);
    k_conv1m<<<1024, 256, 0, stream>>>(x, wt, c1b, f1p);
    k_conv2m<<<1024, 256, 0, stream>>>(f1p, wt + 9216, c2b, ws);
    k_glob  <<<16,   64,  0, stream>>>(gfcw, gfcb, ws);
    k_feat  <<<66,   256, 0, stream>>>(ws);
    k_head  <<<1056, 256, 0, stream>>>(hw, hb, dt, ws);
    k_rfft  <<<512,  256, 0, stream>>>(x, ws);
    k_scan  <<<264,  256, 0, stream>>>(ws);
    k_irfft <<<512,  256, 0, stream>>>(ws);
    k_pif   <<<1024, 256, 0, stream>>>(pifw, pifb, ws);
    k_gnstat<<<64,   256, 0, stream>>>(ws);
    k_normym<<<512,  256, 0, stream>>>(gnw, gnb, ws);
    k_gate  <<<128,  256, 0, stream>>>(g1w, g1b, g2w, g2b, ws);
    k_final <<<2048, 256, 0, stream>>>(x, out, ws);
}

// Round 7
// 313.898 us; speedup vs baseline: 3.7102x; 1.1640x over previous
//
#include <hip/hip_runtime.h>
#include <hip/hip_bf16.h>
#include <math.h>

#define CC 32
#define LL 16
#define HH 64
#define WW 64
#define WF 33
#define RR 16
#define PI_F 3.14159265358979323846f

typedef __attribute__((ext_vector_type(8))) short short8;
typedef __attribute__((ext_vector_type(4))) float f32x4;

// ---- workspace layout (floats). Regions reused across phases. ----
#define OFF_F1      0          // f1 packed bf16 [l][h][w][ci] (2M ushort = 4MB); later reused as Y2 (fp32)
#define OFF_COLSUM  2097152    // 32768    [l][c][w]
#define OFF_GLOB    2130432    // 512 (unused now)
#define OFF_FEAT    2130944    // 16896    [l][wf][c]
#define OFF_ARE     2147840    // 270336   [l][c][wf][r]
#define OFF_AIM     2418176    // 270336
#define OFF_SGG     2688512    // 270336
#define OFF_XFR     2958848    // 1081344  [l][c][h][f]
#define OFF_XFI     4040192    // 1081344
#define OFF_YFR     5121536    // 1081344
#define OFF_YFI     6202880    // 1081344
#define OFF_PART    2958848    // 2097152  conv2 partial colsums [l*64+h][c*64+w] (dead XFR/XFI region)
#define OFF_Y1      2958848    // 2097152  (overlaps dead XFR/XFI)
#define OFF_Y2      0          // 2097152  (overlaps dead F1)
#define OFF_GNM     7284224    // 64
#define OFF_GNR     7284288    // 64
#define OFF_YM      7284352    // 32768    [l][h][c]
#define OFF_GATE    7317120    // 32768
#define OFF_WVEC    7349888    // 66
#define OFF_WT      7350016    // 18432 ushort region (bf16-packed conv weights)
// total ~29.5 MB

__device__ __forceinline__ float sigmoidf_(float x){ return 1.0f/(1.0f+expf(-x)); }
__device__ __forceinline__ unsigned short f2bf(float v){
    __hip_bfloat16 b = __float2bfloat16(v);
    return *reinterpret_cast<unsigned short*>(&b);
}

// ---- K0: collapse mix/rank_scale/proj into two 32-vectors ----
__global__ void k_prep(const float* __restrict__ mix_w, const float* __restrict__ mix_b,
                       const float* __restrict__ rank_scale, const float* __restrict__ proj_w,
                       const float* __restrict__ proj_b, float* __restrict__ ws){
    float* wv = ws + OFF_WVEC;
    int t = threadIdx.x;
    if (t < 32){
        float sre=0.f, sim=0.f;
        for (int r=0;r<RR;r++){
            float a = proj_w[r]*rank_scale[r];
            sre += a*mix_w[r*2*RR + t];
            sim += a*mix_w[(RR+r)*2*RR + t];
        }
        wv[t] = sre;
        wv[32+t] = sim;
    }
    if (t == 0){
        float cre=0.f, cim=0.f;
        for (int r=0;r<RR;r++){
            float a = proj_w[r]*rank_scale[r];
            cre += a*mix_b[r];
            cim += a*mix_b[RR+r];
        }
        wv[64] = cre + proj_b[0];
        wv[65] = cim;
    }
}

// ---- K0b: pack conv weights into MFMA A-fragment lane order, bf16 ----
__global__ void k_wprep(const float* __restrict__ c1w, const float* __restrict__ c2w,
                        float* __restrict__ ws){
    int i = blockIdx.x*256 + threadIdx.x;
    if (i >= 2*9216) return;
    int which = (i >= 9216);
    int j = which ? i - 9216 : i;
    int je   = j & 7;
    int lane = (j >> 3) & 63;
    int ct   = (j >> 9) & 1;
    int tap  = j >> 10;             // 0..8 = kh*3+kw
    int kh = tap/3, kw = tap - kh*3;
    int co = ct*16 + (lane & 15);
    int ci = (lane >> 4)*8 + je;
    const float* cw = which ? c2w : c1w;
    float v = cw[((co*CC + ci)*3 + kh)*3 + kw];
    unsigned short* wt = (unsigned short*)(ws + OFF_WT);
    wt[i] = f2bf(v);
}

// ---- K1: conv1 (MFMA, bf16). Block = (l, h). ----
__global__ __launch_bounds__(256, 4) void k_conv1m(const float* __restrict__ x,
                                                   const unsigned short* __restrict__ wt,
                                                   const float* __restrict__ cb,
                                                   unsigned short* __restrict__ f1p){
    __shared__ __align__(16) unsigned short xs[3*66*32];  // [row][wIdx][ci] bf16, swizzled
    __shared__ __align__(16) unsigned short pw[9216];     // packed weights

    const int tid  = threadIdx.x;
    const int l    = blockIdx.x >> 6;
    const int h    = blockIdx.x & 63;
    const int wid  = tid >> 6;
    const int lane = tid & 63;
    const int col  = lane & 15;
    const int kgrp = lane >> 4;

    {
        const unsigned int* src = (const unsigned int*)wt;
        unsigned int* dst = (unsigned int*)pw;
        #pragma unroll
        for (int j = 0; j < 18; ++j) dst[tid + j*256] = src[tid + j*256];
    }
    {
        const int rr = tid >> 6;       // 0..3 (3 = halo-zero crew)
        const int w  = tid & 63;
        if (rr < 3){
            int hh = h - 1 + rr;
            bool hv = (hh >= 0 && hh < HH);
            const float* sp = x + (long)l*HH*WW + hh*WW + w;   // + ci*LL*HH*WW
            int wIdx = 1 + w;
            #pragma unroll
            for (int cib = 0; cib < 4; ++cib){
                float v[8];
                #pragma unroll
                for (int k = 0; k < 8; ++k)
                    v[k] = hv ? sp[(long)(cib*8 + k)*LL*HH*WW] : 0.f;
                uint4 p;
                p.x = (unsigned)f2bf(v[0]) | ((unsigned)f2bf(v[1])<<16);
                p.y = (unsigned)f2bf(v[2]) | ((unsigned)f2bf(v[3])<<16);
                p.z = (unsigned)f2bf(v[4]) | ((unsigned)f2bf(v[5])<<16);
                p.w = (unsigned)f2bf(v[6]) | ((unsigned)f2bf(v[7])<<16);
                int cs = cib ^ (wIdx & 3);
                *(uint4*)&xs[(rr*66 + wIdx)*32 + cs*8] = p;
            }
        } else {
            int s = tid & 63;
            if (s < 24){
                int row = s >> 3, rest = s & 7;
                int wIdx = (rest >> 2) ? 65 : 0;
                int cib = rest & 3;
                *(uint4*)&xs[(row*66 + wIdx)*32 + cib*8] = make_uint4(0,0,0,0);
            }
        }
    }
    __syncthreads();

    #pragma unroll
    for (int u = 0; u < 2; ++u){
        int unit = wid + u*4;           // 0..7
        int ct   = unit >> 2;
        int wt16 = unit & 3;
        int colw = wt16*16 + col;       // output w
        f32x4 acc = {0.f,0.f,0.f,0.f};
        #pragma unroll
        for (int kh = 0; kh < 3; ++kh){
            #pragma unroll
            for (int kw = 0; kw < 3; ++kw){
                int wIdx = colw + kw;
                int cs = kgrp ^ (wIdx & 3);
                short8 b = *(const short8*)&xs[(kh*66 + wIdx)*32 + cs*8];
                short8 a = *(const short8*)&pw[((kh*3+kw)*2 + ct)*512 + lane*8];
                acc = __builtin_amdgcn_mfma_f32_16x16x32_bf16(a, b, acc, 0, 0, 0);
            }
        }
        int co0 = ct*16 + kgrp*4;
        float o[4];
        #pragma unroll
        for (int r = 0; r < 4; ++r){
            float v = acc[r] + cb[co0+r];
            o[r] = v * sigmoidf_(v);
        }
        uint2 pk;
        pk.x = (unsigned)f2bf(o[0]) | ((unsigned)f2bf(o[1])<<16);
        pk.y = (unsigned)f2bf(o[2]) | ((unsigned)f2bf(o[3])<<16);
        *(uint2*)&f1p[(((long)l*HH + h)*WW + colw)*32 + co0] = pk;
    }
}

// ---- K2: conv2 (MFMA, bf16) -> per-(l,h) partial colsum (NO atomics) ----
__global__ __launch_bounds__(256, 4) void k_conv2m(const unsigned short* __restrict__ f1p,
                                                   const unsigned short* __restrict__ wt,
                                                   const float* __restrict__ cb,
                                                   float* __restrict__ ws){
    __shared__ __align__(16) unsigned short xs[3*66*32];
    __shared__ __align__(16) unsigned short pw[9216];
    __shared__ float red[CC*WW];

    const int tid  = threadIdx.x;
    const int l    = blockIdx.x >> 6;
    const int h    = blockIdx.x & 63;
    const int wid  = tid >> 6;
    const int lane = tid & 63;
    const int col  = lane & 15;
    const int kgrp = lane >> 4;

    {
        const unsigned int* src = (const unsigned int*)wt;
        unsigned int* dst = (unsigned int*)pw;
        #pragma unroll
        for (int j = 0; j < 18; ++j) dst[tid + j*256] = src[tid + j*256];
    }
    {
        const int rr = tid >> 6;
        const int w  = tid & 63;
        if (rr < 3){
            int hh = h - 1 + rr;
            bool hv = (hh >= 0 && hh < HH);
            const uint4* sp = (const uint4*)&f1p[(((long)l*HH + hh)*WW + w)*32];
            int wIdx = 1 + w;
            #pragma unroll
            for (int cib = 0; cib < 4; ++cib){
                uint4 p = hv ? sp[cib] : make_uint4(0,0,0,0);
                int cs = cib ^ (wIdx & 3);
                *(uint4*)&xs[(rr*66 + wIdx)*32 + cs*8] = p;
            }
        } else {
            int s = tid & 63;
            if (s < 24){
                int row = s >> 3, rest = s & 7;
                int wIdx = (rest >> 2) ? 65 : 0;
                int cib = rest & 3;
                *(uint4*)&xs[(row*66 + wIdx)*32 + cib*8] = make_uint4(0,0,0,0);
            }
        }
    }
    __syncthreads();

    #pragma unroll
    for (int u = 0; u < 2; ++u){
        int unit = wid + u*4;
        int ct   = unit >> 2;
        int wt16 = unit & 3;
        int colw = wt16*16 + col;
        f32x4 acc = {0.f,0.f,0.f,0.f};
        #pragma unroll
        for (int kh = 0; kh < 3; ++kh){
            #pragma unroll
            for (int kw = 0; kw < 3; ++kw){
                int wIdx = colw + kw;
                int cs = kgrp ^ (wIdx & 3);
                short8 b = *(const short8*)&xs[(kh*66 + wIdx)*32 + cs*8];
                short8 a = *(const short8*)&pw[((kh*3+kw)*2 + ct)*512 + lane*8];
                acc = __builtin_amdgcn_mfma_f32_16x16x32_bf16(a, b, acc, 0, 0, 0);
            }
        }
        int co0 = ct*16 + kgrp*4;
        #pragma unroll
        for (int r = 0; r < 4; ++r){
            float v = acc[r] + cb[co0+r];
            red[(co0+r)*WW + colw] = v * sigmoidf_(v);   // unique writer, no atomic
        }
    }
    __syncthreads();
    // coalesced partial dump: [l*64+h][2048]
    float4* p4 = (float4*)(ws + OFF_PART + ((long)(l*HH + h))*2048);
    const float4* r4 = (const float4*)red;
    p4[tid]       = r4[tid];
    p4[tid + 256] = r4[tid + 256];
}

// ---- K2b: reduce partials over h -> colsum[l][c][w] ----
__global__ void k_colred(float* __restrict__ ws){
    int b = blockIdx.x;            // l*32 + c
    int l = b >> 5, c = b & 31;
    int w = threadIdx.x;           // 64
    const float* p = ws + OFF_PART + (long)l*HH*2048 + c*WW + w;
    float s = 0.f;
    #pragma unroll 8
    for (int h = 0; h < HH; ++h) s += p[h*2048];
    ws[OFF_COLSUM + (l*CC + c)*WW + w] = s;
}

// ---- K3: glob + adaptive pool fused. Block = l. ----
__global__ void k_globfeat(const float* __restrict__ gfc_w, const float* __restrict__ gfc_b,
                           float* __restrict__ ws){
    __shared__ float gs[CC], gl[CC];
    int l = blockIdx.x;
    int tid = threadIdx.x;
    if (tid < 32){
        const float* cs = ws + OFF_COLSUM + (l*CC+tid)*WW;
        float s = 0.f;
        for (int w=0;w<WW;w++) s += cs[w];
        gs[tid] = s;
    }
    __syncthreads();
    if (tid < 32){
        float acc = gfc_b[tid];
        for (int i=0;i<CC;i++) acc += gs[i]*(1.0f/4096.0f)*gfc_w[tid*CC+i];
        gl[tid] = sigmoidf_(acc);
    }
    __syncthreads();
    for (int i = tid; i < WF*CC; i += 256){
        int c = i & 31, wf = i >> 5;
        int s = (wf*64)/33;
        int e = ((wf+1)*64 + 32)/33;
        const float* cs = ws + OFF_COLSUM + (l*CC+c)*WW;
        float sum = 0.f;
        for (int w=s;w<e;w++) sum += cs[w];
        ws[OFF_FEAT + (l*WF+wf)*CC + c] = gl[c] * sum / (64.0f*(float)(e-s));
    }
}

// ---- K5: head ----
__global__ void k_head(const float* __restrict__ hw, const float* __restrict__ hb,
                       const float* __restrict__ dt, float* __restrict__ ws){
    int t = blockIdx.x*blockDim.x + threadIdx.x;
    if (t >= LL*WF*CC*RR) return;
    int r = t & 15, c = (t>>4) & 31;
    int lw_ = t >> 9;
    int wf = lw_ % WF, l = lw_ / WF;
    const float* feat = ws + OFF_FEAT + (l*WF+wf)*CC;
    int j0 = (c*RR + r)*3;
    const float* w0 = hw + j0*CC;
    float p0=hb[j0], p1=hb[j0+1], p2=hb[j0+2];
    for (int i=0;i<CC;i++){
        float fv = feat[i];
        p0 += fv*w0[i]; p1 += fv*w0[CC+i]; p2 += fv*w0[2*CC+i];
    }
    float nu = fmaxf(p0,0.f) + log1pf(expf(-fabsf(p0)));
    float th = tanhf(p1)*PI_F;
    float sg = sigmoidf_(p2);
    float dtv = dt[l];
    float decay = expf(-nu*dtv);
    float ang = th*dtv;
    float g = 1.0f - expf(-2.0f*fmaxf(dtv,0.f));
    int idx = ((l*CC+c)*WF+wf)*RR + r;
    ws[OFF_ARE+idx] = decay*cosf(ang);
    ws[OFF_AIM+idx] = decay*sinf(ang);
    ws[OFF_SGG+idx] = sg*g;
}

// ---- K6: rfft over W (direct DFT). Block = (l,c). ----
__global__ void k_rfft(const float* __restrict__ x, float* __restrict__ ws){
    __shared__ float plane[HH][WW+1];
    __shared__ float ct[64], st[64];
    int b = blockIdx.x; int l = b >> 5, c = b & 31;
    int tid = threadIdx.x;
    if (tid < 64){
        float ang = 2.0f*PI_F*(float)tid/64.0f;
        ct[tid] = cosf(ang); st[tid] = sinf(ang);
    }
    const float* xp = x + (c*LL + l)*HH*WW;
    for (int k=0;k<16;k++){
        int pix = tid + k*256;
        plane[pix>>6][pix&63] = xp[pix];
    }
    __syncthreads();
    float* xfr = ws + OFF_XFR + (l*CC + c)*HH*WF;
    float* xfi = ws + OFF_XFI + (l*CC + c)*HH*WF;
    for (int k=0;k<9;k++){
        int oi = tid + k*256;
        if (oi >= HH*WF) break;
        int h = oi/WF, f = oi - h*WF;
        float re=0.f, im=0.f;
        int idx = 0;
        for (int w=0;w<WW;w++){
            float v = plane[h][w];
            re += v*ct[idx]; im -= v*st[idx];
            idx = (idx + f) & 63;
        }
        xfr[oi] = re; xfi[oi] = im;
    }
}

// ---- K7: scan over L, fused collapsed mix/proj ----
__global__ void k_scan(float* __restrict__ ws){
    __shared__ float wv[66];
    int tid = threadIdx.x;
    if (tid < 66) wv[tid] = ws[OFF_WVEC + tid];
    __syncthreads();
    int t = blockIdx.x*256 + tid;
    if (t >= CC*HH*WF) return;
    int f = t % WF;
    int c = t / (HH*WF);
    float sre[RR], sim[RR];
    #pragma unroll
    for (int r=0;r<RR;r++){ sre[r]=0.f; sim[r]=0.f; }
    for (int l=0;l<LL;l++){
        int base = ((l*CC+c)*WF+f)*RR;
        const float4* A4 = reinterpret_cast<const float4*>(ws + OFF_ARE + base);
        const float4* I4 = reinterpret_cast<const float4*>(ws + OFF_AIM + base);
        const float4* S4 = reinterpret_cast<const float4*>(ws + OFF_SGG + base);
        float ar[RR], ai[RR], sg[RR];
        #pragma unroll
        for (int q=0;q<4;q++){
            float4 a = A4[q], bb = I4[q], s = S4[q];
            ar[4*q]=a.x; ar[4*q+1]=a.y; ar[4*q+2]=a.z; ar[4*q+3]=a.w;
            ai[4*q]=bb.x; ai[4*q+1]=bb.y; ai[4*q+2]=bb.z; ai[4*q+3]=bb.w;
            sg[4*q]=s.x; sg[4*q+1]=s.y; sg[4*q+2]=s.z; sg[4*q+3]=s.w;
        }
        float xr = ws[OFF_XFR + l*(CC*HH*WF) + t];
        float xi = ws[OFF_XFI + l*(CC*HH*WF) + t];
        float yr = wv[64], yi = wv[65];
        #pragma unroll
        for (int r=0;r<RR;r++){
            float nre = ar[r]*sre[r] - ai[r]*sim[r] + sg[r]*xr;
            float nim = ar[r]*sim[r] + ai[r]*sre[r] + sg[r]*xi;
            sre[r]=nre; sim[r]=nim;
            yr += wv[r]*nre + wv[16+r]*nim;
            yi += wv[32+r]*nre + wv[48+r]*nim;
        }
        ws[OFF_YFR + l*(CC*HH*WF) + t] = yr;
        ws[OFF_YFI + l*(CC*HH*WF) + t] = yi;
    }
}

// ---- K8: irfft ----
__global__ void k_irfft(float* __restrict__ ws){
    __shared__ float yr[HH][WF], yi[HH][WF];
    __shared__ float ct[64], st[64];
    int b = blockIdx.x; int l = b>>5, c = b&31;
    int tid = threadIdx.x;
    if (tid < 64){ float ang = 2.f*PI_F*(float)tid/64.f; ct[tid]=cosf(ang); st[tid]=sinf(ang); }
    const float* Yr = ws + OFF_YFR + (l*CC+c)*HH*WF;
    const float* Yi = ws + OFF_YFI + (l*CC+c)*HH*WF;
    for (int k=0;k<9;k++){
        int i = tid + k*256;
        if (i < HH*WF){ int h=i/WF, f=i-h*WF; yr[h][f]=Yr[i]; yi[h][f]=Yi[i]; }
    }
    __syncthreads();
    float* y1 = ws + OFF_Y1 + (l*CC+c)*HH*WW;
    for (int k=0;k<16;k++){
        int pix = tid + k*256;
        int h = pix>>6, w = pix&63;
        float acc = yr[h][0] + ((w&1)? -yr[h][32] : yr[h][32]);
        #pragma unroll
        for (int f=1;f<32;f++){
            int a = (f*w)&63;
            acc += 2.0f*(yr[h][f]*ct[a] - yi[h][f]*st[a]);
        }
        y1[pix] = acc*(1.0f/64.0f);
    }
}

// ---- K9: pif ----
__global__ void k_pif(const float* __restrict__ pw, const float* __restrict__ pb,
                      float* __restrict__ ws){
    __shared__ float row[CC][WW];
    int b = blockIdx.x; int l = b>>6, h = b&63;
    int tid = threadIdx.x;
    for (int k=0;k<8;k++){
        int i = tid + k*256;
        int ci = i>>6, w = i&63;
        row[ci][w] = ws[OFF_Y1 + ((l*CC+ci)*HH + h)*WW + w];
    }
    __syncthreads();
    for (int k=0;k<8;k++){
        int i = tid + k*256;
        int o = i>>6, w = i&63;
        float acc = pb[o];
        #pragma unroll
        for (int ci=0;ci<CC;ci++) acc += pw[o*CC+ci]*row[ci][w];
        ws[OFF_Y2 + ((l*CC+o)*HH + h)*WW + w] = acc;
    }
}

// ---- K10: GroupNorm stats ----
__global__ void k_gnstat(float* __restrict__ ws){
    __shared__ float rs[256], rq[256];
    int b = blockIdx.x; int l = b>>2, g = b&3;
    const float* z = ws + OFF_Y2 + (l*CC + g*8)*HH*WW;
    int tid = threadIdx.x;
    float s=0.f, q=0.f;
    for (int i=tid;i<8*HH*WW;i+=256){ float v=z[i]; s+=v; q+=v*v; }
    rs[tid]=s; rq[tid]=q; __syncthreads();
    for (int off=128; off>0; off>>=1){
        if (tid<off){ rs[tid]+=rs[tid+off]; rq[tid]+=rq[tid+off]; }
        __syncthreads();
    }
    if (tid==0){
        float mean = rs[0]/32768.0f;
        float var = rq[0]/32768.0f - mean*mean;
        ws[OFF_GNM + b] = mean;
        ws[OFF_GNR + b] = rsqrtf(var + 1e-5f);
    }
}

// ---- K11: normalize + W-mean ----
__global__ void k_normym(const float* __restrict__ gn_w, const float* __restrict__ gn_b,
                         float* __restrict__ ws){
    int b = blockIdx.x; int l = b>>5, c = b&31;
    int tid = threadIdx.x;
    int g = c>>3;
    float mu = ws[OFF_GNM + l*4+g], rstd = ws[OFF_GNR + l*4+g];
    float gw = gn_w[c], gb = gn_b[c];
    float* z = ws + OFF_Y2 + (l*CC+c)*HH*WW;
    int w = tid&63, hs = tid>>6;
    for (int k=0;k<16;k++){
        int h = hs*16 + k;
        int i = h*WW + w;
        float v = (z[i]-mu)*rstd*gw + gb;
        z[i] = v;
        float s = v;
        for (int off=32; off>0; off>>=1) s += __shfl_down(s, off, 64);
        if ((tid&63)==0) ws[OFF_YM + (l*HH+h)*CC + c] = s*(1.0f/64.0f);
    }
}

// ---- K12: gate MLP ----
__global__ void k_gate(const float* __restrict__ g1w, const float* __restrict__ g1b,
                       const float* __restrict__ g2w, const float* __restrict__ g2b,
                       float* __restrict__ ws){
    int t = blockIdx.x*256 + threadIdx.x;
    if (t >= LL*HH*CC) return;
    int c = t & 31, h = (t>>5)&63, l = t>>11;
    const float* ym = ws + OFF_YM + (l*HH+h)*CC;
    float mid[4];
    #pragma unroll
    for (int m=0;m<4;m++){
        float a = g1b[m];
        for (int i=0;i<CC;i++) a += ym[i]*g1w[m*CC+i];
        mid[m] = a*sigmoidf_(a);
    }
    float a = g2b[c];
    #pragma unroll
    for (int m=0;m<4;m++) a += mid[m]*g2w[c*4+m];
    ws[OFF_GATE + t] = sigmoidf_(a);
}

// ---- K13: residual (float4) ----
__global__ void k_final(const float* __restrict__ x, float* __restrict__ out,
                        const float* __restrict__ ws){
    int t = blockIdx.x*256 + threadIdx.x;   // quad index
    int n = t*4;
    int h = (n>>6)&63, l = (n>>12)&15, c = n>>16;
    float4 z  = *(const float4*)(ws + OFF_Y2 + (((l*CC+c)*HH+h)*WW) + (n&63));
    float  gt = ws[OFF_GATE + (l*HH+h)*CC + c];
    float4 xv = *(const float4*)(x + n);
    float4 o;
    o.x = xv.x + z.x*gt; o.y = xv.y + z.y*gt;
    o.z = xv.z + z.z*gt; o.w = xv.w + z.w*gt;
    *(float4*)(out + n) = o;
}

extern "C" void kernel_launch(void* const* d_in, const int* in_sizes, int n_in,
                              void* d_out, int out_size, void* d_ws, size_t ws_size,
                              hipStream_t stream){
    const float* x    = (const float*)d_in[0];
    const float* dt   = (const float*)d_in[1];
    const float* c1w  = (const float*)d_in[2];
    const float* c1b  = (const float*)d_in[3];
    const float* c2w  = (const float*)d_in[4];
    const float* c2b  = (const float*)d_in[5];
    const float* gfcw = (const float*)d_in[6];
    const float* gfcb = (const float*)d_in[7];
    const float* hw   = (const float*)d_in[8];
    const float* hb   = (const float*)d_in[9];
    const float* mixw = (const float*)d_in[10];
    const float* mixb = (const float*)d_in[11];
    const float* rs   = (const float*)d_in[12];
    const float* pjw  = (const float*)d_in[13];
    const float* pjb  = (const float*)d_in[14];
    const float* pifw = (const float*)d_in[15];
    const float* pifb = (const float*)d_in[16];
    const float* gnw  = (const float*)d_in[17];
    const float* gnb  = (const float*)d_in[18];
    const float* g1w  = (const float*)d_in[19];
    const float* g1b  = (const float*)d_in[20];
    const float* g2w  = (const float*)d_in[21];
    const float* g2b  = (const float*)d_in[22];
    float* ws  = (float*)d_ws;
    float* out = (float*)d_out;
    unsigned short* wt  = (unsigned short*)(ws + OFF_WT);
    unsigned short* f1p = (unsigned short*)(ws + OFF_F1);

    k_prep    <<<1,    64,  0, stream>>>(mixw, mixb, rs, pjw, pjb, ws);
    k_wprep   <<<72,   256, 0, stream>>>(c1w, c2w, ws);
    k_conv1m  <<<1024, 256, 0, stream>>>(x, wt, c1b, f1p);
    k_conv2m  <<<1024, 256, 0, stream>>>(f1p, wt + 9216, c2b, ws);
    k_colred  <<<512,  64,  0, stream>>>(ws);
    k_globfeat<<<16,   256, 0, stream>>>(gfcw, gfcb, ws);
    k_head    <<<1056, 256, 0, stream>>>(hw, hb, dt, ws);
    k_rfft    <<<512,  256, 0, stream>>>(x, ws);
    k_scan    <<<264,  256, 0, stream>>>(ws);
    k_irfft   <<<512,  256, 0, stream>>>(ws);
    k_pif     <<<1024, 256, 0, stream>>>(pifw, pifb, ws);
    k_gnstat  <<<64,   256, 0, stream>>>(ws);
    k_normym  <<<512,  256, 0, stream>>>(gnw, gnb, ws);
    k_gate    <<<128,  256, 0, stream>>>(g1w, g1b, g2w, g2b, ws);
    k_final   <<<2048, 256, 0, stream>>>(x, out, ws);
}

// Round 8
// 287.863 us; speedup vs baseline: 4.0457x; 1.0904x over previous
//
#include <hip/hip_runtime.h>
#include <hip/hip_bf16.h>
#include <math.h>

#define CC 32
#define LL 16
#define HH 64
#define WW 64
#define WF 33
#define RR 16
#define PI_F 3.14159265358979323846f

typedef __attribute__((ext_vector_type(8))) short short8;
typedef __attribute__((ext_vector_type(4))) float f32x4;

// ---- workspace layout (floats). Regions reused across phases. ----
#define OFF_F1      0          // f1 packed bf16 [l][h][w][ci] (2M ushort = 4MB); later reused as Y2 (fp32)
#define OFF_COLSUM  2097152    // 32768    [l][c][w]
#define OFF_FEAT    2130944    // 16896    [l][wf][c]
#define OFF_ARE     2147840    // 270336   [l][c][wf][r]
#define OFF_AIM     2418176    // 270336
#define OFF_SGG     2688512    // 270336
#define OFF_XFR     2958848    // 1081344  [l][c][f][h]  (TRANSPOSED inner layout)
#define OFF_XFI     4040192    // 1081344
#define OFF_YFR     5121536    // 1081344  [l][c][f][h]
#define OFF_YFI     6202880    // 1081344
#define OFF_PART    2958848    // 2097152  conv2 partial colsums (dead XFR/XFI region, consumed before rfft)
#define OFF_Y1      2958848    // 2097152  irfft out (overlaps dead XFR/XFI)
#define OFF_Y2      0          // 2097152  (overlaps dead F1)
#define OFF_GNM     7284224    // 64
#define OFF_GNR     7284288    // 64
#define OFF_YM      7284352    // 32768    [l][h][c]
#define OFF_GATE    7317120    // 32768
#define OFF_WVEC    7349888    // 66
#define OFF_WT      7350016    // 18432 ushort region (bf16-packed conv weights)
// total ~29.5 MB

__device__ __forceinline__ float sigmoidf_(float x){ return 1.0f/(1.0f+expf(-x)); }
__device__ __forceinline__ unsigned short f2bf(float v){
    __hip_bfloat16 b = __float2bfloat16(v);
    return *reinterpret_cast<unsigned short*>(&b);
}

// ---- K0: collapse mix/rank_scale/proj into two 32-vectors ----
__global__ void k_prep(const float* __restrict__ mix_w, const float* __restrict__ mix_b,
                       const float* __restrict__ rank_scale, const float* __restrict__ proj_w,
                       const float* __restrict__ proj_b, float* __restrict__ ws){
    float* wv = ws + OFF_WVEC;
    int t = threadIdx.x;
    if (t < 32){
        float sre=0.f, sim=0.f;
        for (int r=0;r<RR;r++){
            float a = proj_w[r]*rank_scale[r];
            sre += a*mix_w[r*2*RR + t];
            sim += a*mix_w[(RR+r)*2*RR + t];
        }
        wv[t] = sre;
        wv[32+t] = sim;
    }
    if (t == 0){
        float cre=0.f, cim=0.f;
        for (int r=0;r<RR;r++){
            float a = proj_w[r]*rank_scale[r];
            cre += a*mix_b[r];
            cim += a*mix_b[RR+r];
        }
        wv[64] = cre + proj_b[0];
        wv[65] = cim;
    }
}

// ---- K0b: pack conv weights into MFMA A-fragment lane order, bf16 ----
__global__ void k_wprep(const float* __restrict__ c1w, const float* __restrict__ c2w,
                        float* __restrict__ ws){
    int i = blockIdx.x*256 + threadIdx.x;
    if (i >= 2*9216) return;
    int which = (i >= 9216);
    int j = which ? i - 9216 : i;
    int je   = j & 7;
    int lane = (j >> 3) & 63;
    int ct   = (j >> 9) & 1;
    int tap  = j >> 10;             // 0..8 = kh*3+kw
    int kh = tap/3, kw = tap - kh*3;
    int co = ct*16 + (lane & 15);
    int ci = (lane >> 4)*8 + je;
    const float* cw = which ? c2w : c1w;
    float v = cw[((co*CC + ci)*3 + kh)*3 + kw];
    unsigned short* wt = (unsigned short*)(ws + OFF_WT);
    wt[i] = f2bf(v);
}

// ---- K1: conv1 (MFMA, bf16). Block = (l, h). ----
__global__ __launch_bounds__(256, 4) void k_conv1m(const float* __restrict__ x,
                                                   const unsigned short* __restrict__ wt,
                                                   const float* __restrict__ cb,
                                                   unsigned short* __restrict__ f1p){
    __shared__ __align__(16) unsigned short xs[3*66*32];  // [row][wIdx][ci] bf16, swizzled
    __shared__ __align__(16) unsigned short pw[9216];     // packed weights

    const int tid  = threadIdx.x;
    const int l    = blockIdx.x >> 6;
    const int h    = blockIdx.x & 63;
    const int wid  = tid >> 6;
    const int lane = tid & 63;
    const int col  = lane & 15;
    const int kgrp = lane >> 4;

    {
        const unsigned int* src = (const unsigned int*)wt;
        unsigned int* dst = (unsigned int*)pw;
        #pragma unroll
        for (int j = 0; j < 18; ++j) dst[tid + j*256] = src[tid + j*256];
    }
    {
        const int rr = tid >> 6;       // 0..3 (3 = halo-zero crew)
        const int w  = tid & 63;
        if (rr < 3){
            int hh = h - 1 + rr;
            bool hv = (hh >= 0 && hh < HH);
            const float* sp = x + (long)l*HH*WW + hh*WW + w;   // + ci*LL*HH*WW
            int wIdx = 1 + w;
            #pragma unroll
            for (int cib = 0; cib < 4; ++cib){
                float v[8];
                #pragma unroll
                for (int k = 0; k < 8; ++k)
                    v[k] = hv ? sp[(long)(cib*8 + k)*LL*HH*WW] : 0.f;
                uint4 p;
                p.x = (unsigned)f2bf(v[0]) | ((unsigned)f2bf(v[1])<<16);
                p.y = (unsigned)f2bf(v[2]) | ((unsigned)f2bf(v[3])<<16);
                p.z = (unsigned)f2bf(v[4]) | ((unsigned)f2bf(v[5])<<16);
                p.w = (unsigned)f2bf(v[6]) | ((unsigned)f2bf(v[7])<<16);
                int cs = cib ^ (wIdx & 3);
                *(uint4*)&xs[(rr*66 + wIdx)*32 + cs*8] = p;
            }
        } else {
            int s = tid & 63;
            if (s < 24){
                int row = s >> 3, rest = s & 7;
                int wIdx = (rest >> 2) ? 65 : 0;
                int cib = rest & 3;
                *(uint4*)&xs[(row*66 + wIdx)*32 + cib*8] = make_uint4(0,0,0,0);
            }
        }
    }
    __syncthreads();

    #pragma unroll
    for (int u = 0; u < 2; ++u){
        int unit = wid + u*4;           // 0..7
        int ct   = unit >> 2;
        int wt16 = unit & 3;
        int colw = wt16*16 + col;       // output w
        f32x4 acc = {0.f,0.f,0.f,0.f};
        #pragma unroll
        for (int kh = 0; kh < 3; ++kh){
            #pragma unroll
            for (int kw = 0; kw < 3; ++kw){
                int wIdx = colw + kw;
                int cs = kgrp ^ (wIdx & 3);
                short8 b = *(const short8*)&xs[(kh*66 + wIdx)*32 + cs*8];
                short8 a = *(const short8*)&pw[((kh*3+kw)*2 + ct)*512 + lane*8];
                acc = __builtin_amdgcn_mfma_f32_16x16x32_bf16(a, b, acc, 0, 0, 0);
            }
        }
        int co0 = ct*16 + kgrp*4;
        float o[4];
        #pragma unroll
        for (int r = 0; r < 4; ++r){
            float v = acc[r] + cb[co0+r];
            o[r] = v * sigmoidf_(v);
        }
        uint2 pk;
        pk.x = (unsigned)f2bf(o[0]) | ((unsigned)f2bf(o[1])<<16);
        pk.y = (unsigned)f2bf(o[2]) | ((unsigned)f2bf(o[3])<<16);
        *(uint2*)&f1p[(((long)l*HH + h)*WW + colw)*32 + co0] = pk;
    }
}

// ---- K2: conv2 (MFMA, bf16) -> per-(l,h) partial colsum (NO atomics) ----
__global__ __launch_bounds__(256, 4) void k_conv2m(const unsigned short* __restrict__ f1p,
                                                   const unsigned short* __restrict__ wt,
                                                   const float* __restrict__ cb,
                                                   float* __restrict__ ws){
    __shared__ __align__(16) unsigned short xs[3*66*32];
    __shared__ __align__(16) unsigned short pw[9216];
    __shared__ float red[CC*WW];

    const int tid  = threadIdx.x;
    const int l    = blockIdx.x >> 6;
    const int h    = blockIdx.x & 63;
    const int wid  = tid >> 6;
    const int lane = tid & 63;
    const int col  = lane & 15;
    const int kgrp = lane >> 4;

    {
        const unsigned int* src = (const unsigned int*)wt;
        unsigned int* dst = (unsigned int*)pw;
        #pragma unroll
        for (int j = 0; j < 18; ++j) dst[tid + j*256] = src[tid + j*256];
    }
    {
        const int rr = tid >> 6;
        const int w  = tid & 63;
        if (rr < 3){
            int hh = h - 1 + rr;
            bool hv = (hh >= 0 && hh < HH);
            const uint4* sp = (const uint4*)&f1p[(((long)l*HH + hh)*WW + w)*32];
            int wIdx = 1 + w;
            #pragma unroll
            for (int cib = 0; cib < 4; ++cib){
                uint4 p = hv ? sp[cib] : make_uint4(0,0,0,0);
                int cs = cib ^ (wIdx & 3);
                *(uint4*)&xs[(rr*66 + wIdx)*32 + cs*8] = p;
            }
        } else {
            int s = tid & 63;
            if (s < 24){
                int row = s >> 3, rest = s & 7;
                int wIdx = (rest >> 2) ? 65 : 0;
                int cib = rest & 3;
                *(uint4*)&xs[(row*66 + wIdx)*32 + cib*8] = make_uint4(0,0,0,0);
            }
        }
    }
    __syncthreads();

    #pragma unroll
    for (int u = 0; u < 2; ++u){
        int unit = wid + u*4;
        int ct   = unit >> 2;
        int wt16 = unit & 3;
        int colw = wt16*16 + col;
        f32x4 acc = {0.f,0.f,0.f,0.f};
        #pragma unroll
        for (int kh = 0; kh < 3; ++kh){
            #pragma unroll
            for (int kw = 0; kw < 3; ++kw){
                int wIdx = colw + kw;
                int cs = kgrp ^ (wIdx & 3);
                short8 b = *(const short8*)&xs[(kh*66 + wIdx)*32 + cs*8];
                short8 a = *(const short8*)&pw[((kh*3+kw)*2 + ct)*512 + lane*8];
                acc = __builtin_amdgcn_mfma_f32_16x16x32_bf16(a, b, acc, 0, 0, 0);
            }
        }
        int co0 = ct*16 + kgrp*4;
        #pragma unroll
        for (int r = 0; r < 4; ++r){
            float v = acc[r] + cb[co0+r];
            red[(co0+r)*WW + colw] = v * sigmoidf_(v);   // unique writer, no atomic
        }
    }
    __syncthreads();
    float4* p4 = (float4*)(ws + OFF_PART + ((long)(l*HH + h))*2048);
    const float4* r4 = (const float4*)red;
    p4[tid]       = r4[tid];
    p4[tid + 256] = r4[tid + 256];
}

// ---- K2b: reduce partials over h -> colsum[l][c][w] ----
__global__ void k_colred(float* __restrict__ ws){
    int b = blockIdx.x;            // l*32 + c
    int l = b >> 5, c = b & 31;
    int w = threadIdx.x;           // 64
    const float* p = ws + OFF_PART + (long)l*HH*2048 + c*WW + w;
    float s = 0.f;
    #pragma unroll 8
    for (int h = 0; h < HH; ++h) s += p[h*2048];
    ws[OFF_COLSUM + (l*CC + c)*WW + w] = s;
}

// ---- K3: glob + adaptive pool fused. Block = l. ----
__global__ void k_globfeat(const float* __restrict__ gfc_w, const float* __restrict__ gfc_b,
                           float* __restrict__ ws){
    __shared__ float gs[CC], gl[CC];
    int l = blockIdx.x;
    int tid = threadIdx.x;
    if (tid < 32){
        const float* cs = ws + OFF_COLSUM + (l*CC+tid)*WW;
        float s = 0.f;
        for (int w=0;w<WW;w++) s += cs[w];
        gs[tid] = s;
    }
    __syncthreads();
    if (tid < 32){
        float acc = gfc_b[tid];
        for (int i=0;i<CC;i++) acc += gs[i]*(1.0f/4096.0f)*gfc_w[tid*CC+i];
        gl[tid] = sigmoidf_(acc);
    }
    __syncthreads();
    for (int i = tid; i < WF*CC; i += 256){
        int c = i & 31, wf = i >> 5;
        int s = (wf*64)/33;
        int e = ((wf+1)*64 + 32)/33;
        const float* cs = ws + OFF_COLSUM + (l*CC+c)*WW;
        float sum = 0.f;
        for (int w=s;w<e;w++) sum += cs[w];
        ws[OFF_FEAT + (l*WF+wf)*CC + c] = gl[c] * sum / (64.0f*(float)(e-s));
    }
}

// ---- K5: head ----
__global__ void k_head(const float* __restrict__ hw, const float* __restrict__ hb,
                       const float* __restrict__ dt, float* __restrict__ ws){
    int t = blockIdx.x*blockDim.x + threadIdx.x;
    if (t >= LL*WF*CC*RR) return;
    int r = t & 15, c = (t>>4) & 31;
    int lw_ = t >> 9;
    int wf = lw_ % WF, l = lw_ / WF;
    const float* feat = ws + OFF_FEAT + (l*WF+wf)*CC;
    int j0 = (c*RR + r)*3;
    const float* w0 = hw + j0*CC;
    float p0=hb[j0], p1=hb[j0+1], p2=hb[j0+2];
    for (int i=0;i<CC;i++){
        float fv = feat[i];
        p0 += fv*w0[i]; p1 += fv*w0[CC+i]; p2 += fv*w0[2*CC+i];
    }
    float nu = fmaxf(p0,0.f) + log1pf(expf(-fabsf(p0)));
    float th = tanhf(p1)*PI_F;
    float sg = sigmoidf_(p2);
    float dtv = dt[l];
    float decay = expf(-nu*dtv);
    float ang = th*dtv;
    float g = 1.0f - expf(-2.0f*fmaxf(dtv,0.f));
    int idx = ((l*CC+c)*WF+wf)*RR + r;
    ws[OFF_ARE+idx] = decay*cosf(ang);
    ws[OFF_AIM+idx] = decay*sinf(ang);
    ws[OFF_SGG+idx] = sg*g;
}

// ---- K6: rfft over W (direct DFT). Block = (l,c). Output layout [f][h]. ----
__global__ void k_rfft(const float* __restrict__ x, float* __restrict__ ws){
    __shared__ float plane[HH][WW+1];
    __shared__ float ct[64], st[64];
    int b = blockIdx.x; int l = b >> 5, c = b & 31;
    int tid = threadIdx.x;
    if (tid < 64){
        float ang = 2.0f*PI_F*(float)tid/64.0f;
        ct[tid] = cosf(ang); st[tid] = sinf(ang);
    }
    const float* xp = x + (c*LL + l)*HH*WW;
    for (int k=0;k<16;k++){
        int pix = tid + k*256;
        plane[pix>>6][pix&63] = xp[pix];
    }
    __syncthreads();
    float* xfr = ws + OFF_XFR + (l*CC + c)*HH*WF;
    float* xfi = ws + OFF_XFI + (l*CC + c)*HH*WF;
    for (int k=0;k<9;k++){
        int oi = tid + k*256;
        if (oi >= HH*WF) break;
        int f = oi >> 6, h = oi & 63;      // [f][h]: wave-uniform f
        float re=0.f, im=0.f;
        int idx = 0;
        for (int w=0;w<WW;w++){
            float v = plane[h][w];
            re += v*ct[idx]; im -= v*st[idx];
            idx = (idx + f) & 63;
        }
        xfr[oi] = re; xfi[oi] = im;
    }
}

// ---- K7: scan over L. Block = (c, wf); 256 thr = 64 h x 4 r-quads.
//      A/I/S staged in LDS once; 4 complex states/thread; shfl reduce. ----
__global__ __launch_bounds__(256) void k_scan(float* __restrict__ ws){
    __shared__ float lA[LL*RR], lI[LL*RR], lS[LL*RR];
    __shared__ float wv[66];
    int b = blockIdx.x;                // c*WF + wf
    int c = b / WF, f = b - c*WF;
    int tid = threadIdx.x;
    if (tid < 66) wv[tid] = ws[OFF_WVEC + tid];
    {
        int l = tid >> 4, r = tid & 15;
        int src = ((l*CC + c)*WF + f)*RR + r;
        lA[tid] = ws[OFF_ARE + src];
        lI[tid] = ws[OFF_AIM + src];
        lS[tid] = ws[OFF_SGG + src];
    }
    __syncthreads();
    const int h  = tid >> 2;
    const int rq = tid & 3;            // ranks rq*4 .. rq*4+3
    float sre[4] = {0,0,0,0}, sim[4] = {0,0,0,0};
    float w0_[4], w1_[4], w2_[4], w3_[4];
    #pragma unroll
    for (int q=0;q<4;q++){
        int r = rq*4 + q;
        w0_[q]=wv[r]; w1_[q]=wv[16+r]; w2_[q]=wv[32+r]; w3_[q]=wv[48+r];
    }
    const float cre = wv[64], cim = wv[65];
    const long fh = (long)(c*WF + f)*HH + h;
    #pragma unroll 1
    for (int l=0;l<LL;l++){
        float xr = ws[OFF_XFR + l*(CC*HH*WF) + fh];
        float xi = ws[OFF_XFI + l*(CC*HH*WF) + fh];
        float yr = 0.f, yi = 0.f;
        #pragma unroll
        for (int q=0;q<4;q++){
            int r = rq*4 + q;
            float a = lA[l*16+r], ii = lI[l*16+r], s = lS[l*16+r];
            float nre = a*sre[q] - ii*sim[q] + s*xr;
            float nim = a*sim[q] + ii*sre[q] + s*xi;
            sre[q]=nre; sim[q]=nim;
            yr += w0_[q]*nre + w1_[q]*nim;
            yi += w2_[q]*nre + w3_[q]*nim;
        }
        yr += __shfl_xor(yr, 1); yr += __shfl_xor(yr, 2);
        yi += __shfl_xor(yi, 1); yi += __shfl_xor(yi, 2);
        if (rq == 0){
            ws[OFF_YFR + l*(CC*HH*WF) + fh] = yr + cre;
            ws[OFF_YFI + l*(CC*HH*WF) + fh] = yi + cim;
        }
    }
}

// ---- K8: irfft. Input layout [f][h]. ----
__global__ void k_irfft(float* __restrict__ ws){
    __shared__ float yr[HH][WF], yi[HH][WF];
    __shared__ float ct[64], st[64];
    int b = blockIdx.x; int l = b>>5, c = b&31;
    int tid = threadIdx.x;
    if (tid < 64){ float ang = 2.f*PI_F*(float)tid/64.f; ct[tid]=cosf(ang); st[tid]=sinf(ang); }
    const float* Yr = ws + OFF_YFR + (l*CC+c)*HH*WF;
    const float* Yi = ws + OFF_YFI + (l*CC+c)*HH*WF;
    for (int k=0;k<9;k++){
        int i = tid + k*256;
        if (i < HH*WF){ int f=i>>6, h=i&63; yr[h][f]=Yr[i]; yi[h][f]=Yi[i]; }
    }
    __syncthreads();
    float* y1 = ws + OFF_Y1 + (l*CC+c)*HH*WW;
    for (int k=0;k<16;k++){
        int pix = tid + k*256;
        int h = pix>>6, w = pix&63;
        float acc = yr[h][0] + ((w&1)? -yr[h][32] : yr[h][32]);
        #pragma unroll
        for (int f=1;f<32;f++){
            int a = (f*w)&63;
            acc += 2.0f*(yr[h][f]*ct[a] - yi[h][f]*st[a]);
        }
        y1[pix] = acc*(1.0f/64.0f);
    }
}

// ---- K9: pif ----
__global__ void k_pif(const float* __restrict__ pw, const float* __restrict__ pb,
                      float* __restrict__ ws){
    __shared__ float row[CC][WW];
    int b = blockIdx.x; int l = b>>6, h = b&63;
    int tid = threadIdx.x;
    for (int k=0;k<8;k++){
        int i = tid + k*256;
        int ci = i>>6, w = i&63;
        row[ci][w] = ws[OFF_Y1 + ((l*CC+ci)*HH + h)*WW + w];
    }
    __syncthreads();
    for (int k=0;k<8;k++){
        int i = tid + k*256;
        int o = i>>6, w = i&63;
        float acc = pb[o];
        #pragma unroll
        for (int ci=0;ci<CC;ci++) acc += pw[o*CC+ci]*row[ci][w];
        ws[OFF_Y2 + ((l*CC+o)*HH + h)*WW + w] = acc;
    }
}

// ---- K10: GroupNorm stats ----
__global__ void k_gnstat(float* __restrict__ ws){
    __shared__ float rs[256], rq[256];
    int b = blockIdx.x; int l = b>>2, g = b&3;
    const float* z = ws + OFF_Y2 + (l*CC + g*8)*HH*WW;
    int tid = threadIdx.x;
    float s=0.f, q=0.f;
    for (int i=tid;i<8*HH*WW;i+=256){ float v=z[i]; s+=v; q+=v*v; }
    rs[tid]=s; rq[tid]=q; __syncthreads();
    for (int off=128; off>0; off>>=1){
        if (tid<off){ rs[tid]+=rs[tid+off]; rq[tid]+=rq[tid+off]; }
        __syncthreads();
    }
    if (tid==0){
        float mean = rs[0]/32768.0f;
        float var = rq[0]/32768.0f - mean*mean;
        ws[OFF_GNM + b] = mean;
        ws[OFF_GNR + b] = rsqrtf(var + 1e-5f);
    }
}

// ---- K11: normalize + W-mean ----
__global__ void k_normym(const float* __restrict__ gn_w, const float* __restrict__ gn_b,
                         float* __restrict__ ws){
    int b = blockIdx.x; int l = b>>5, c = b&31;
    int tid = threadIdx.x;
    int g = c>>3;
    float mu = ws[OFF_GNM + l*4+g], rstd = ws[OFF_GNR + l*4+g];
    float gw = gn_w[c], gb = gn_b[c];
    float* z = ws + OFF_Y2 + (l*CC+c)*HH*WW;
    int w = tid&63, hs = tid>>6;
    for (int k=0;k<16;k++){
        int h = hs*16 + k;
        int i = h*WW + w;
        float v = (z[i]-mu)*rstd*gw + gb;
        z[i] = v;
        float s = v;
        for (int off=32; off>0; off>>=1) s += __shfl_down(s, off, 64);
        if ((tid&63)==0) ws[OFF_YM + (l*HH+h)*CC + c] = s*(1.0f/64.0f);
    }
}

// ---- K12: gate MLP ----
__global__ void k_gate(const float* __restrict__ g1w, const float* __restrict__ g1b,
                       const float* __restrict__ g2w, const float* __restrict__ g2b,
                       float* __restrict__ ws){
    int t = blockIdx.x*256 + threadIdx.x;
    if (t >= LL*HH*CC) return;
    int c = t & 31, h = (t>>5)&63, l = t>>11;
    const float* ym = ws + OFF_YM + (l*HH+h)*CC;
    float mid[4];
    #pragma unroll
    for (int m=0;m<4;m++){
        float a = g1b[m];
        for (int i=0;i<CC;i++) a += ym[i]*g1w[m*CC+i];
        mid[m] = a*sigmoidf_(a);
    }
    float a = g2b[c];
    #pragma unroll
    for (int m=0;m<4;m++) a += mid[m]*g2w[c*4+m];
    ws[OFF_GATE + t] = sigmoidf_(a);
}

// ---- K13: residual (float4) ----
__global__ void k_final(const float* __restrict__ x, float* __restrict__ out,
                        const float* __restrict__ ws){
    int t = blockIdx.x*256 + threadIdx.x;   // quad index
    int n = t*4;
    int h = (n>>6)&63, l = (n>>12)&15, c = n>>16;
    float4 z  = *(const float4*)(ws + OFF_Y2 + (((l*CC+c)*HH+h)*WW) + (n&63));
    float  gt = ws[OFF_GATE + (l*HH+h)*CC + c];
    float4 xv = *(const float4*)(x + n);
    float4 o;
    o.x = xv.x + z.x*gt; o.y = xv.y + z.y*gt;
    o.z = xv.z + z.z*gt; o.w = xv.w + z.w*gt;
    *(float4*)(out + n) = o;
}

extern "C" void kernel_launch(void* const* d_in, const int* in_sizes, int n_in,
                              void* d_out, int out_size, void* d_ws, size_t ws_size,
                              hipStream_t stream){
    const float* x    = (const float*)d_in[0];
    const float* dt   = (const float*)d_in[1];
    const float* c1w  = (const float*)d_in[2];
    const float* c1b  = (const float*)d_in[3];
    const float* c2w  = (const float*)d_in[4];
    const float* c2b  = (const float*)d_in[5];
    const float* gfcw = (const float*)d_in[6];
    const float* gfcb = (const float*)d_in[7];
    const float* hw   = (const float*)d_in[8];
    const float* hb   = (const float*)d_in[9];
    const float* mixw = (const float*)d_in[10];
    const float* mixb = (const float*)d_in[11];
    const float* rs   = (const float*)d_in[12];
    const float* pjw  = (const float*)d_in[13];
    const float* pjb  = (const float*)d_in[14];
    const float* pifw = (const float*)d_in[15];
    const float* pifb = (const float*)d_in[16];
    const float* gnw  = (const float*)d_in[17];
    const float* gnb  = (const float*)d_in[18];
    const float* g1w  = (const float*)d_in[19];
    const float* g1b  = (const float*)d_in[20];
    const float* g2w  = (const float*)d_in[21];
    const float* g2b  = (const float*)d_in[22];
    float* ws  = (float*)d_ws;
    float* out = (float*)d_out;
    unsigned short* wt  = (unsigned short*)(ws + OFF_WT);
    unsigned short* f1p = (unsigned short*)(ws + OFF_F1);

    k_prep    <<<1,    64,  0, stream>>>(mixw, mixb, rs, pjw, pjb, ws);
    k_wprep   <<<72,   256, 0, stream>>>(c1w, c2w, ws);
    k_conv1m  <<<1024, 256, 0, stream>>>(x, wt, c1b, f1p);
    k_conv2m  <<<1024, 256, 0, stream>>>(f1p, wt + 9216, c2b, ws);
    k_colred  <<<512,  64,  0, stream>>>(ws);
    k_globfeat<<<16,   256, 0, stream>>>(gfcw, gfcb, ws);
    k_head    <<<1056, 256, 0, stream>>>(hw, hb, dt, ws);
    k_rfft    <<<512,  256, 0, stream>>>(x, ws);
    k_scan    <<<1056, 256, 0, stream>>>(ws);
    k_irfft   <<<512,  256, 0, stream>>>(ws);
    k_pif     <<<1024, 256, 0, stream>>>(pifw, pifb, ws);
    k_gnstat  <<<64,   256, 0, stream>>>(ws);
    k_normym  <<<512,  256, 0, stream>>>(gnw, gnb, ws);
    k_gate    <<<128,  256, 0, stream>>>(g1w, g1b, g2w, g2b, ws);
    k_final   <<<2048, 256, 0, stream>>>(x, out, ws);
}

// Round 9
// 238.999 us; speedup vs baseline: 4.8729x; 1.2045x over previous
//
#include <hip/hip_runtime.h>
#include <hip/hip_bf16.h>
#include <math.h>

#define CC 32
#define LL 16
#define HH 64
#define WW 64
#define WF 33
#define RR 16
#define PI_F 3.14159265358979323846f

typedef __attribute__((ext_vector_type(8))) short short8;
typedef __attribute__((ext_vector_type(4))) float f32x4;

// ---- workspace layout (floats). Regions reused across phases. ----
#define OFF_F1      0          // f1 packed bf16 [l][h][w][ci]; later reused as Y2 (fp32)
#define OFF_COLSUM  2097152    // 32768    [l][c][w]
#define OFF_FEAT    2130944    // 16896    [l][wf][c]
#define OFF_ARE     2147840    // 270336   [l][c][wf][r]
#define OFF_AIM     2418176    // 270336
#define OFF_SGG     2688512    // 270336
#define OFF_XFR     2958848    // 1081344  [l][c][f][h]
#define OFF_XFI     4040192    // 1081344
#define OFF_YFR     5121536    // 1081344  [l][c][f][h]
#define OFF_YFI     6202880    // 1081344
#define OFF_PART    2958848    // 2097152  conv2 partials (dead XFR/XFI region, consumed pre-rfft)
#define OFF_Y1      2958848    // 2097152  irfft out (overlaps dead XFR/XFI)
#define OFF_Y2      0          // 2097152  pif raw out (overlaps dead F1)
#define OFF_GNM     7284224    // 64
#define OFF_GNR     7284288    // 64
#define OFF_YM      7284352    // 32768    [l][h][c] RAW w-means of Y2
#define OFF_GATE    7317120    // 32768
#define OFF_WVEC    7349888    // 66
#define OFF_WT      7350016    // ushort region: conv(18432) + AT(10240) + BT(12288) = 40960 u16
// total ~29.5 MB

__device__ __forceinline__ float sigmoidf_(float x){ return 1.0f/(1.0f+expf(-x)); }
__device__ __forceinline__ unsigned short f2bf(float v){
    __hip_bfloat16 b = __float2bfloat16(v);
    return *reinterpret_cast<unsigned short*>(&b);
}
__device__ __forceinline__ float bf2f(unsigned short u){
    __hip_bfloat16 b = *reinterpret_cast<__hip_bfloat16*>(&u);
    return __bfloat162float(b);
}

// ---- K0: all precompute: wvec, conv weight pack, rfft A-table, irfft B-table ----
__global__ void k_prep0(const float* __restrict__ mix_w, const float* __restrict__ mix_b,
                        const float* __restrict__ rank_scale, const float* __restrict__ proj_w,
                        const float* __restrict__ proj_b,
                        const float* __restrict__ c1w, const float* __restrict__ c2w,
                        float* __restrict__ ws){
    unsigned short* wt = (unsigned short*)(ws + OFF_WT);
    if (blockIdx.x == 0){
        float* wv = ws + OFF_WVEC;
        int t = threadIdx.x;
        if (t < 32){
            float sre=0.f, sim=0.f;
            for (int r=0;r<RR;r++){
                float a = proj_w[r]*rank_scale[r];
                sre += a*mix_w[r*2*RR + t];
                sim += a*mix_w[(RR+r)*2*RR + t];
            }
            wv[t] = sre; wv[32+t] = sim;
        }
        if (t == 0){
            float cre=0.f, cim=0.f;
            for (int r=0;r<RR;r++){
                float a = proj_w[r]*rank_scale[r];
                cre += a*mix_b[r];
                cim += a*mix_b[RR+r];
            }
            wv[64] = cre + proj_b[0]; wv[65] = cim;
        }
        return;
    }
    int i = (blockIdx.x-1)*256 + threadIdx.x;
    if (i < 18432){
        // conv weights -> MFMA A-frag order
        int which = (i >= 9216);
        int j = which ? i - 9216 : i;
        int je   = j & 7;
        int lane = (j >> 3) & 63;
        int ct   = (j >> 9) & 1;
        int tap  = j >> 10;
        int kh = tap/3, kw = tap - kh*3;
        int co = ct*16 + (lane & 15);
        int ci = (lane >> 4)*8 + je;
        const float* cw = which ? c2w : c1w;
        wt[i] = f2bf(cw[((co*CC + ci)*3 + kh)*3 + kw]);
        return;
    }
    i -= 18432;
    if (i < 10240){
        // rfft A-table: [tile5][chunk4][lane][8]; rows: 0..32 cos, 33..65 -sin
        int j = i & 7, lane = (i>>3)&63, cch = (i>>9)&3, t = i>>11;
        int frow = t*16 + (lane & 15);
        int k = ((lane>>4)&3)*8 + j;
        int w = (cch & 1)*32 + k;
        float coef = 0.f;
        if (frow < 33)       coef =  cosf(2.0f*PI_F*(float)(frow*w)/64.0f);
        else if (frow < 66)  coef = -sinf(2.0f*PI_F*(float)((frow-33)*w)/64.0f);
        unsigned short hi = f2bf(coef);
        wt[18432 + i] = (cch < 2) ? hi : f2bf(coef - bf2f(hi));
        return;
    }
    i -= 10240;
    if (i < 12288){
        // irfft B-table: [wtile4][chunk6][lane][8]; k rows: 0..32 s*cos/64, 33..65 -s*sin/64
        int wtile = i / 3072;
        int rem = i - wtile*3072;
        int ch = rem >> 9;
        int ll = rem & 511;
        int lane = ll >> 3, j = ll & 7;
        int w = wtile*16 + (lane & 15);
        int k = (ch % 3)*32 + ((lane>>4)&3)*8 + j;   // f' 0..95
        float coef = 0.f;
        if (k < 33){
            float s = (k==0 || k==32) ? 1.f : 2.f;
            coef = s*cosf(2.0f*PI_F*(float)(k*w)/64.0f)*(1.0f/64.0f);
        } else if (k < 66){
            int f = k - 33;
            float s = (f==0 || f==32) ? 1.f : 2.f;
            coef = -s*sinf(2.0f*PI_F*(float)(f*w)/64.0f)*(1.0f/64.0f);
        }
        unsigned short hi = f2bf(coef);
        wt[18432 + 10240 + i] = (ch < 3) ? hi : f2bf(coef - bf2f(hi));
        return;
    }
}

// ---- K1: conv1 (MFMA, bf16). Block = (l, h). ----
__global__ __launch_bounds__(256, 4) void k_conv1m(const float* __restrict__ x,
                                                   const unsigned short* __restrict__ wt,
                                                   const float* __restrict__ cb,
                                                   unsigned short* __restrict__ f1p){
    __shared__ __align__(16) unsigned short xs[3*66*32];
    __shared__ __align__(16) unsigned short pw[9216];

    const int tid  = threadIdx.x;
    const int l    = blockIdx.x >> 6;
    const int h    = blockIdx.x & 63;
    const int wid  = tid >> 6;
    const int lane = tid & 63;
    const int col  = lane & 15;
    const int kgrp = lane >> 4;

    {
        const unsigned int* src = (const unsigned int*)wt;
        unsigned int* dst = (unsigned int*)pw;
        #pragma unroll
        for (int j = 0; j < 18; ++j) dst[tid + j*256] = src[tid + j*256];
    }
    {
        const int rr = tid >> 6;
        const int w  = tid & 63;
        if (rr < 3){
            int hh = h - 1 + rr;
            bool hv = (hh >= 0 && hh < HH);
            const float* sp = x + (long)l*HH*WW + hh*WW + w;
            int wIdx = 1 + w;
            #pragma unroll
            for (int cib = 0; cib < 4; ++cib){
                float v[8];
                #pragma unroll
                for (int k = 0; k < 8; ++k)
                    v[k] = hv ? sp[(long)(cib*8 + k)*LL*HH*WW] : 0.f;
                uint4 p;
                p.x = (unsigned)f2bf(v[0]) | ((unsigned)f2bf(v[1])<<16);
                p.y = (unsigned)f2bf(v[2]) | ((unsigned)f2bf(v[3])<<16);
                p.z = (unsigned)f2bf(v[4]) | ((unsigned)f2bf(v[5])<<16);
                p.w = (unsigned)f2bf(v[6]) | ((unsigned)f2bf(v[7])<<16);
                int cs = cib ^ (wIdx & 3);
                *(uint4*)&xs[(rr*66 + wIdx)*32 + cs*8] = p;
            }
        } else {
            int s = tid & 63;
            if (s < 24){
                int row = s >> 3, rest = s & 7;
                int wIdx = (rest >> 2) ? 65 : 0;
                int cib = rest & 3;
                *(uint4*)&xs[(row*66 + wIdx)*32 + cib*8] = make_uint4(0,0,0,0);
            }
        }
    }
    __syncthreads();

    #pragma unroll
    for (int u = 0; u < 2; ++u){
        int unit = wid + u*4;
        int ct   = unit >> 2;
        int wt16 = unit & 3;
        int colw = wt16*16 + col;
        f32x4 acc = {0.f,0.f,0.f,0.f};
        #pragma unroll
        for (int kh = 0; kh < 3; ++kh){
            #pragma unroll
            for (int kw = 0; kw < 3; ++kw){
                int wIdx = colw + kw;
                int cs = kgrp ^ (wIdx & 3);
                short8 b = *(const short8*)&xs[(kh*66 + wIdx)*32 + cs*8];
                short8 a = *(const short8*)&pw[((kh*3+kw)*2 + ct)*512 + lane*8];
                acc = __builtin_amdgcn_mfma_f32_16x16x32_bf16(a, b, acc, 0, 0, 0);
            }
        }
        int co0 = ct*16 + kgrp*4;
        float o[4];
        #pragma unroll
        for (int r = 0; r < 4; ++r){
            float v = acc[r] + cb[co0+r];
            o[r] = v * sigmoidf_(v);
        }
        uint2 pk;
        pk.x = (unsigned)f2bf(o[0]) | ((unsigned)f2bf(o[1])<<16);
        pk.y = (unsigned)f2bf(o[2]) | ((unsigned)f2bf(o[3])<<16);
        *(uint2*)&f1p[(((long)l*HH + h)*WW + colw)*32 + co0] = pk;
    }
}

// ---- K2: conv2 (MFMA, bf16) -> per-(l,h) partial colsum ----
__global__ __launch_bounds__(256, 4) void k_conv2m(const unsigned short* __restrict__ f1p,
                                                   const unsigned short* __restrict__ wt,
                                                   const float* __restrict__ cb,
                                                   float* __restrict__ ws){
    __shared__ __align__(16) unsigned short xs[3*66*32];
    __shared__ __align__(16) unsigned short pw[9216];
    __shared__ float red[CC*WW];

    const int tid  = threadIdx.x;
    const int l    = blockIdx.x >> 6;
    const int h    = blockIdx.x & 63;
    const int wid  = tid >> 6;
    const int lane = tid & 63;
    const int col  = lane & 15;
    const int kgrp = lane >> 4;

    {
        const unsigned int* src = (const unsigned int*)wt;
        unsigned int* dst = (unsigned int*)pw;
        #pragma unroll
        for (int j = 0; j < 18; ++j) dst[tid + j*256] = src[tid + j*256];
    }
    {
        const int rr = tid >> 6;
        const int w  = tid & 63;
        if (rr < 3){
            int hh = h - 1 + rr;
            bool hv = (hh >= 0 && hh < HH);
            const uint4* sp = (const uint4*)&f1p[(((long)l*HH + hh)*WW + w)*32];
            int wIdx = 1 + w;
            #pragma unroll
            for (int cib = 0; cib < 4; ++cib){
                uint4 p = hv ? sp[cib] : make_uint4(0,0,0,0);
                int cs = cib ^ (wIdx & 3);
                *(uint4*)&xs[(rr*66 + wIdx)*32 + cs*8] = p;
            }
        } else {
            int s = tid & 63;
            if (s < 24){
                int row = s >> 3, rest = s & 7;
                int wIdx = (rest >> 2) ? 65 : 0;
                int cib = rest & 3;
                *(uint4*)&xs[(row*66 + wIdx)*32 + cib*8] = make_uint4(0,0,0,0);
            }
        }
    }
    __syncthreads();

    #pragma unroll
    for (int u = 0; u < 2; ++u){
        int unit = wid + u*4;
        int ct   = unit >> 2;
        int wt16 = unit & 3;
        int colw = wt16*16 + col;
        f32x4 acc = {0.f,0.f,0.f,0.f};
        #pragma unroll
        for (int kh = 0; kh < 3; ++kh){
            #pragma unroll
            for (int kw = 0; kw < 3; ++kw){
                int wIdx = colw + kw;
                int cs = kgrp ^ (wIdx & 3);
                short8 b = *(const short8*)&xs[(kh*66 + wIdx)*32 + cs*8];
                short8 a = *(const short8*)&pw[((kh*3+kw)*2 + ct)*512 + lane*8];
                acc = __builtin_amdgcn_mfma_f32_16x16x32_bf16(a, b, acc, 0, 0, 0);
            }
        }
        int co0 = ct*16 + kgrp*4;
        #pragma unroll
        for (int r = 0; r < 4; ++r){
            float v = acc[r] + cb[co0+r];
            red[(co0+r)*WW + colw] = v * sigmoidf_(v);
        }
    }
    __syncthreads();
    float4* p4 = (float4*)(ws + OFF_PART + ((long)(l*HH + h))*2048);
    const float4* r4 = (const float4*)red;
    p4[tid]       = r4[tid];
    p4[tid + 256] = r4[tid + 256];
}

// ---- K2b: reduce partials over h -> colsum[l][c][w] ----
__global__ void k_colred(float* __restrict__ ws){
    int b = blockIdx.x;
    int l = b >> 5, c = b & 31;
    int w = threadIdx.x;
    const float* p = ws + OFF_PART + (long)l*HH*2048 + c*WW + w;
    float s = 0.f;
    #pragma unroll 8
    for (int h = 0; h < HH; ++h) s += p[h*2048];
    ws[OFF_COLSUM + (l*CC + c)*WW + w] = s;
}

// ---- K3: glob + adaptive pool fused ----
__global__ void k_globfeat(const float* __restrict__ gfc_w, const float* __restrict__ gfc_b,
                           float* __restrict__ ws){
    __shared__ float gs[CC], gl[CC];
    int l = blockIdx.x;
    int tid = threadIdx.x;
    if (tid < 32){
        const float* cs = ws + OFF_COLSUM + (l*CC+tid)*WW;
        float s = 0.f;
        for (int w=0;w<WW;w++) s += cs[w];
        gs[tid] = s;
    }
    __syncthreads();
    if (tid < 32){
        float acc = gfc_b[tid];
        for (int i=0;i<CC;i++) acc += gs[i]*(1.0f/4096.0f)*gfc_w[tid*CC+i];
        gl[tid] = sigmoidf_(acc);
    }
    __syncthreads();
    for (int i = tid; i < WF*CC; i += 256){
        int c = i & 31, wf = i >> 5;
        int s = (wf*64)/33;
        int e = ((wf+1)*64 + 32)/33;
        const float* cs = ws + OFF_COLSUM + (l*CC+c)*WW;
        float sum = 0.f;
        for (int w=s;w<e;w++) sum += cs[w];
        ws[OFF_FEAT + (l*WF+wf)*CC + c] = gl[c] * sum / (64.0f*(float)(e-s));
    }
}

// ---- K5: head ----
__global__ void k_head(const float* __restrict__ hw, const float* __restrict__ hb,
                       const float* __restrict__ dt, float* __restrict__ ws){
    int t = blockIdx.x*blockDim.x + threadIdx.x;
    if (t >= LL*WF*CC*RR) return;
    int r = t & 15, c = (t>>4) & 31;
    int lw_ = t >> 9;
    int wf = lw_ % WF, l = lw_ / WF;
    const float* feat = ws + OFF_FEAT + (l*WF+wf)*CC;
    int j0 = (c*RR + r)*3;
    const float* w0 = hw + j0*CC;
    float p0=hb[j0], p1=hb[j0+1], p2=hb[j0+2];
    for (int i=0;i<CC;i++){
        float fv = feat[i];
        p0 += fv*w0[i]; p1 += fv*w0[CC+i]; p2 += fv*w0[2*CC+i];
    }
    float nu = fmaxf(p0,0.f) + log1pf(expf(-fabsf(p0)));
    float th = tanhf(p1)*PI_F;
    float sg = sigmoidf_(p2);
    float dtv = dt[l];
    float decay = expf(-nu*dtv);
    float ang = th*dtv;
    float g = 1.0f - expf(-2.0f*fmaxf(dtv,0.f));
    int idx = ((l*CC+c)*WF+wf)*RR + r;
    ws[OFF_ARE+idx] = decay*cosf(ang);
    ws[OFF_AIM+idx] = decay*sinf(ang);
    ws[OFF_SGG+idx] = sg*g;
}

// ---- K6: rfft via MFMA. Block=(l,c). D[f'][h] = T2[f'][w-hi|w-lo] x X[w][h]x2 ----
__global__ __launch_bounds__(256, 4) void k_rfftm(const float* __restrict__ x,
                                                  const unsigned short* __restrict__ at,
                                                  float* __restrict__ ws){
    __shared__ __align__(16) unsigned short xs[HH*68];   // [h][w] bf16, row pad 68
    int b = blockIdx.x; int l = b >> 5, c = b & 31;
    int tid = threadIdx.x;
    const int wid  = tid >> 6;
    const int lane = tid & 63;
    const int col  = lane & 15;
    const int kgrp = lane >> 4;

    const float* xp = x + (long)(c*LL + l)*HH*WW;
    for (int i = tid; i < HH*WW; i += 256){
        int h = i >> 6, w = i & 63;
        xs[h*68 + w] = f2bf(xp[i]);
    }
    __syncthreads();

    float* xfr = ws + OFF_XFR + (long)(l*CC + c)*HH*WF;
    float* xfi = ws + OFF_XFI + (long)(l*CC + c)*HH*WF;
    // 20 units = 5 f-tiles x 4 h-tiles, over 4 waves
    #pragma unroll
    for (int q = 0; q < 5; ++q){
        int unit = wid + q*4;
        int ftile = unit >> 2;        // 0..4
        int htile = unit & 3;         // 0..3
        f32x4 acc = {0.f,0.f,0.f,0.f};
        #pragma unroll
        for (int cch = 0; cch < 4; ++cch){
            short8 a = *(const short8*)&at[(((ftile*4 + cch)*64) + lane)*8];
            short8 bb = *(const short8*)&xs[(htile*16 + col)*68 + (cch & 1)*32 + kgrp*8];
            acc = __builtin_amdgcn_mfma_f32_16x16x32_bf16(a, bb, acc, 0, 0, 0);
        }
        int h = htile*16 + col;
        #pragma unroll
        for (int r = 0; r < 4; ++r){
            int fr = ftile*16 + kgrp*4 + r;
            if (fr < 33)      xfr[fr*HH + h] = acc[r];
            else if (fr < 66) xfi[(fr-33)*HH + h] = acc[r];
        }
    }
}

// ---- K7: scan over L. Block = (c, wf) ----
__global__ __launch_bounds__(256) void k_scan(float* __restrict__ ws){
    __shared__ float lA[LL*RR], lI[LL*RR], lS[LL*RR];
    __shared__ float wv[66];
    int b = blockIdx.x;
    int c = b / WF, f = b - c*WF;
    int tid = threadIdx.x;
    if (tid < 66) wv[tid] = ws[OFF_WVEC + tid];
    {
        int l = tid >> 4, r = tid & 15;
        int src = ((l*CC + c)*WF + f)*RR + r;
        lA[tid] = ws[OFF_ARE + src];
        lI[tid] = ws[OFF_AIM + src];
        lS[tid] = ws[OFF_SGG + src];
    }
    __syncthreads();
    const int h  = tid >> 2;
    const int rq = tid & 3;
    float sre[4] = {0,0,0,0}, sim[4] = {0,0,0,0};
    float w0_[4], w1_[4], w2_[4], w3_[4];
    #pragma unroll
    for (int q=0;q<4;q++){
        int r = rq*4 + q;
        w0_[q]=wv[r]; w1_[q]=wv[16+r]; w2_[q]=wv[32+r]; w3_[q]=wv[48+r];
    }
    const float cre = wv[64], cim = wv[65];
    const long fh = (long)(c*WF + f)*HH + h;
    #pragma unroll 1
    for (int l=0;l<LL;l++){
        float xr = ws[OFF_XFR + l*(CC*HH*WF) + fh];
        float xi = ws[OFF_XFI + l*(CC*HH*WF) + fh];
        float yr = 0.f, yi = 0.f;
        #pragma unroll
        for (int q=0;q<4;q++){
            int r = rq*4 + q;
            float a = lA[l*16+r], ii = lI[l*16+r], s = lS[l*16+r];
            float nre = a*sre[q] - ii*sim[q] + s*xr;
            float nim = a*sim[q] + ii*sre[q] + s*xi;
            sre[q]=nre; sim[q]=nim;
            yr += w0_[q]*nre + w1_[q]*nim;
            yi += w2_[q]*nre + w3_[q]*nim;
        }
        yr += __shfl_xor(yr, 1); yr += __shfl_xor(yr, 2);
        yi += __shfl_xor(yi, 1); yi += __shfl_xor(yi, 2);
        if (rq == 0){
            ws[OFF_YFR + l*(CC*HH*WF) + fh] = yr + cre;
            ws[OFF_YFI + l*(CC*HH*WF) + fh] = yi + cim;
        }
    }
}

// ---- K8: irfft via MFMA. Block=(l,c). y[h][w] = M[h][f'-hi|f'-lo] x T3 ----
__global__ __launch_bounds__(256, 4) void k_irfftm(const unsigned short* __restrict__ btb,
                                                   float* __restrict__ ws){
    __shared__ __align__(16) unsigned short mh[HH*100];  // [h][f'0..95 + pad], bf16
    int b = blockIdx.x; int l = b >> 5, c = b & 31;
    int tid = threadIdx.x;
    const int wid  = tid >> 6;
    const int lane = tid & 63;
    const int col  = lane & 15;
    const int kgrp = lane >> 4;

    const float* Yr = ws + OFF_YFR + (long)(l*CC + c)*HH*WF;
    const float* Yi = ws + OFF_YFI + (long)(l*CC + c)*HH*WF;
    for (int i = tid; i < 33*64; i += 256){
        int f = i >> 6, h = i & 63;
        mh[h*100 + f]      = f2bf(Yr[i]);
        mh[h*100 + 33 + f] = f2bf(Yi[i]);
    }
    for (int i = tid; i < 64*34; i += 256){
        int h = i / 34, f = 66 + (i - (i/34)*34);
        mh[h*100 + f] = 0;
    }
    __syncthreads();

    float* y1 = ws + OFF_Y1 + (long)(l*CC + c)*HH*WW;
    // 16 units = 4 h-tiles x 4 w-tiles over 4 waves
    #pragma unroll
    for (int q = 0; q < 4; ++q){
        int unit = wid + q*4;
        int htile = unit >> 2;
        int wtile = unit & 3;
        f32x4 acc = {0.f,0.f,0.f,0.f};
        #pragma unroll
        for (int ch = 0; ch < 6; ++ch){
            int kof = (ch % 3)*32 + kgrp*8;
            short8 a = *(const short8*)&mh[(htile*16 + col)*100 + kof];
            short8 bb = *(const short8*)&btb[(((wtile*6 + ch)*64) + lane)*8];
            acc = __builtin_amdgcn_mfma_f32_16x16x32_bf16(a, bb, acc, 0, 0, 0);
        }
        int w = wtile*16 + col;
        #pragma unroll
        for (int r = 0; r < 4; ++r){
            int h = htile*16 + kgrp*4 + r;
            y1[h*WW + w] = acc[r];
        }
    }
}

// ---- K9: pif + raw W-mean (ym). Block = (l,h). ----
__global__ void k_pif(const float* __restrict__ pw, const float* __restrict__ pb,
                      float* __restrict__ ws){
    __shared__ float row[CC][WW];
    int b = blockIdx.x; int l = b>>6, h = b&63;
    int tid = threadIdx.x;
    for (int k=0;k<8;k++){
        int i = tid + k*256;
        int ci = i>>6, w = i&63;
        row[ci][w] = ws[OFF_Y1 + ((l*CC+ci)*HH + h)*WW + w];
    }
    __syncthreads();
    for (int k=0;k<8;k++){
        int i = tid + k*256;
        int o = i>>6, w = i&63;   // o wave-uniform: o = k*4 + (tid>>6)
        float acc = pb[o];
        #pragma unroll
        for (int ci=0;ci<CC;ci++) acc += pw[o*CC+ci]*row[ci][w];
        ws[OFF_Y2 + ((l*CC+o)*HH + h)*WW + w] = acc;
        float s = acc;
        s += __shfl_down(s, 32, 64); s += __shfl_down(s, 16, 64);
        s += __shfl_down(s, 8, 64);  s += __shfl_down(s, 4, 64);
        s += __shfl_down(s, 2, 64);  s += __shfl_down(s, 1, 64);
        if ((tid & 63) == 0) ws[OFF_YM + (l*HH+h)*CC + o] = s*(1.0f/64.0f);
    }
}

// ---- K10: GroupNorm stats (on raw Y2) ----
__global__ void k_gnstat(float* __restrict__ ws){
    __shared__ float rs[256], rq[256];
    int b = blockIdx.x; int l = b>>2, g = b&3;
    const float* z = ws + OFF_Y2 + (l*CC + g*8)*HH*WW;
    int tid = threadIdx.x;
    float s=0.f, q=0.f;
    for (int i=tid;i<8*HH*WW;i+=256){ float v=z[i]; s+=v; q+=v*v; }
    rs[tid]=s; rq[tid]=q; __syncthreads();
    for (int off=128; off>0; off>>=1){
        if (tid<off){ rs[tid]+=rs[tid+off]; rq[tid]+=rq[tid+off]; }
        __syncthreads();
    }
    if (tid==0){
        float mean = rs[0]/32768.0f;
        float var = rq[0]/32768.0f - mean*mean;
        ws[OFF_GNM + b] = mean;
        ws[OFF_GNR + b] = rsqrtf(var + 1e-5f);
    }
}

// ---- K12: gate MLP (normalizes raw ym inline) ----
__global__ void k_gate(const float* __restrict__ g1w, const float* __restrict__ g1b,
                       const float* __restrict__ g2w, const float* __restrict__ g2b,
                       const float* __restrict__ gnw, const float* __restrict__ gnb,
                       float* __restrict__ ws){
    int t = blockIdx.x*256 + threadIdx.x;
    if (t >= LL*HH*CC) return;
    int c = t & 31, h = (t>>5)&63, l = t>>11;
    const float* ym = ws + OFF_YM + (l*HH+h)*CC;
    float mus[4], rsd[4];
    #pragma unroll
    for (int g=0; g<4; ++g){ mus[g] = ws[OFF_GNM + l*4+g]; rsd[g] = ws[OFF_GNR + l*4+g]; }
    float ymn[CC];
    #pragma unroll
    for (int i=0;i<CC;i++){
        int g = i>>3;
        ymn[i] = (ym[i] - mus[g])*rsd[g]*gnw[i] + gnb[i];
    }
    float mid[4];
    #pragma unroll
    for (int m=0;m<4;m++){
        float a = g1b[m];
        #pragma unroll
        for (int i=0;i<CC;i++) a += ymn[i]*g1w[m*CC+i];
        mid[m] = a*sigmoidf_(a);
    }
    float a = g2b[c];
    #pragma unroll
    for (int m=0;m<4;m++) a += mid[m]*g2w[c*4+m];
    ws[OFF_GATE + t] = sigmoidf_(a);
}

// ---- K13: residual (float4), GN applied inline on raw Y2 ----
__global__ void k_final(const float* __restrict__ x, float* __restrict__ out,
                        const float* __restrict__ gnw, const float* __restrict__ gnb,
                        const float* __restrict__ ws){
    int t = blockIdx.x*256 + threadIdx.x;
    int n = t*4;
    int h = (n>>6)&63, l = (n>>12)&15, c = n>>16;
    int g = c>>3;
    float mu = ws[OFF_GNM + l*4+g], rstd = ws[OFF_GNR + l*4+g];
    float gw = gnw[c]*rstd, gb = gnb[c] - mu*gnw[c]*rstd;
    float4 z  = *(const float4*)(ws + OFF_Y2 + (((l*CC+c)*HH+h)*WW) + (n&63));
    float  gt = ws[OFF_GATE + (l*HH+h)*CC + c];
    float4 xv = *(const float4*)(x + n);
    float4 o;
    o.x = xv.x + (z.x*gw+gb)*gt; o.y = xv.y + (z.y*gw+gb)*gt;
    o.z = xv.z + (z.z*gw+gb)*gt; o.w = xv.w + (z.w*gw+gb)*gt;
    *(float4*)(out + n) = o;
}

extern "C" void kernel_launch(void* const* d_in, const int* in_sizes, int n_in,
                              void* d_out, int out_size, void* d_ws, size_t ws_size,
                              hipStream_t stream){
    const float* x    = (const float*)d_in[0];
    const float* dt   = (const float*)d_in[1];
    const float* c1w  = (const float*)d_in[2];
    const float* c1b  = (const float*)d_in[3];
    const float* c2w  = (const float*)d_in[4];
    const float* c2b  = (const float*)d_in[5];
    const float* gfcw = (const float*)d_in[6];
    const float* gfcb = (const float*)d_in[7];
    const float* hw   = (const float*)d_in[8];
    const float* hb   = (const float*)d_in[9];
    const float* mixw = (const float*)d_in[10];
    const float* mixb = (const float*)d_in[11];
    const float* rs   = (const float*)d_in[12];
    const float* pjw  = (const float*)d_in[13];
    const float* pjb  = (const float*)d_in[14];
    const float* pifw = (const float*)d_in[15];
    const float* pifb = (const float*)d_in[16];
    const float* gnw  = (const float*)d_in[17];
    const float* gnb  = (const float*)d_in[18];
    const float* g1w  = (const float*)d_in[19];
    const float* g1b  = (const float*)d_in[20];
    const float* g2w  = (const float*)d_in[21];
    const float* g2b  = (const float*)d_in[22];
    float* ws  = (float*)d_ws;
    float* out = (float*)d_out;
    unsigned short* wt  = (unsigned short*)(ws + OFF_WT);
    unsigned short* at  = wt + 18432;
    unsigned short* btb = wt + 18432 + 10240;
    unsigned short* f1p = (unsigned short*)(ws + OFF_F1);

    k_prep0   <<<161,  256, 0, stream>>>(mixw, mixb, rs, pjw, pjb, c1w, c2w, ws);
    k_conv1m  <<<1024, 256, 0, stream>>>(x, wt, c1b, f1p);
    k_conv2m  <<<1024, 256, 0, stream>>>(f1p, wt + 9216, c2b, ws);
    k_colred  <<<512,  64,  0, stream>>>(ws);
    k_globfeat<<<16,   256, 0, stream>>>(gfcw, gfcb, ws);
    k_head    <<<1056, 256, 0, stream>>>(hw, hb, dt, ws);
    k_rfftm   <<<512,  256, 0, stream>>>(x, at, ws);
    k_scan    <<<1056, 256, 0, stream>>>(ws);
    k_irfftm  <<<512,  256, 0, stream>>>(btb, ws);
    k_pif     <<<1024, 256, 0, stream>>>(pifw, pifb, ws);
    k_gnstat  <<<64,   256, 0, stream>>>(ws);
    k_gate    <<<128,  256, 0, stream>>>(g1w, g1b, g2w, g2b, gnw, gnb, ws);
    k_final   <<<2048, 256, 0, stream>>>(x, out, gnw, gnb, ws);
}

// Round 11
// 208.249 us; speedup vs baseline: 5.5924x; 1.1477x over previous
//
#include <hip/hip_runtime.h>
#include <hip/hip_bf16.h>
#include <math.h>

#define CC 32
#define LL 16
#define HH 64
#define WW 64
#define WF 33
#define RR 16
#define PI_F 3.14159265358979323846f

typedef __attribute__((ext_vector_type(8))) short short8;
typedef __attribute__((ext_vector_type(4))) float f32x4;

// ---- workspace layout (floats). Regions reused across phases. ----
#define OFF_F1      0          // f1 packed bf16 [l][h][w][ci]; later reused as Y2 (fp32)
#define OFF_COLSUM  2097152    // 32768    [l][c][w]
#define OFF_FEAT    2130944    // 16896    [l][wf][c]
#define OFF_ARE     2147840    // 270336   [l][c][wf][r]
#define OFF_AIM     2418176    // 270336
#define OFF_SGG     2688512    // 270336
#define OFF_XFR     2958848    // 1081344  [l][c][f][h]
#define OFF_XFI     4040192    // 1081344
#define OFF_YFR     5121536    // 1081344  [l][c][f][h]
#define OFF_YFI     6202880    // 1081344
#define OFF_PART    2958848    // 2097152  conv2 partials (dead XFR/XFI region, consumed pre-rfft)
#define OFF_Y1      2958848    // 2097152  irfft out (overlaps dead XFR/XFI)
#define OFF_Y2      0          // 2097152  pif raw out (overlaps dead F1)
#define OFF_GNM     7284224    // 64
#define OFF_GNR     7284288    // 64
#define OFF_YM      7284352    // 32768    [l][h][c] RAW w-means of Y2
#define OFF_GATE    7317120    // 32768
#define OFF_WVEC    7349888    // 66
#define OFF_WT      7350016    // ushort region: conv(18432) + AT(10240) + BT(12288) = 40960 u16 = 20480 f
#define OFF_YQ      7370496    // 32768    [l][h][c] row sum-of-squares of Y2
// total ~29.6 MB

__device__ __forceinline__ float sigmoidf_(float x){ return 1.0f/(1.0f+expf(-x)); }
__device__ __forceinline__ unsigned short f2bf(float v){
    __hip_bfloat16 b = __float2bfloat16(v);
    return *reinterpret_cast<unsigned short*>(&b);
}
__device__ __forceinline__ float bf2f(unsigned short u){
    __hip_bfloat16 b = *reinterpret_cast<__hip_bfloat16*>(&u);
    return __bfloat162float(b);
}

// ---- K0: all precompute: wvec, conv weight pack, rfft A-table, irfft B-table ----
__global__ void k_prep0(const float* __restrict__ mix_w, const float* __restrict__ mix_b,
                        const float* __restrict__ rank_scale, const float* __restrict__ proj_w,
                        const float* __restrict__ proj_b,
                        const float* __restrict__ c1w, const float* __restrict__ c2w,
                        float* __restrict__ ws){
    unsigned short* wt = (unsigned short*)(ws + OFF_WT);
    if (blockIdx.x == 0){
        float* wv = ws + OFF_WVEC;
        int t = threadIdx.x;
        if (t < 32){
            float sre=0.f, sim=0.f;
            for (int r=0;r<RR;r++){
                float a = proj_w[r]*rank_scale[r];
                sre += a*mix_w[r*2*RR + t];
                sim += a*mix_w[(RR+r)*2*RR + t];
            }
            wv[t] = sre; wv[32+t] = sim;
        }
        if (t == 0){
            float cre=0.f, cim=0.f;
            for (int r=0;r<RR;r++){
                float a = proj_w[r]*rank_scale[r];
                cre += a*mix_b[r];
                cim += a*mix_b[RR+r];
            }
            wv[64] = cre + proj_b[0]; wv[65] = cim;
        }
        return;
    }
    int i = (blockIdx.x-1)*256 + threadIdx.x;
    if (i < 18432){
        int which = (i >= 9216);
        int j = which ? i - 9216 : i;
        int je   = j & 7;
        int lane = (j >> 3) & 63;
        int ct   = (j >> 9) & 1;
        int tap  = j >> 10;
        int kh = tap/3, kw = tap - kh*3;
        int co = ct*16 + (lane & 15);
        int ci = (lane >> 4)*8 + je;
        const float* cw = which ? c2w : c1w;
        wt[i] = f2bf(cw[((co*CC + ci)*3 + kh)*3 + kw]);
        return;
    }
    i -= 18432;
    if (i < 10240){
        int j = i & 7, lane = (i>>3)&63, cch = (i>>9)&3, t = i>>11;
        int frow = t*16 + (lane & 15);
        int k = ((lane>>4)&3)*8 + j;
        int w = (cch & 1)*32 + k;
        float coef = 0.f;
        if (frow < 33)       coef =  cosf(2.0f*PI_F*(float)(frow*w)/64.0f);
        else if (frow < 66)  coef = -sinf(2.0f*PI_F*(float)((frow-33)*w)/64.0f);
        unsigned short hi = f2bf(coef);
        wt[18432 + i] = (cch < 2) ? hi : f2bf(coef - bf2f(hi));
        return;
    }
    i -= 10240;
    if (i < 12288){
        int wtile = i / 3072;
        int rem = i - wtile*3072;
        int ch = rem >> 9;
        int ll = rem & 511;
        int lane = ll >> 3, j = ll & 7;
        int w = wtile*16 + (lane & 15);
        int k = (ch % 3)*32 + ((lane>>4)&3)*8 + j;
        float coef = 0.f;
        if (k < 33){
            float s = (k==0 || k==32) ? 1.f : 2.f;
            coef = s*cosf(2.0f*PI_F*(float)(k*w)/64.0f)*(1.0f/64.0f);
        } else if (k < 66){
            int f = k - 33;
            float s = (f==0 || f==32) ? 1.f : 2.f;
            coef = -s*sinf(2.0f*PI_F*(float)(f*w)/64.0f)*(1.0f/64.0f);
        }
        unsigned short hi = f2bf(coef);
        wt[18432 + 10240 + i] = (ch < 3) ? hi : f2bf(coef - bf2f(hi));
        return;
    }
}

// ---- K1: conv1 (MFMA, bf16). Block = (l, h-tile of 2). Grid 512. ----
__global__ __launch_bounds__(256, 4) void k_conv1m(const float* __restrict__ x,
                                                   const unsigned short* __restrict__ wt,
                                                   const float* __restrict__ cb,
                                                   unsigned short* __restrict__ f1p){
    __shared__ __align__(16) unsigned short xs[4*66*32];  // rows h0-1..h0+2
    __shared__ __align__(16) unsigned short pw[9216];

    const int tid  = threadIdx.x;
    const int l    = blockIdx.x >> 5;
    const int h0   = (blockIdx.x & 31)*2;
    const int wid  = tid >> 6;
    const int lane = tid & 63;
    const int col  = lane & 15;
    const int kgrp = lane >> 4;

    {
        const unsigned int* src = (const unsigned int*)wt;
        unsigned int* dst = (unsigned int*)pw;
        #pragma unroll
        for (int j = 0; j < 18; ++j) dst[tid + j*256] = src[tid + j*256];
    }
    {
        const int rr = tid >> 6;          // 0..3 -> rows h0-1..h0+2
        const int w  = tid & 63;
        int hh = h0 - 1 + rr;
        bool hv = (hh >= 0 && hh < HH);
        const float* sp = x + (long)l*HH*WW + hh*WW + w;
        int wIdx = 1 + w;
        #pragma unroll
        for (int cib = 0; cib < 4; ++cib){
            float v[8];
            #pragma unroll
            for (int k = 0; k < 8; ++k)
                v[k] = hv ? sp[(long)(cib*8 + k)*LL*HH*WW] : 0.f;
            uint4 p;
            p.x = (unsigned)f2bf(v[0]) | ((unsigned)f2bf(v[1])<<16);
            p.y = (unsigned)f2bf(v[2]) | ((unsigned)f2bf(v[3])<<16);
            p.z = (unsigned)f2bf(v[4]) | ((unsigned)f2bf(v[5])<<16);
            p.w = (unsigned)f2bf(v[6]) | ((unsigned)f2bf(v[7])<<16);
            int cs = cib ^ (wIdx & 3);
            *(uint4*)&xs[(rr*66 + wIdx)*32 + cs*8] = p;
        }
    }
    if (tid < 32){   // halo columns, 4 rows x 2 cols x 4 cib
        int row = tid >> 3, rest = tid & 7;
        int wIdx = (rest >> 2) ? 65 : 0;
        int cib = rest & 3;
        *(uint4*)&xs[(row*66 + wIdx)*32 + cib*8] = make_uint4(0,0,0,0);
    }
    __syncthreads();

    #pragma unroll
    for (int u = 0; u < 4; ++u){
        int unit = wid + u*4;             // 0..15
        int hloc = unit >> 3;             // 0..1
        int rem  = unit & 7;
        int ct   = rem >> 2;
        int wt16 = rem & 3;
        int colw = wt16*16 + col;
        f32x4 acc = {0.f,0.f,0.f,0.f};
        #pragma unroll
        for (int kh = 0; kh < 3; ++kh){
            #pragma unroll
            for (int kw = 0; kw < 3; ++kw){
                int wIdx = colw + kw;
                int cs = kgrp ^ (wIdx & 3);
                short8 b = *(const short8*)&xs[((hloc+kh)*66 + wIdx)*32 + cs*8];
                short8 a = *(const short8*)&pw[((kh*3+kw)*2 + ct)*512 + lane*8];
                acc = __builtin_amdgcn_mfma_f32_16x16x32_bf16(a, b, acc, 0, 0, 0);
            }
        }
        int co0 = ct*16 + kgrp*4;
        int h = h0 + hloc;
        float o[4];
        #pragma unroll
        for (int r = 0; r < 4; ++r){
            float v = acc[r] + cb[co0+r];
            o[r] = v * sigmoidf_(v);
        }
        uint2 pk;
        pk.x = (unsigned)f2bf(o[0]) | ((unsigned)f2bf(o[1])<<16);
        pk.y = (unsigned)f2bf(o[2]) | ((unsigned)f2bf(o[3])<<16);
        *(uint2*)&f1p[(((long)l*HH + h)*WW + colw)*32 + co0] = pk;
    }
}

// ---- K2: conv2 (MFMA, bf16) -> PART directly (no LDS bounce). Grid 512. ----
__global__ __launch_bounds__(256, 4) void k_conv2m(const unsigned short* __restrict__ f1p,
                                                   const unsigned short* __restrict__ wt,
                                                   const float* __restrict__ cb,
                                                   float* __restrict__ ws){
    __shared__ __align__(16) unsigned short xs[4*66*32];
    __shared__ __align__(16) unsigned short pw[9216];

    const int tid  = threadIdx.x;
    const int l    = blockIdx.x >> 5;
    const int h0   = (blockIdx.x & 31)*2;
    const int wid  = tid >> 6;
    const int lane = tid & 63;
    const int col  = lane & 15;
    const int kgrp = lane >> 4;

    {
        const unsigned int* src = (const unsigned int*)wt;
        unsigned int* dst = (unsigned int*)pw;
        #pragma unroll
        for (int j = 0; j < 18; ++j) dst[tid + j*256] = src[tid + j*256];
    }
    {
        const int rr = tid >> 6;
        const int w  = tid & 63;
        int hh = h0 - 1 + rr;
        bool hv = (hh >= 0 && hh < HH);
        const uint4* sp = (const uint4*)&f1p[(((long)l*HH + hh)*WW + w)*32];
        int wIdx = 1 + w;
        #pragma unroll
        for (int cib = 0; cib < 4; ++cib){
            uint4 p = hv ? sp[cib] : make_uint4(0,0,0,0);
            int cs = cib ^ (wIdx & 3);
            *(uint4*)&xs[(rr*66 + wIdx)*32 + cs*8] = p;
        }
    }
    if (tid < 32){
        int row = tid >> 3, rest = tid & 7;
        int wIdx = (rest >> 2) ? 65 : 0;
        int cib = rest & 3;
        *(uint4*)&xs[(row*66 + wIdx)*32 + cib*8] = make_uint4(0,0,0,0);
    }
    __syncthreads();

    #pragma unroll
    for (int u = 0; u < 4; ++u){
        int unit = wid + u*4;
        int hloc = unit >> 3;
        int rem  = unit & 7;
        int ct   = rem >> 2;
        int wt16 = rem & 3;
        int colw = wt16*16 + col;
        f32x4 acc = {0.f,0.f,0.f,0.f};
        #pragma unroll
        for (int kh = 0; kh < 3; ++kh){
            #pragma unroll
            for (int kw = 0; kw < 3; ++kw){
                int wIdx = colw + kw;
                int cs = kgrp ^ (wIdx & 3);
                short8 b = *(const short8*)&xs[((hloc+kh)*66 + wIdx)*32 + cs*8];
                short8 a = *(const short8*)&pw[((kh*3+kw)*2 + ct)*512 + lane*8];
                acc = __builtin_amdgcn_mfma_f32_16x16x32_bf16(a, b, acc, 0, 0, 0);
            }
        }
        int co0 = ct*16 + kgrp*4;
        int h = h0 + hloc;
        float* pp = ws + OFF_PART + ((long)(l*HH + h))*2048 + colw;
        #pragma unroll
        for (int r = 0; r < 4; ++r){
            float v = acc[r] + cb[co0+r];
            pp[(co0+r)*WW] = v * sigmoidf_(v);
        }
    }
}

// ---- K2b: reduce partials over h -> colsum[l][c][w] ----
__global__ void k_colred(float* __restrict__ ws){
    int b = blockIdx.x;
    int l = b >> 5, c = b & 31;
    int w = threadIdx.x;
    const float* p = ws + OFF_PART + (long)l*HH*2048 + c*WW + w;
    float s = 0.f;
    #pragma unroll 8
    for (int h = 0; h < HH; ++h) s += p[h*2048];
    ws[OFF_COLSUM + (l*CC + c)*WW + w] = s;
}

// ---- K3: glob + adaptive pool fused ----
__global__ void k_globfeat(const float* __restrict__ gfc_w, const float* __restrict__ gfc_b,
                           float* __restrict__ ws){
    __shared__ float gs[CC], gl[CC];
    int l = blockIdx.x;
    int tid = threadIdx.x;
    if (tid < 32){
        const float* cs = ws + OFF_COLSUM + (l*CC+tid)*WW;
        float s = 0.f;
        for (int w=0;w<WW;w++) s += cs[w];
        gs[tid] = s;
    }
    __syncthreads();
    if (tid < 32){
        float acc = gfc_b[tid];
        for (int i=0;i<CC;i++) acc += gs[i]*(1.0f/4096.0f)*gfc_w[tid*CC+i];
        gl[tid] = sigmoidf_(acc);
    }
    __syncthreads();
    for (int i = tid; i < WF*CC; i += 256){
        int c = i & 31, wf = i >> 5;
        int s = (wf*64)/33;
        int e = ((wf+1)*64 + 32)/33;
        const float* cs = ws + OFF_COLSUM + (l*CC+c)*WW;
        float sum = 0.f;
        for (int w=s;w<e;w++) sum += cs[w];
        ws[OFF_FEAT + (l*WF+wf)*CC + c] = gl[c] * sum / (64.0f*(float)(e-s));
    }
}

// ---- K5: head ----
__global__ void k_head(const float* __restrict__ hw, const float* __restrict__ hb,
                       const float* __restrict__ dt, float* __restrict__ ws){
    int t = blockIdx.x*blockDim.x + threadIdx.x;
    if (t >= LL*WF*CC*RR) return;
    int r = t & 15, c = (t>>4) & 31;
    int lw_ = t >> 9;
    int wf = lw_ % WF, l = lw_ / WF;
    const float* feat = ws + OFF_FEAT + (l*WF+wf)*CC;
    int j0 = (c*RR + r)*3;
    const float* w0 = hw + j0*CC;
    float p0=hb[j0], p1=hb[j0+1], p2=hb[j0+2];
    for (int i=0;i<CC;i++){
        float fv = feat[i];
        p0 += fv*w0[i]; p1 += fv*w0[CC+i]; p2 += fv*w0[2*CC+i];
    }
    float nu = fmaxf(p0,0.f) + log1pf(expf(-fabsf(p0)));
    float th = tanhf(p1)*PI_F;
    float sg = sigmoidf_(p2);
    float dtv = dt[l];
    float decay = expf(-nu*dtv);
    float ang = th*dtv;
    float g = 1.0f - expf(-2.0f*fmaxf(dtv,0.f));
    int idx = ((l*CC+c)*WF+wf)*RR + r;
    ws[OFF_ARE+idx] = decay*cosf(ang);
    ws[OFF_AIM+idx] = decay*sinf(ang);
    ws[OFF_SGG+idx] = sg*g;
}

// ---- K6: rfft via MFMA. Block=(l,c). ----
__global__ __launch_bounds__(256, 4) void k_rfftm(const float* __restrict__ x,
                                                  const unsigned short* __restrict__ at,
                                                  float* __restrict__ ws){
    __shared__ __align__(16) unsigned short xs[HH*68];
    int b = blockIdx.x; int l = b >> 5, c = b & 31;
    int tid = threadIdx.x;
    const int wid  = tid >> 6;
    const int lane = tid & 63;
    const int col  = lane & 15;
    const int kgrp = lane >> 4;

    const float* xp = x + (long)(c*LL + l)*HH*WW;
    for (int i = tid; i < HH*WW; i += 256){
        int h = i >> 6, w = i & 63;
        xs[h*68 + w] = f2bf(xp[i]);
    }
    __syncthreads();

    float* xfr = ws + OFF_XFR + (long)(l*CC + c)*HH*WF;
    float* xfi = ws + OFF_XFI + (long)(l*CC + c)*HH*WF;
    #pragma unroll
    for (int q = 0; q < 5; ++q){
        int unit = wid + q*4;
        int ftile = unit >> 2;
        int htile = unit & 3;
        f32x4 acc = {0.f,0.f,0.f,0.f};
        #pragma unroll
        for (int cch = 0; cch < 4; ++cch){
            short8 a = *(const short8*)&at[(((ftile*4 + cch)*64) + lane)*8];
            short8 bb = *(const short8*)&xs[(htile*16 + col)*68 + (cch & 1)*32 + kgrp*8];
            acc = __builtin_amdgcn_mfma_f32_16x16x32_bf16(a, bb, acc, 0, 0, 0);
        }
        int h = htile*16 + col;
        #pragma unroll
        for (int r = 0; r < 4; ++r){
            int fr = ftile*16 + kgrp*4 + r;
            if (fr < 33)      xfr[fr*HH + h] = acc[r];
            else if (fr < 66) xfi[(fr-33)*HH + h] = acc[r];
        }
    }
}

// ---- K7: scan over L. Block = (c, wf) ----
__global__ __launch_bounds__(256) void k_scan(float* __restrict__ ws){
    __shared__ float lA[LL*RR], lI[LL*RR], lS[LL*RR];
    __shared__ float wv[66];
    int b = blockIdx.x;
    int c = b / WF, f = b - c*WF;
    int tid = threadIdx.x;
    if (tid < 66) wv[tid] = ws[OFF_WVEC + tid];
    {
        int l = tid >> 4, r = tid & 15;
        int src = ((l*CC + c)*WF + f)*RR + r;
        lA[tid] = ws[OFF_ARE + src];
        lI[tid] = ws[OFF_AIM + src];
        lS[tid] = ws[OFF_SGG + src];
    }
    __syncthreads();
    const int h  = tid >> 2;
    const int rq = tid & 3;
    float sre[4] = {0,0,0,0}, sim[4] = {0,0,0,0};
    float w0_[4], w1_[4], w2_[4], w3_[4];
    #pragma unroll
    for (int q=0;q<4;q++){
        int r = rq*4 + q;
        w0_[q]=wv[r]; w1_[q]=wv[16+r]; w2_[q]=wv[32+r]; w3_[q]=wv[48+r];
    }
    const float cre = wv[64], cim = wv[65];
    const long fh = (long)(c*WF + f)*HH + h;
    #pragma unroll 1
    for (int l=0;l<LL;l++){
        float xr = ws[OFF_XFR + l*(CC*HH*WF) + fh];
        float xi = ws[OFF_XFI + l*(CC*HH*WF) + fh];
        float yr = 0.f, yi = 0.f;
        #pragma unroll
        for (int q=0;q<4;q++){
            int r = rq*4 + q;
            float a = lA[l*16+r], ii = lI[l*16+r], s = lS[l*16+r];
            float nre = a*sre[q] - ii*sim[q] + s*xr;
            float nim = a*sim[q] + ii*sre[q] + s*xi;
            sre[q]=nre; sim[q]=nim;
            yr += w0_[q]*nre + w1_[q]*nim;
            yi += w2_[q]*nre + w3_[q]*nim;
        }
        yr += __shfl_xor(yr, 1); yr += __shfl_xor(yr, 2);
        yi += __shfl_xor(yi, 1); yi += __shfl_xor(yi, 2);
        if (rq == 0){
            ws[OFF_YFR + l*(CC*HH*WF) + fh] = yr + cre;
            ws[OFF_YFI + l*(CC*HH*WF) + fh] = yi + cim;
        }
    }
}

// ---- K8: irfft via MFMA. Block=(l,c). ----
__global__ __launch_bounds__(256, 4) void k_irfftm(const unsigned short* __restrict__ btb,
                                                   float* __restrict__ ws){
    __shared__ __align__(16) unsigned short mh[HH*100];
    int b = blockIdx.x; int l = b >> 5, c = b & 31;
    int tid = threadIdx.x;
    const int wid  = tid >> 6;
    const int lane = tid & 63;
    const int col  = lane & 15;
    const int kgrp = lane >> 4;

    const float* Yr = ws + OFF_YFR + (long)(l*CC + c)*HH*WF;
    const float* Yi = ws + OFF_YFI + (long)(l*CC + c)*HH*WF;
    for (int i = tid; i < 33*64; i += 256){
        int f = i >> 6, h = i & 63;
        mh[h*100 + f]      = f2bf(Yr[i]);
        mh[h*100 + 33 + f] = f2bf(Yi[i]);
    }
    for (int i = tid; i < 64*34; i += 256){
        int h = i / 34, f = 66 + (i - (i/34)*34);
        mh[h*100 + f] = 0;
    }
    __syncthreads();

    float* y1 = ws + OFF_Y1 + (long)(l*CC + c)*HH*WW;
    #pragma unroll
    for (int q = 0; q < 4; ++q){
        int unit = wid + q*4;
        int htile = unit >> 2;
        int wtile = unit & 3;
        f32x4 acc = {0.f,0.f,0.f,0.f};
        #pragma unroll
        for (int ch = 0; ch < 6; ++ch){
            int kof = (ch % 3)*32 + kgrp*8;
            short8 a = *(const short8*)&mh[(htile*16 + col)*100 + kof];
            short8 bb = *(const short8*)&btb[(((wtile*6 + ch)*64) + lane)*8];
            acc = __builtin_amdgcn_mfma_f32_16x16x32_bf16(a, bb, acc, 0, 0, 0);
        }
        int w = wtile*16 + col;
        #pragma unroll
        for (int r = 0; r < 4; ++r){
            int h = htile*16 + kgrp*4 + r;
            y1[h*WW + w] = acc[r];
        }
    }
}

// ---- K9: pif + raw W-mean (YM) + row sum-of-squares (YQ). Block = (l,h). ----
__global__ void k_pif(const float* __restrict__ pw, const float* __restrict__ pb,
                      float* __restrict__ ws){
    __shared__ float row[CC][WW];
    int b = blockIdx.x; int l = b>>6, h = b&63;
    int tid = threadIdx.x;
    for (int k=0;k<8;k++){
        int i = tid + k*256;
        int ci = i>>6, w = i&63;
        row[ci][w] = ws[OFF_Y1 + ((l*CC+ci)*HH + h)*WW + w];
    }
    __syncthreads();
    for (int k=0;k<8;k++){
        int i = tid + k*256;
        int o = i>>6, w = i&63;   // o wave-uniform
        float acc = pb[o];
        #pragma unroll
        for (int ci=0;ci<CC;ci++) acc += pw[o*CC+ci]*row[ci][w];
        ws[OFF_Y2 + ((l*CC+o)*HH + h)*WW + w] = acc;
        float s = acc, q = acc*acc;
        s += __shfl_down(s, 32, 64); q += __shfl_down(q, 32, 64);
        s += __shfl_down(s, 16, 64); q += __shfl_down(q, 16, 64);
        s += __shfl_down(s,  8, 64); q += __shfl_down(q,  8, 64);
        s += __shfl_down(s,  4, 64); q += __shfl_down(q,  4, 64);
        s += __shfl_down(s,  2, 64); q += __shfl_down(q,  2, 64);
        s += __shfl_down(s,  1, 64); q += __shfl_down(q,  1, 64);
        if ((tid & 63) == 0){
            ws[OFF_YM + (l*HH+h)*CC + o] = s*(1.0f/64.0f);
            ws[OFF_YQ + (l*HH+h)*CC + o] = q;
        }
    }
}

// ---- K10: GroupNorm stats from row moments (reads 0.26 MB, not 8.4 MB) ----
__global__ void k_gnred(float* __restrict__ ws){
    __shared__ float rs[256], rq[256];
    int b = blockIdx.x; int l = b>>2, g = b&3;
    int tid = threadIdx.x;
    float s=0.f, q=0.f;
    for (int j = tid; j < 512; j += 256){
        int h = j >> 3, cc = j & 7;
        int off = (l*HH+h)*CC + g*8 + cc;
        s += ws[OFF_YM + off];
        q += ws[OFF_YQ + off];
    }
    rs[tid]=s; rq[tid]=q; __syncthreads();
    for (int off=128; off>0; off>>=1){
        if (tid<off){ rs[tid]+=rs[tid+off]; rq[tid]+=rq[tid+off]; }
        __syncthreads();
    }
    if (tid==0){
        float mean = rs[0]*(1.0f/512.0f);          // YM entries are w-means
        float ex2  = rq[0]*(1.0f/32768.0f);        // YQ entries are w-sumsq
        float var = ex2 - mean*mean;
        ws[OFF_GNM + b] = mean;
        ws[OFF_GNR + b] = rsqrtf(var + 1e-5f);
    }
}

// ---- K12: gate MLP (normalizes raw ym inline) ----
__global__ void k_gate(const float* __restrict__ g1w, const float* __restrict__ g1b,
                       const float* __restrict__ g2w, const float* __restrict__ g2b,
                       const float* __restrict__ gnw, const float* __restrict__ gnb,
                       float* __restrict__ ws){
    int t = blockIdx.x*256 + threadIdx.x;
    if (t >= LL*HH*CC) return;
    int c = t & 31, h = (t>>5)&63, l = t>>11;
    const float* ym = ws + OFF_YM + (l*HH+h)*CC;
    float mus[4], rsd[4];
    #pragma unroll
    for (int g=0; g<4; ++g){ mus[g] = ws[OFF_GNM + l*4+g]; rsd[g] = ws[OFF_GNR + l*4+g]; }
    float ymn[CC];
    #pragma unroll
    for (int i=0;i<CC;i++){
        int g = i>>3;
        ymn[i] = (ym[i] - mus[g])*rsd[g]*gnw[i] + gnb[i];
    }
    float mid[4];
    #pragma unroll
    for (int m=0;m<4;m++){
        float a = g1b[m];
        #pragma unroll
        for (int i=0;i<CC;i++) a += ymn[i]*g1w[m*CC+i];
        mid[m] = a*sigmoidf_(a);
    }
    float a = g2b[c];
    #pragma unroll
    for (int m=0;m<4;m++) a += mid[m]*g2w[c*4+m];
    ws[OFF_GATE + t] = sigmoidf_(a);
}

// ---- K13: residual (float4), GN applied inline on raw Y2 ----
__global__ void k_final(const float* __restrict__ x, float* __restrict__ out,
                        const float* __restrict__ gnw, const float* __restrict__ gnb,
                        const float* __restrict__ ws){
    int t = blockIdx.x*256 + threadIdx.x;
    int n = t*4;
    int h = (n>>6)&63, l = (n>>12)&15, c = n>>16;
    int g = c>>3;
    float mu = ws[OFF_GNM + l*4+g], rstd = ws[OFF_GNR + l*4+g];
    float gw = gnw[c]*rstd, gb = gnb[c] - mu*gnw[c]*rstd;
    float4 z  = *(const float4*)(ws + OFF_Y2 + (((l*CC+c)*HH+h)*WW) + (n&63));
    float  gt = ws[OFF_GATE + (l*HH+h)*CC + c];
    float4 xv = *(const float4*)(x + n);
    float4 o;
    o.x = xv.x + (z.x*gw+gb)*gt; o.y = xv.y + (z.y*gw+gb)*gt;
    o.z = xv.z + (z.z*gw+gb)*gt; o.w = xv.w + (z.w*gw+gb)*gt;
    *(float4*)(out + n) = o;
}

extern "C" void kernel_launch(void* const* d_in, const int* in_sizes, int n_in,
                              void* d_out, int out_size, void* d_ws, size_t ws_size,
                              hipStream_t stream){
    const float* x    = (const float*)d_in[0];
    const float* dt   = (const float*)d_in[1];
    const float* c1w  = (const float*)d_in[2];
    const float* c1b  = (const float*)d_in[3];
    const float* c2w  = (const float*)d_in[4];
    const float* c2b  = (const float*)d_in[5];
    const float* gfcw = (const float*)d_in[6];
    const float* gfcb = (const float*)d_in[7];
    const float* hw   = (const float*)d_in[8];
    const float* hb   = (const float*)d_in[9];
    const float* mixw = (const float*)d_in[10];
    const float* mixb = (const float*)d_in[11];
    const float* rs   = (const float*)d_in[12];
    const float* pjw  = (const float*)d_in[13];
    const float* pjb  = (const float*)d_in[14];
    const float* pifw = (const float*)d_in[15];
    const float* pifb = (const float*)d_in[16];
    const float* gnw  = (const float*)d_in[17];
    const float* gnb  = (const float*)d_in[18];
    const float* g1w  = (const float*)d_in[19];
    const float* g1b  = (const float*)d_in[20];
    const float* g2w  = (const float*)d_in[21];
    const float* g2b  = (const float*)d_in[22];
    float* ws  = (float*)d_ws;
    float* out = (float*)d_out;
    unsigned short* wt  = (unsigned short*)(ws + OFF_WT);
    unsigned short* at  = wt + 18432;
    unsigned short* btb = wt + 18432 + 10240;
    unsigned short* f1p = (unsigned short*)(ws + OFF_F1);

    k_prep0   <<<161,  256, 0, stream>>>(mixw, mixb, rs, pjw, pjb, c1w, c2w, ws);
    k_conv1m  <<<512,  256, 0, stream>>>(x, wt, c1b, f1p);
    k_conv2m  <<<512,  256, 0, stream>>>(f1p, wt + 9216, c2b, ws);
    k_colred  <<<512,  64,  0, stream>>>(ws);
    k_globfeat<<<16,   256, 0, stream>>>(gfcw, gfcb, ws);
    k_head    <<<1056, 256, 0, stream>>>(hw, hb, dt, ws);
    k_rfftm   <<<512,  256, 0, stream>>>(x, at, ws);
    k_scan    <<<1056, 256, 0, stream>>>(ws);
    k_irfftm  <<<512,  256, 0, stream>>>(btb, ws);
    k_pif     <<<1024, 256, 0, stream>>>(pifw, pifb, ws);
    k_gnred   <<<64,   256, 0, stream>>>(ws);
    k_gate    <<<128,  256, 0, stream>>>(g1w, g1b, g2w, g2b, gnw, gnb, ws);
    k_final   <<<2048, 256, 0, stream>>>(x, out, gnw, gnb, ws);
}

// Round 12
// 201.441 us; speedup vs baseline: 5.7814x; 1.0338x over previous
//
#include <hip/hip_runtime.h>
#include <hip/hip_bf16.h>
#include <math.h>

#define CC 32
#define LL 16
#define HH 64
#define WW 64
#define WF 33
#define RR 16
#define PI_F 3.14159265358979323846f

typedef __attribute__((ext_vector_type(8))) short short8;
typedef __attribute__((ext_vector_type(4))) float f32x4;

// ---- workspace layout (floats). Regions reused across phases. ----
#define OFF_F1      0          // f1 packed bf16 [l][h][w][ci]; later reused as Y2 (fp32)
#define OFF_COLSUM  2097152    // 32768    [l][c][w]
#define OFF_FEAT    2130944    // 16896    [l][wf][c]
#define OFF_XFR     2958848    // 1081344  [l][c][f][h]
#define OFF_XFI     4040192    // 1081344
#define OFF_YFR     5121536    // 1081344  [l][c][f][h]
#define OFF_YFI     6202880    // 1081344
#define OFF_PART    2958848    // 2097152  conv2 partials (dead XFR/XFI region, consumed pre-rfft)
#define OFF_Y1      2958848    // 2097152  irfft out (overlaps dead XFR/XFI)
#define OFF_Y2      0          // 2097152  pif raw out (overlaps dead F1)
#define OFF_GNM     7284224    // 64
#define OFF_GNR     7284288    // 64
#define OFF_YM      7284352    // 32768    [l][h][c] RAW w-means of Y2
#define OFF_GATE    7317120    // 32768
#define OFF_WVEC    7349888    // 66
#define OFF_WT      7350016    // ushort region: conv(18432) + AT(10240) + BT(12288) = 40960 u16 = 20480 f
#define OFF_YQ      7370496    // 32768    [l][h][c] row sum-of-squares of Y2
// total ~29.6 MB

__device__ __forceinline__ float sigmoidf_(float x){ return 1.0f/(1.0f+expf(-x)); }
__device__ __forceinline__ unsigned short f2bf(float v){
    __hip_bfloat16 b = __float2bfloat16(v);
    return *reinterpret_cast<unsigned short*>(&b);
}
__device__ __forceinline__ float bf2f(unsigned short u){
    __hip_bfloat16 b = *reinterpret_cast<__hip_bfloat16*>(&u);
    return __bfloat162float(b);
}

// ---- K0: all precompute: wvec, conv weight pack, rfft A-table, irfft B-table ----
__global__ void k_prep0(const float* __restrict__ mix_w, const float* __restrict__ mix_b,
                        const float* __restrict__ rank_scale, const float* __restrict__ proj_w,
                        const float* __restrict__ proj_b,
                        const float* __restrict__ c1w, const float* __restrict__ c2w,
                        float* __restrict__ ws){
    unsigned short* wt = (unsigned short*)(ws + OFF_WT);
    if (blockIdx.x == 0){
        float* wv = ws + OFF_WVEC;
        int t = threadIdx.x;
        if (t < 32){
            float sre=0.f, sim=0.f;
            for (int r=0;r<RR;r++){
                float a = proj_w[r]*rank_scale[r];
                sre += a*mix_w[r*2*RR + t];
                sim += a*mix_w[(RR+r)*2*RR + t];
            }
            wv[t] = sre; wv[32+t] = sim;
        }
        if (t == 0){
            float cre=0.f, cim=0.f;
            for (int r=0;r<RR;r++){
                float a = proj_w[r]*rank_scale[r];
                cre += a*mix_b[r];
                cim += a*mix_b[RR+r];
            }
            wv[64] = cre + proj_b[0]; wv[65] = cim;
        }
        return;
    }
    int i = (blockIdx.x-1)*256 + threadIdx.x;
    if (i < 18432){
        int which = (i >= 9216);
        int j = which ? i - 9216 : i;
        int je   = j & 7;
        int lane = (j >> 3) & 63;
        int ct   = (j >> 9) & 1;
        int tap  = j >> 10;
        int kh = tap/3, kw = tap - kh*3;
        int co = ct*16 + (lane & 15);
        int ci = (lane >> 4)*8 + je;
        const float* cw = which ? c2w : c1w;
        wt[i] = f2bf(cw[((co*CC + ci)*3 + kh)*3 + kw]);
        return;
    }
    i -= 18432;
    if (i < 10240){
        int j = i & 7, lane = (i>>3)&63, cch = (i>>9)&3, t = i>>11;
        int frow = t*16 + (lane & 15);
        int k = ((lane>>4)&3)*8 + j;
        int w = (cch & 1)*32 + k;
        float coef = 0.f;
        if (frow < 33)       coef =  cosf(2.0f*PI_F*(float)(frow*w)/64.0f);
        else if (frow < 66)  coef = -sinf(2.0f*PI_F*(float)((frow-33)*w)/64.0f);
        unsigned short hi = f2bf(coef);
        wt[18432 + i] = (cch < 2) ? hi : f2bf(coef - bf2f(hi));
        return;
    }
    i -= 10240;
    if (i < 12288){
        int wtile = i / 3072;
        int rem = i - wtile*3072;
        int ch = rem >> 9;
        int ll = rem & 511;
        int lane = ll >> 3, j = ll & 7;
        int w = wtile*16 + (lane & 15);
        int k = (ch % 3)*32 + ((lane>>4)&3)*8 + j;
        float coef = 0.f;
        if (k < 33){
            float s = (k==0 || k==32) ? 1.f : 2.f;
            coef = s*cosf(2.0f*PI_F*(float)(k*w)/64.0f)*(1.0f/64.0f);
        } else if (k < 66){
            int f = k - 33;
            float s = (f==0 || f==32) ? 1.f : 2.f;
            coef = -s*sinf(2.0f*PI_F*(float)(f*w)/64.0f)*(1.0f/64.0f);
        }
        unsigned short hi = f2bf(coef);
        wt[18432 + 10240 + i] = (ch < 3) ? hi : f2bf(coef - bf2f(hi));
        return;
    }
}

// ---- K1: conv1 (MFMA, bf16). Block = (l, h-tile of 2). Grid 512. ----
__global__ __launch_bounds__(256, 4) void k_conv1m(const float* __restrict__ x,
                                                   const unsigned short* __restrict__ wt,
                                                   const float* __restrict__ cb,
                                                   unsigned short* __restrict__ f1p){
    __shared__ __align__(16) unsigned short xs[4*66*32];  // rows h0-1..h0+2
    __shared__ __align__(16) unsigned short pw[9216];

    const int tid  = threadIdx.x;
    const int l    = blockIdx.x >> 5;
    const int h0   = (blockIdx.x & 31)*2;
    const int wid  = tid >> 6;
    const int lane = tid & 63;
    const int col  = lane & 15;
    const int kgrp = lane >> 4;

    {
        const unsigned int* src = (const unsigned int*)wt;
        unsigned int* dst = (unsigned int*)pw;
        #pragma unroll
        for (int j = 0; j < 18; ++j) dst[tid + j*256] = src[tid + j*256];
    }
    {
        const int rr = tid >> 6;          // 0..3 -> rows h0-1..h0+2
        const int w  = tid & 63;
        int hh = h0 - 1 + rr;
        bool hv = (hh >= 0 && hh < HH);
        const float* sp = x + (long)l*HH*WW + hh*WW + w;
        int wIdx = 1 + w;
        #pragma unroll
        for (int cib = 0; cib < 4; ++cib){
            float v[8];
            #pragma unroll
            for (int k = 0; k < 8; ++k)
                v[k] = hv ? sp[(long)(cib*8 + k)*LL*HH*WW] : 0.f;
            uint4 p;
            p.x = (unsigned)f2bf(v[0]) | ((unsigned)f2bf(v[1])<<16);
            p.y = (unsigned)f2bf(v[2]) | ((unsigned)f2bf(v[3])<<16);
            p.z = (unsigned)f2bf(v[4]) | ((unsigned)f2bf(v[5])<<16);
            p.w = (unsigned)f2bf(v[6]) | ((unsigned)f2bf(v[7])<<16);
            int cs = cib ^ (wIdx & 3);
            *(uint4*)&xs[(rr*66 + wIdx)*32 + cs*8] = p;
        }
    }
    if (tid < 32){   // halo columns, 4 rows x 2 cols x 4 cib
        int row = tid >> 3, rest = tid & 7;
        int wIdx = (rest >> 2) ? 65 : 0;
        int cib = rest & 3;
        *(uint4*)&xs[(row*66 + wIdx)*32 + cib*8] = make_uint4(0,0,0,0);
    }
    __syncthreads();

    #pragma unroll
    for (int u = 0; u < 4; ++u){
        int unit = wid + u*4;             // 0..15
        int hloc = unit >> 3;             // 0..1
        int rem  = unit & 7;
        int ct   = rem >> 2;
        int wt16 = rem & 3;
        int colw = wt16*16 + col;
        f32x4 acc = {0.f,0.f,0.f,0.f};
        #pragma unroll
        for (int kh = 0; kh < 3; ++kh){
            #pragma unroll
            for (int kw = 0; kw < 3; ++kw){
                int wIdx = colw + kw;
                int cs = kgrp ^ (wIdx & 3);
                short8 b = *(const short8*)&xs[((hloc+kh)*66 + wIdx)*32 + cs*8];
                short8 a = *(const short8*)&pw[((kh*3+kw)*2 + ct)*512 + lane*8];
                acc = __builtin_amdgcn_mfma_f32_16x16x32_bf16(a, b, acc, 0, 0, 0);
            }
        }
        int co0 = ct*16 + kgrp*4;
        int h = h0 + hloc;
        float o[4];
        #pragma unroll
        for (int r = 0; r < 4; ++r){
            float v = acc[r] + cb[co0+r];
            o[r] = v * sigmoidf_(v);
        }
        uint2 pk;
        pk.x = (unsigned)f2bf(o[0]) | ((unsigned)f2bf(o[1])<<16);
        pk.y = (unsigned)f2bf(o[2]) | ((unsigned)f2bf(o[3])<<16);
        *(uint2*)&f1p[(((long)l*HH + h)*WW + colw)*32 + co0] = pk;
    }
}

// ---- K2: conv2 (MFMA, bf16) -> PART directly (no LDS bounce). Grid 512. ----
__global__ __launch_bounds__(256, 4) void k_conv2m(const unsigned short* __restrict__ f1p,
                                                   const unsigned short* __restrict__ wt,
                                                   const float* __restrict__ cb,
                                                   float* __restrict__ ws){
    __shared__ __align__(16) unsigned short xs[4*66*32];
    __shared__ __align__(16) unsigned short pw[9216];

    const int tid  = threadIdx.x;
    const int l    = blockIdx.x >> 5;
    const int h0   = (blockIdx.x & 31)*2;
    const int wid  = tid >> 6;
    const int lane = tid & 63;
    const int col  = lane & 15;
    const int kgrp = lane >> 4;

    {
        const unsigned int* src = (const unsigned int*)wt;
        unsigned int* dst = (unsigned int*)pw;
        #pragma unroll
        for (int j = 0; j < 18; ++j) dst[tid + j*256] = src[tid + j*256];
    }
    {
        const int rr = tid >> 6;
        const int w  = tid & 63;
        int hh = h0 - 1 + rr;
        bool hv = (hh >= 0 && hh < HH);
        const uint4* sp = (const uint4*)&f1p[(((long)l*HH + hh)*WW + w)*32];
        int wIdx = 1 + w;
        #pragma unroll
        for (int cib = 0; cib < 4; ++cib){
            uint4 p = hv ? sp[cib] : make_uint4(0,0,0,0);
            int cs = cib ^ (wIdx & 3);
            *(uint4*)&xs[(rr*66 + wIdx)*32 + cs*8] = p;
        }
    }
    if (tid < 32){
        int row = tid >> 3, rest = tid & 7;
        int wIdx = (rest >> 2) ? 65 : 0;
        int cib = rest & 3;
        *(uint4*)&xs[(row*66 + wIdx)*32 + cib*8] = make_uint4(0,0,0,0);
    }
    __syncthreads();

    #pragma unroll
    for (int u = 0; u < 4; ++u){
        int unit = wid + u*4;
        int hloc = unit >> 3;
        int rem  = unit & 7;
        int ct   = rem >> 2;
        int wt16 = rem & 3;
        int colw = wt16*16 + col;
        f32x4 acc = {0.f,0.f,0.f,0.f};
        #pragma unroll
        for (int kh = 0; kh < 3; ++kh){
            #pragma unroll
            for (int kw = 0; kw < 3; ++kw){
                int wIdx = colw + kw;
                int cs = kgrp ^ (wIdx & 3);
                short8 b = *(const short8*)&xs[((hloc+kh)*66 + wIdx)*32 + cs*8];
                short8 a = *(const short8*)&pw[((kh*3+kw)*2 + ct)*512 + lane*8];
                acc = __builtin_amdgcn_mfma_f32_16x16x32_bf16(a, b, acc, 0, 0, 0);
            }
        }
        int co0 = ct*16 + kgrp*4;
        int h = h0 + hloc;
        float* pp = ws + OFF_PART + ((long)(l*HH + h))*2048 + colw;
        #pragma unroll
        for (int r = 0; r < 4; ++r){
            float v = acc[r] + cb[co0+r];
            pp[(co0+r)*WW] = v * sigmoidf_(v);
        }
    }
}

// ---- K2b: reduce partials over h -> colsum[l][c][w] ----
__global__ void k_colred(float* __restrict__ ws){
    int b = blockIdx.x;
    int l = b >> 5, c = b & 31;
    int w = threadIdx.x;
    const float* p = ws + OFF_PART + (long)l*HH*2048 + c*WW + w;
    float s = 0.f;
    #pragma unroll 8
    for (int h = 0; h < HH; ++h) s += p[h*2048];
    ws[OFF_COLSUM + (l*CC + c)*WW + w] = s;
}

// ---- K3: glob + adaptive pool fused ----
__global__ void k_globfeat(const float* __restrict__ gfc_w, const float* __restrict__ gfc_b,
                           float* __restrict__ ws){
    __shared__ float gs[CC], gl[CC];
    int l = blockIdx.x;
    int tid = threadIdx.x;
    if (tid < 32){
        const float* cs = ws + OFF_COLSUM + (l*CC+tid)*WW;
        float s = 0.f;
        for (int w=0;w<WW;w++) s += cs[w];
        gs[tid] = s;
    }
    __syncthreads();
    if (tid < 32){
        float acc = gfc_b[tid];
        for (int i=0;i<CC;i++) acc += gs[i]*(1.0f/4096.0f)*gfc_w[tid*CC+i];
        gl[tid] = sigmoidf_(acc);
    }
    __syncthreads();
    for (int i = tid; i < WF*CC; i += 256){
        int c = i & 31, wf = i >> 5;
        int s = (wf*64)/33;
        int e = ((wf+1)*64 + 32)/33;
        const float* cs = ws + OFF_COLSUM + (l*CC+c)*WW;
        float sum = 0.f;
        for (int w=s;w<e;w++) sum += cs[w];
        ws[OFF_FEAT + (l*WF+wf)*CC + c] = gl[c] * sum / (64.0f*(float)(e-s));
    }
}

// ---- K6: rfft via MFMA. Block=(l,c). ----
__global__ __launch_bounds__(256, 4) void k_rfftm(const float* __restrict__ x,
                                                  const unsigned short* __restrict__ at,
                                                  float* __restrict__ ws){
    __shared__ __align__(16) unsigned short xs[HH*68];
    int b = blockIdx.x; int l = b >> 5, c = b & 31;
    int tid = threadIdx.x;
    const int wid  = tid >> 6;
    const int lane = tid & 63;
    const int col  = lane & 15;
    const int kgrp = lane >> 4;

    const float* xp = x + (long)(c*LL + l)*HH*WW;
    for (int i = tid; i < HH*WW; i += 256){
        int h = i >> 6, w = i & 63;
        xs[h*68 + w] = f2bf(xp[i]);
    }
    __syncthreads();

    float* xfr = ws + OFF_XFR + (long)(l*CC + c)*HH*WF;
    float* xfi = ws + OFF_XFI + (long)(l*CC + c)*HH*WF;
    #pragma unroll
    for (int q = 0; q < 5; ++q){
        int unit = wid + q*4;
        int ftile = unit >> 2;
        int htile = unit & 3;
        f32x4 acc = {0.f,0.f,0.f,0.f};
        #pragma unroll
        for (int cch = 0; cch < 4; ++cch){
            short8 a = *(const short8*)&at[(((ftile*4 + cch)*64) + lane)*8];
            short8 bb = *(const short8*)&xs[(htile*16 + col)*68 + (cch & 1)*32 + kgrp*8];
            acc = __builtin_amdgcn_mfma_f32_16x16x32_bf16(a, bb, acc, 0, 0, 0);
        }
        int h = htile*16 + col;
        #pragma unroll
        for (int r = 0; r < 4; ++r){
            int fr = ftile*16 + kgrp*4 + r;
            if (fr < 33)      xfr[fr*HH + h] = acc[r];
            else if (fr < 66) xfi[(fr-33)*HH + h] = acc[r];
        }
    }
}

// ---- K7: scan over L, HEAD FUSED IN. Block = (c, wf). ----
__global__ __launch_bounds__(256) void k_scan(const float* __restrict__ hw,
                                              const float* __restrict__ hb,
                                              const float* __restrict__ dt,
                                              float* __restrict__ ws){
    __shared__ float lA[LL*RR], lI[LL*RR], lS[LL*RR];
    __shared__ float wv[66];
    __shared__ float lfeat[LL*CC];
    int b = blockIdx.x;
    int c = b / WF, f = b - c*WF;
    int tid = threadIdx.x;
    if (tid < 66) wv[tid] = ws[OFF_WVEC + tid];
    for (int i = tid; i < LL*CC; i += 256){
        int l = i >> 5, ii = i & 31;
        lfeat[i] = ws[OFF_FEAT + (l*WF + f)*CC + ii];
    }
    __syncthreads();
    {
        // head: one (l,r) triple per thread
        int l = tid >> 4, r = tid & 15;
        const float* feat = lfeat + l*CC;
        int j0 = (c*RR + r)*3;
        const float* w0 = hw + j0*CC;
        float p0=hb[j0], p1=hb[j0+1], p2=hb[j0+2];
        #pragma unroll 8
        for (int i=0;i<CC;i++){
            float fv = feat[i];
            p0 += fv*w0[i]; p1 += fv*w0[CC+i]; p2 += fv*w0[2*CC+i];
        }
        float nu = fmaxf(p0,0.f) + log1pf(expf(-fabsf(p0)));
        float th = tanhf(p1)*PI_F;
        float sg = sigmoidf_(p2);
        float dtv = dt[l];
        float decay = expf(-nu*dtv);
        float ang = th*dtv;
        lA[tid] = decay*cosf(ang);
        lI[tid] = decay*sinf(ang);
        lS[tid] = sg*(1.0f - expf(-2.0f*fmaxf(dtv,0.f)));
    }
    __syncthreads();
    const int h  = tid >> 2;
    const int rq = tid & 3;
    float sre[4] = {0,0,0,0}, sim[4] = {0,0,0,0};
    float w0_[4], w1_[4], w2_[4], w3_[4];
    #pragma unroll
    for (int q=0;q<4;q++){
        int r = rq*4 + q;
        w0_[q]=wv[r]; w1_[q]=wv[16+r]; w2_[q]=wv[32+r]; w3_[q]=wv[48+r];
    }
    const float cre = wv[64], cim = wv[65];
    const long fh = (long)(c*WF + f)*HH + h;
    #pragma unroll 1
    for (int l=0;l<LL;l++){
        float xr = ws[OFF_XFR + l*(CC*HH*WF) + fh];
        float xi = ws[OFF_XFI + l*(CC*HH*WF) + fh];
        float yr = 0.f, yi = 0.f;
        #pragma unroll
        for (int q=0;q<4;q++){
            int r = rq*4 + q;
            float a = lA[l*16+r], ii = lI[l*16+r], s = lS[l*16+r];
            float nre = a*sre[q] - ii*sim[q] + s*xr;
            float nim = a*sim[q] + ii*sre[q] + s*xi;
            sre[q]=nre; sim[q]=nim;
            yr += w0_[q]*nre + w1_[q]*nim;
            yi += w2_[q]*nre + w3_[q]*nim;
        }
        yr += __shfl_xor(yr, 1); yr += __shfl_xor(yr, 2);
        yi += __shfl_xor(yi, 1); yi += __shfl_xor(yi, 2);
        if (rq == 0){
            ws[OFF_YFR + l*(CC*HH*WF) + fh] = yr + cre;
            ws[OFF_YFI + l*(CC*HH*WF) + fh] = yi + cim;
        }
    }
}

// ---- K8: irfft via MFMA. Block=(l,c). ----
__global__ __launch_bounds__(256, 4) void k_irfftm(const unsigned short* __restrict__ btb,
                                                   float* __restrict__ ws){
    __shared__ __align__(16) unsigned short mh[HH*100];
    int b = blockIdx.x; int l = b >> 5, c = b & 31;
    int tid = threadIdx.x;
    const int wid  = tid >> 6;
    const int lane = tid & 63;
    const int col  = lane & 15;
    const int kgrp = lane >> 4;

    const float* Yr = ws + OFF_YFR + (long)(l*CC + c)*HH*WF;
    const float* Yi = ws + OFF_YFI + (long)(l*CC + c)*HH*WF;
    for (int i = tid; i < 33*64; i += 256){
        int f = i >> 6, h = i & 63;
        mh[h*100 + f]      = f2bf(Yr[i]);
        mh[h*100 + 33 + f] = f2bf(Yi[i]);
    }
    for (int i = tid; i < 64*34; i += 256){
        int h = i / 34, f = 66 + (i - (i/34)*34);
        mh[h*100 + f] = 0;
    }
    __syncthreads();

    float* y1 = ws + OFF_Y1 + (long)(l*CC + c)*HH*WW;
    #pragma unroll
    for (int q = 0; q < 4; ++q){
        int unit = wid + q*4;
        int htile = unit >> 2;
        int wtile = unit & 3;
        f32x4 acc = {0.f,0.f,0.f,0.f};
        #pragma unroll
        for (int ch = 0; ch < 6; ++ch){
            int kof = (ch % 3)*32 + kgrp*8;
            short8 a = *(const short8*)&mh[(htile*16 + col)*100 + kof];
            short8 bb = *(const short8*)&btb[(((wtile*6 + ch)*64) + lane)*8];
            acc = __builtin_amdgcn_mfma_f32_16x16x32_bf16(a, bb, acc, 0, 0, 0);
        }
        int w = wtile*16 + col;
        #pragma unroll
        for (int r = 0; r < 4; ++r){
            int h = htile*16 + kgrp*4 + r;
            y1[h*WW + w] = acc[r];
        }
    }
}

// ---- K9: pif + raw W-mean (YM) + row sum-of-squares (YQ). Block = (l,h). ----
__global__ void k_pif(const float* __restrict__ pw, const float* __restrict__ pb,
                      float* __restrict__ ws){
    __shared__ float row[CC][WW];
    int b = blockIdx.x; int l = b>>6, h = b&63;
    int tid = threadIdx.x;
    for (int k=0;k<8;k++){
        int i = tid + k*256;
        int ci = i>>6, w = i&63;
        row[ci][w] = ws[OFF_Y1 + ((l*CC+ci)*HH + h)*WW + w];
    }
    __syncthreads();
    for (int k=0;k<8;k++){
        int i = tid + k*256;
        int o = i>>6, w = i&63;   // o wave-uniform
        float acc = pb[o];
        #pragma unroll
        for (int ci=0;ci<CC;ci++) acc += pw[o*CC+ci]*row[ci][w];
        ws[OFF_Y2 + ((l*CC+o)*HH + h)*WW + w] = acc;
        float s = acc, q = acc*acc;
        s += __shfl_down(s, 32, 64); q += __shfl_down(q, 32, 64);
        s += __shfl_down(s, 16, 64); q += __shfl_down(q, 16, 64);
        s += __shfl_down(s,  8, 64); q += __shfl_down(q,  8, 64);
        s += __shfl_down(s,  4, 64); q += __shfl_down(q,  4, 64);
        s += __shfl_down(s,  2, 64); q += __shfl_down(q,  2, 64);
        s += __shfl_down(s,  1, 64); q += __shfl_down(q,  1, 64);
        if ((tid & 63) == 0){
            ws[OFF_YM + (l*HH+h)*CC + o] = s*(1.0f/64.0f);
            ws[OFF_YQ + (l*HH+h)*CC + o] = q;
        }
    }
}

// ---- K12: gate, with GN stats fused (per-l, per-h-quad). Grid 64. ----
__global__ void k_gatel(const float* __restrict__ g1w, const float* __restrict__ g1b,
                        const float* __restrict__ g2w, const float* __restrict__ g2b,
                        const float* __restrict__ gnw, const float* __restrict__ gnb,
                        float* __restrict__ ws){
    __shared__ float mus[4], rsd[4];
    __shared__ float ymn[16][CC+1];
    __shared__ float mid[16][4];
    int blk = blockIdx.x;
    int l = blk >> 2, hq = blk & 3;
    int h0 = hq*16;
    int tid = threadIdx.x;

    // group stats over full l: group g = tid>>6 (one wave per group), j = lane = h row
    {
        int g = tid >> 6, j = tid & 63;
        const float* ymp = ws + OFF_YM + (l*HH + j)*CC + g*8;
        const float* yqp = ws + OFF_YQ + (l*HH + j)*CC + g*8;
        float s = 0.f, q = 0.f;
        #pragma unroll
        for (int cc = 0; cc < 8; ++cc){ s += ymp[cc]; q += yqp[cc]; }
        #pragma unroll
        for (int off = 32; off > 0; off >>= 1){
            s += __shfl_down(s, off, 64);
            q += __shfl_down(q, off, 64);
        }
        if (j == 0){
            float mean = s*(1.0f/512.0f);
            float rstd = rsqrtf(q*(1.0f/32768.0f) - mean*mean + 1e-5f);
            mus[g] = mean; rsd[g] = rstd;
            if (hq == 0){ ws[OFF_GNM + l*4+g] = mean; ws[OFF_GNR + l*4+g] = rstd; }
        }
    }
    __syncthreads();
    // normalize this quad's ym rows into LDS: 16h x 32c = 512
    for (int i = tid; i < 16*CC; i += 256){
        int hh = i >> 5, cidx = i & 31;
        int g = cidx >> 3;
        ymn[hh][cidx] = (ws[OFF_YM + (l*HH + h0 + hh)*CC + cidx] - mus[g])*rsd[g]*gnw[cidx] + gnb[cidx];
    }
    __syncthreads();
    // mid[4] per h: 64 threads
    if (tid < 64){
        int hh = tid >> 2, m = tid & 3;
        float a = g1b[m];
        #pragma unroll 8
        for (int i = 0; i < CC; ++i) a += ymn[hh][i]*g1w[m*CC+i];
        mid[hh][m] = a*sigmoidf_(a);
    }
    __syncthreads();
    // gates: 512 per block
    for (int i = tid; i < 16*CC; i += 256){
        int hh = i >> 5, cidx = i & 31;
        float a = g2b[cidx];
        #pragma unroll
        for (int m = 0; m < 4; ++m) a += mid[hh][m]*g2w[cidx*4+m];
        ws[OFF_GATE + (l*HH + h0 + hh)*CC + cidx] = sigmoidf_(a);
    }
}

// ---- K13: residual (float4), GN applied inline on raw Y2 ----
__global__ void k_final(const float* __restrict__ x, float* __restrict__ out,
                        const float* __restrict__ gnw, const float* __restrict__ gnb,
                        const float* __restrict__ ws){
    int t = blockIdx.x*256 + threadIdx.x;
    int n = t*4;
    int h = (n>>6)&63, l = (n>>12)&15, c = n>>16;
    int g = c>>3;
    float mu = ws[OFF_GNM + l*4+g], rstd = ws[OFF_GNR + l*4+g];
    float gw = gnw[c]*rstd, gb = gnb[c] - mu*gnw[c]*rstd;
    float4 z  = *(const float4*)(ws + OFF_Y2 + (((l*CC+c)*HH+h)*WW) + (n&63));
    float  gt = ws[OFF_GATE + (l*HH+h)*CC + c];
    float4 xv = *(const float4*)(x + n);
    float4 o;
    o.x = xv.x + (z.x*gw+gb)*gt; o.y = xv.y + (z.y*gw+gb)*gt;
    o.z = xv.z + (z.z*gw+gb)*gt; o.w = xv.w + (z.w*gw+gb)*gt;
    *(float4*)(out + n) = o;
}

extern "C" void kernel_launch(void* const* d_in, const int* in_sizes, int n_in,
                              void* d_out, int out_size, void* d_ws, size_t ws_size,
                              hipStream_t stream){
    const float* x    = (const float*)d_in[0];
    const float* dt   = (const float*)d_in[1];
    const float* c1w  = (const float*)d_in[2];
    const float* c1b  = (const float*)d_in[3];
    const float* c2w  = (const float*)d_in[4];
    const float* c2b  = (const float*)d_in[5];
    const float* gfcw = (const float*)d_in[6];
    const float* gfcb = (const float*)d_in[7];
    const float* hw   = (const float*)d_in[8];
    const float* hb   = (const float*)d_in[9];
    const float* mixw = (const float*)d_in[10];
    const float* mixb = (const float*)d_in[11];
    const float* rs   = (const float*)d_in[12];
    const float* pjw  = (const float*)d_in[13];
    const float* pjb  = (const float*)d_in[14];
    const float* pifw = (const float*)d_in[15];
    const float* pifb = (const float*)d_in[16];
    const float* gnw  = (const float*)d_in[17];
    const float* gnb  = (const float*)d_in[18];
    const float* g1w  = (const float*)d_in[19];
    const float* g1b  = (const float*)d_in[20];
    const float* g2w  = (const float*)d_in[21];
    const float* g2b  = (const float*)d_in[22];
    float* ws  = (float*)d_ws;
    float* out = (float*)d_out;
    unsigned short* wt  = (unsigned short*)(ws + OFF_WT);
    unsigned short* at  = wt + 18432;
    unsigned short* btb = wt + 18432 + 10240;
    unsigned short* f1p = (unsigned short*)(ws + OFF_F1);

    k_prep0   <<<161,  256, 0, stream>>>(mixw, mixb, rs, pjw, pjb, c1w, c2w, ws);
    k_conv1m  <<<512,  256, 0, stream>>>(x, wt, c1b, f1p);
    k_conv2m  <<<512,  256, 0, stream>>>(f1p, wt + 9216, c2b, ws);
    k_colred  <<<512,  64,  0, stream>>>(ws);
    k_globfeat<<<16,   256, 0, stream>>>(gfcw, gfcb, ws);
    k_rfftm   <<<512,  256, 0, stream>>>(x, at, ws);
    k_scan    <<<1056, 256, 0, stream>>>(hw, hb, dt, ws);
    k_irfftm  <<<512,  256, 0, stream>>>(btb, ws);
    k_pif     <<<1024, 256, 0, stream>>>(pifw, pifb, ws);
    k_gatel   <<<64,   256, 0, stream>>>(g1w, g1b, g2w, g2b, gnw, gnb, ws);
    k_final   <<<2048, 256, 0, stream>>>(x, out, gnw, gnb, ws);
}